// Round 1
// baseline (1222.629 us; speedup 1.0000x reference)
//
#include <hip/hip_runtime.h>
#include <hip/hip_bf16.h>

#define N_NODES 50000
#define N_EDGES 800000
#define TOT_E   (N_EDGES + N_NODES)   // edges + self loops

// ---------------- edge-index dtype detection + repack ----------------
// Reference declares int64; harness doc says int32. Detect on device:
// under int64 layout every odd 32-bit word is 0 (values < 2^31).
__global__ void k_detect(const unsigned* __restrict__ e_raw, int* __restrict__ flag) {
    __shared__ int nz;
    if (threadIdx.x == 0) nz = 0;
    __syncthreads();
    int cnt = 0;
    for (int i = threadIdx.x; i < 2048; i += 256)
        if (e_raw[2 * i + 1] != 0u) cnt = 1;
    if (cnt) atomicOr(&nz, 1);
    __syncthreads();
    if (threadIdx.x == 0) *flag = (nz == 0) ? 1 : 0;   // 1 == int64 layout
}

__global__ __launch_bounds__(256) void k_repack(const void* __restrict__ e_raw,
        const int* __restrict__ flag, int* __restrict__ edges) {
    int i = blockIdx.x * 256 + threadIdx.x;
    if (i >= 2 * N_EDGES) return;
    if (*flag) edges[i] = (int)((const long long*)e_raw)[i];
    else       edges[i] = ((const int*)e_raw)[i];
}

// ---------------- K1: h = x @ W_gat ; a_src/a_dst head dots ----------------
// block = 128 threads (one per output column), 8 rows per block.
__global__ __launch_bounds__(128) void k_gat_lin(const float* __restrict__ x,
        const float* __restrict__ W, const float* __restrict__ att_s,
        const float* __restrict__ att_d, float* __restrict__ h,
        float* __restrict__ a_src, float* __restrict__ a_dst) {
    __shared__ float xs[8][128];
    const int j = threadIdx.x;
    const int n0 = blockIdx.x * 8;

    const float4* xg = (const float4*)(x + (size_t)n0 * 128);
    float4* xls = (float4*)&xs[0][0];
#pragma unroll
    for (int i = 0; i < 2; i++) xls[j + 128 * i] = xg[j + 128 * i];
    __syncthreads();

    float acc[8];
#pragma unroll
    for (int r = 0; r < 8; r++) acc[r] = 0.f;

    for (int k = 0; k < 128; k += 4) {
        float w0 = W[(k + 0) * 128 + j];
        float w1 = W[(k + 1) * 128 + j];
        float w2 = W[(k + 2) * 128 + j];
        float w3 = W[(k + 3) * 128 + j];
#pragma unroll
        for (int r = 0; r < 8; r++) {
            float4 xv = *(const float4*)&xs[r][k];
            acc[r] = fmaf(xv.x, w0, acc[r]);
            acc[r] = fmaf(xv.y, w1, acc[r]);
            acc[r] = fmaf(xv.z, w2, acc[r]);
            acc[r] = fmaf(xv.w, w3, acc[r]);
        }
    }

    const float ws_ = att_s[j];   // att flat index == j (head=j>>5, c=j&31)
    const float wd_ = att_d[j];
#pragma unroll
    for (int r = 0; r < 8; r++) {
        h[(size_t)(n0 + r) * 128 + j] = acc[r];
        float vs = acc[r] * ws_;
        float vd = acc[r] * wd_;
#pragma unroll
        for (int o = 16; o >= 1; o >>= 1) {
            vs += __shfl_down(vs, o, 32);
            vd += __shfl_down(vd, o, 32);
        }
        if ((j & 31) == 0) {
            a_src[(n0 + r) * 4 + (j >> 5)] = vs;
            a_dst[(n0 + r) * 4 + (j >> 5)] = vd;
        }
    }
}

// ---------------- K2: edge attention logits -> exp, denom accumulation ----
__global__ __launch_bounds__(256) void k_edge1(const int* __restrict__ es,
        const float* __restrict__ a_src, const float* __restrict__ a_dst,
        float* __restrict__ e_exp, float* __restrict__ denom) {
    int e = blockIdx.x * 256 + threadIdx.x;
    if (e >= TOT_E) return;
    int s, d;
    if (e < N_EDGES) { s = es[e]; d = es[N_EDGES + e]; }
    else { s = e - N_EDGES; d = s; }

    float4 av = ((const float4*)a_src)[s];
    float4 dv = ((const float4*)a_dst)[d];
    float4 ex;
    float t;
    t = av.x + dv.x; t = (t > 0.f) ? t : 0.2f * t; ex.x = __expf(t);
    t = av.y + dv.y; t = (t > 0.f) ? t : 0.2f * t; ex.y = __expf(t);
    t = av.z + dv.z; t = (t > 0.f) ? t : 0.2f * t; ex.z = __expf(t);
    t = av.w + dv.w; t = (t > 0.f) ? t : 0.2f * t; ex.w = __expf(t);
    ((float4*)e_exp)[e] = ex;
    atomicAdd(&denom[d * 4 + 0], ex.x);
    atomicAdd(&denom[d * 4 + 1], ex.y);
    atomicAdd(&denom[d * 4 + 2], ex.z);
    atomicAdd(&denom[d * 4 + 3], ex.w);
}

// ---------------- K3: message scatter: agg[dst] += h[src] * alpha --------
// 64 lanes per edge, 2 channels per lane.
__global__ __launch_bounds__(256) void k_scatter(const int* __restrict__ es,
        const float* __restrict__ h, const float* __restrict__ e_exp,
        const float* __restrict__ denom, float* __restrict__ agg) {
    int e = blockIdx.x * 4 + (threadIdx.x >> 6);
    int lane = threadIdx.x & 63;
    if (e >= TOT_E) return;
    int s, d;
    if (e < N_EDGES) { s = es[e]; d = es[N_EDGES + e]; }
    else { s = e - N_EDGES; d = s; }
    int hd = lane >> 4;   // channels 2*lane, 2*lane+1 share head
    float a = e_exp[e * 4 + hd] / (denom[d * 4 + hd] + 1e-16f);
    float2 hv = ((const float2*)h)[(size_t)s * 64 + lane];
    atomicAdd(&agg[(size_t)d * 128 + 2 * lane + 0], hv.x * a);
    atomicAdd(&agg[(size_t)d * 128 + 2 * lane + 1], hv.y * a);
}

// ---------------- K4a: x1=elu(agg+b_gat); enc; x2=elu(dec) ---------------
__global__ __launch_bounds__(256) void k_mlp1(const float* __restrict__ agg,
        const float* __restrict__ b_gat, const float* __restrict__ W_enc,
        const float* __restrict__ b_enc, const float* __restrict__ W_dec,
        const float* __restrict__ b_dec, float* __restrict__ x2g) {
    __shared__ float sWe[128 * 64];
    __shared__ float sWd[64 * 128];
    __shared__ float sbg[128], sbe[64], sbd[128];
    __shared__ float sx1[2][128];
    __shared__ float senc[2][64];

    for (int i = threadIdx.x; i < 128 * 64; i += 256) sWe[i] = W_enc[i];
    for (int i = threadIdx.x; i < 64 * 128; i += 256) sWd[i] = W_dec[i];
    if (threadIdx.x < 128) sbg[threadIdx.x] = b_gat[threadIdx.x];
    if (threadIdx.x < 64)  sbe[threadIdx.x] = b_enc[threadIdx.x];
    if (threadIdx.x < 128) sbd[threadIdx.x] = b_dec[threadIdx.x];
    __syncthreads();

    const int half = threadIdx.x >> 7;
    const int t = threadIdx.x & 127;

    for (int pair = blockIdx.x; pair < N_NODES / 2; pair += gridDim.x) {
        int n = pair * 2 + half;
        {
            float v = agg[(size_t)n * 128 + t] + sbg[t];
            sx1[half][t] = (v > 0.f) ? v : (__expf(v) - 1.f);
        }
        __syncthreads();
        if (t < 64) {
            float acc = sbe[t];
            for (int k = 0; k < 128; k += 4) {
                float4 xv = *(const float4*)&sx1[half][k];
                acc = fmaf(xv.x, sWe[(k + 0) * 64 + t], acc);
                acc = fmaf(xv.y, sWe[(k + 1) * 64 + t], acc);
                acc = fmaf(xv.z, sWe[(k + 2) * 64 + t], acc);
                acc = fmaf(xv.w, sWe[(k + 3) * 64 + t], acc);
            }
            senc[half][t] = acc;
        }
        __syncthreads();
        {
            float acc = sbd[t];
            for (int k = 0; k < 64; k += 4) {
                float4 xv = *(const float4*)&senc[half][k];
                acc = fmaf(xv.x, sWd[(k + 0) * 128 + t], acc);
                acc = fmaf(xv.y, sWd[(k + 1) * 128 + t], acc);
                acc = fmaf(xv.z, sWd[(k + 2) * 128 + t], acc);
                acc = fmaf(xv.w, sWd[(k + 3) * 128 + t], acc);
            }
            float v = (acc > 0.f) ? acc : (__expf(acc) - 1.f);
            x2g[(size_t)n * 128 + t] = v;
        }
        __syncthreads();
    }
}

// ---------------- K4b: out = x2 @ W_out + b_out --------------------------
__global__ __launch_bounds__(256) void k_mlp2(const float* __restrict__ x2g,
        const float* __restrict__ W_out, const float* __restrict__ b_out,
        float* __restrict__ out) {
    __shared__ float sW[128 * 128];
    __shared__ float sb[128];
    __shared__ float sx[2][128];

    for (int i = threadIdx.x; i < 128 * 128; i += 256) sW[i] = W_out[i];
    if (threadIdx.x < 128) sb[threadIdx.x] = b_out[threadIdx.x];
    __syncthreads();

    const int half = threadIdx.x >> 7;
    const int t = threadIdx.x & 127;

    for (int pair = blockIdx.x; pair < N_NODES / 2; pair += gridDim.x) {
        int n = pair * 2 + half;
        sx[half][t] = x2g[(size_t)n * 128 + t];
        __syncthreads();
        float acc = sb[t];
        for (int k = 0; k < 128; k += 4) {
            float4 xv = *(const float4*)&sx[half][k];
            acc = fmaf(xv.x, sW[(k + 0) * 128 + t], acc);
            acc = fmaf(xv.y, sW[(k + 1) * 128 + t], acc);
            acc = fmaf(xv.z, sW[(k + 2) * 128 + t], acc);
            acc = fmaf(xv.w, sW[(k + 3) * 128 + t], acc);
        }
        out[(size_t)n * 128 + t] = acc;
        __syncthreads();
    }
}

extern "C" void kernel_launch(void* const* d_in, const int* in_sizes, int n_in,
                              void* d_out, int out_size, void* d_ws, size_t ws_size,
                              hipStream_t stream) {
    const float* x       = (const float*)d_in[0];
    const void*  e_raw   = d_in[1];
    const float* W_gat   = (const float*)d_in[2];
    const float* b_gat   = (const float*)d_in[3];
    const float* att_src = (const float*)d_in[4];
    const float* att_dst = (const float*)d_in[5];
    const float* W_enc   = (const float*)d_in[6];
    const float* b_enc   = (const float*)d_in[7];
    const float* W_dec   = (const float*)d_in[8];
    const float* b_dec   = (const float*)d_in[9];
    const float* W_out   = (const float*)d_in[10];
    const float* b_out   = (const float*)d_in[11];
    float* out = (float*)d_out;

    // workspace layout (floats)
    float* ws    = (float*)d_ws;
    float* h     = ws;                       // 6,400,000
    float* a_src = h + 6400000;              // 200,000
    float* a_dst = a_src + 200000;           // 200,000
    float* denom = a_dst + 200000;           // 200,000
    float* e_exp = denom + 200000;           // 3,400,000 (TOT_E*4)
    float* agg   = e_exp + 3400000;          // 6,400,000
    int*   edges = (int*)(agg + 6400000);    // 1,600,000 ints
    int*   flag  = edges + 1600000;          // 1 int
    float* x2g   = h;                        // reuse h after scatter

    k_detect<<<1, 256, 0, stream>>>((const unsigned*)e_raw, flag);
    k_repack<<<(2 * N_EDGES + 255) / 256, 256, 0, stream>>>(e_raw, flag, edges);

    k_gat_lin<<<N_NODES / 8, 128, 0, stream>>>(x, W_gat, att_src, att_dst, h, a_src, a_dst);

    hipMemsetAsync(denom, 0, 200000 * sizeof(float), stream);
    hipMemsetAsync(agg, 0, 6400000 * sizeof(float), stream);

    k_edge1<<<(TOT_E + 255) / 256, 256, 0, stream>>>(edges, a_src, a_dst, e_exp, denom);
    k_scatter<<<(TOT_E + 3) / 4, 256, 0, stream>>>(edges, h, e_exp, denom, agg);

    k_mlp1<<<512, 256, 0, stream>>>(agg, b_gat, W_enc, b_enc, W_dec, b_dec, x2g);
    k_mlp2<<<512, 256, 0, stream>>>(x2g, W_out, b_out, out);
}

// Round 2
// 657.349 us; speedup vs baseline: 1.8599x; 1.8599x over previous
//
#include <hip/hip_runtime.h>
#include <hip/hip_bf16.h>

#define N_NODES 50000
#define N_EDGES 800000

// ---------------- edge-index dtype detection + repack ----------------
__global__ void k_detect(const unsigned* __restrict__ e_raw, int* __restrict__ flag) {
    __shared__ int nz;
    if (threadIdx.x == 0) nz = 0;
    __syncthreads();
    int cnt = 0;
    for (int i = threadIdx.x; i < 2048; i += 256)
        if (e_raw[2 * i + 1] != 0u) cnt = 1;
    if (cnt) atomicOr(&nz, 1);
    __syncthreads();
    if (threadIdx.x == 0) *flag = (nz == 0) ? 1 : 0;   // 1 == int64 layout
}

__global__ __launch_bounds__(256) void k_repack(const void* __restrict__ e_raw,
        const int* __restrict__ flag, int* __restrict__ edges) {
    int i = blockIdx.x * 256 + threadIdx.x;
    if (i >= 2 * N_EDGES) return;
    if (*flag) edges[i] = (int)((const long long*)e_raw)[i];
    else       edges[i] = ((const int*)e_raw)[i];
}

// ---------------- K1: h = x @ W_gat ; a_src/a_dst head dots ----------------
__global__ __launch_bounds__(128) void k_gat_lin(const float* __restrict__ x,
        const float* __restrict__ W, const float* __restrict__ att_s,
        const float* __restrict__ att_d, float* __restrict__ h,
        float* __restrict__ a_src, float* __restrict__ a_dst) {
    __shared__ float xs[8][128];
    const int j = threadIdx.x;
    const int n0 = blockIdx.x * 8;

    const float4* xg = (const float4*)(x + (size_t)n0 * 128);
    float4* xls = (float4*)&xs[0][0];
#pragma unroll
    for (int i = 0; i < 2; i++) xls[j + 128 * i] = xg[j + 128 * i];
    __syncthreads();

    float acc[8];
#pragma unroll
    for (int r = 0; r < 8; r++) acc[r] = 0.f;

    for (int k = 0; k < 128; k += 4) {
        float w0 = W[(k + 0) * 128 + j];
        float w1 = W[(k + 1) * 128 + j];
        float w2 = W[(k + 2) * 128 + j];
        float w3 = W[(k + 3) * 128 + j];
#pragma unroll
        for (int r = 0; r < 8; r++) {
            float4 xv = *(const float4*)&xs[r][k];
            acc[r] = fmaf(xv.x, w0, acc[r]);
            acc[r] = fmaf(xv.y, w1, acc[r]);
            acc[r] = fmaf(xv.z, w2, acc[r]);
            acc[r] = fmaf(xv.w, w3, acc[r]);
        }
    }

    const float ws_ = att_s[j];
    const float wd_ = att_d[j];
#pragma unroll
    for (int r = 0; r < 8; r++) {
        h[(size_t)(n0 + r) * 128 + j] = acc[r];
        float vs = acc[r] * ws_;
        float vd = acc[r] * wd_;
#pragma unroll
        for (int o = 16; o >= 1; o >>= 1) {
            vs += __shfl_down(vs, o, 32);
            vd += __shfl_down(vd, o, 32);
        }
        if ((j & 31) == 0) {
            a_src[(n0 + r) * 4 + (j >> 5)] = vs;
            a_dst[(n0 + r) * 4 + (j >> 5)] = vd;
        }
    }
}

// ---------------- CSR build: histogram -> scan -> fill -------------------
__global__ __launch_bounds__(256) void k_hist(const int* __restrict__ edges,
        int* __restrict__ cnt) {
    int e = blockIdx.x * 256 + threadIdx.x;
    if (e >= N_EDGES) return;
    atomicAdd(&cnt[edges[N_EDGES + e]], 1);
}

// single block of 256: chunked exclusive scan of 50000 counters
__global__ __launch_bounds__(256) void k_scan(const int* __restrict__ cnt,
        int* __restrict__ off, int* __restrict__ cursor) {
    __shared__ int ssum[256];
    const int t = threadIdx.x;
    const int chunk = (N_NODES + 255) / 256;   // 196
    int lo = t * chunk;
    int hi = lo + chunk; if (hi > N_NODES) hi = N_NODES;
    if (lo > N_NODES) lo = N_NODES;
    int s = 0;
    for (int i = lo; i < hi; i++) s += cnt[i];
    ssum[t] = s;
    __syncthreads();
    for (int o = 1; o < 256; o <<= 1) {
        int v = (t >= o) ? ssum[t - o] : 0;
        __syncthreads();
        ssum[t] += v;
        __syncthreads();
    }
    int base = (t == 0) ? 0 : ssum[t - 1];
    for (int i = lo; i < hi; i++) {
        off[i] = base; cursor[i] = base;
        base += cnt[i];
    }
    if (t == 255) off[N_NODES] = base;
}

__global__ __launch_bounds__(256) void k_fill(const int* __restrict__ edges,
        int* __restrict__ cursor, int* __restrict__ csr_src) {
    int e = blockIdx.x * 256 + threadIdx.x;
    if (e >= N_EDGES) return;
    int s = edges[e], d = edges[N_EDGES + e];
    int pos = atomicAdd(&cursor[d], 1);
    csr_src[pos] = s;
}

// ---------------- K3: CSR gather — softmax + weighted aggregation --------
// one wave (64 lanes) per destination node; 2 channels per lane.
__global__ __launch_bounds__(256) void k_gather(const int* __restrict__ off,
        const int* __restrict__ csr_src, const float* __restrict__ a_src,
        const float* __restrict__ a_dst, const float* __restrict__ h,
        float* __restrict__ agg) {
    int d = blockIdx.x * 4 + (threadIdx.x >> 6);
    if (d >= N_NODES) return;
    const int lane = threadIdx.x & 63;
    const int hd = lane >> 4;          // head of channels 2*lane, 2*lane+1
    const int lo = off[d], hi = off[d + 1];

    float4 ad = ((const float4*)a_dst)[d];

    // pass 1: denominator (all 4 heads), wave-strided over in-edges
    float dx = 0.f, dy = 0.f, dz = 0.f, dw = 0.f;
    for (int i = lo + lane; i < hi; i += 64) {
        int s = csr_src[i];
        float4 as = ((const float4*)a_src)[s];
        float t;
        t = as.x + ad.x; t = t > 0.f ? t : 0.2f * t; dx += __expf(t);
        t = as.y + ad.y; t = t > 0.f ? t : 0.2f * t; dy += __expf(t);
        t = as.z + ad.z; t = t > 0.f ? t : 0.2f * t; dz += __expf(t);
        t = as.w + ad.w; t = t > 0.f ? t : 0.2f * t; dw += __expf(t);
    }
#pragma unroll
    for (int o = 32; o >= 1; o >>= 1) {
        dx += __shfl_down(dx, o); dy += __shfl_down(dy, o);
        dz += __shfl_down(dz, o); dw += __shfl_down(dw, o);
    }
    dx = __shfl(dx, 0); dy = __shfl(dy, 0);
    dz = __shfl(dz, 0); dw = __shfl(dw, 0);

    // self-loop exp (identical in all lanes)
    float4 asd = ((const float4*)a_src)[d];
    float t;
    t = asd.x + ad.x; t = t > 0.f ? t : 0.2f * t; float sx = __expf(t);
    t = asd.y + ad.y; t = t > 0.f ? t : 0.2f * t; float sy = __expf(t);
    t = asd.z + ad.z; t = t > 0.f ? t : 0.2f * t; float sz = __expf(t);
    t = asd.w + ad.w; t = t > 0.f ? t : 0.2f * t; float sw = __expf(t);
    dx += sx; dy += sy; dz += sz; dw += sw;

    float den = (hd == 0) ? dx : (hd == 1) ? dy : (hd == 2) ? dz : dw;
    float inv = 1.f / (den + 1e-16f);
    float selfe = (hd == 0) ? sx : (hd == 1) ? sy : (hd == 2) ? sz : sw;
    float adh = (hd == 0) ? ad.x : (hd == 1) ? ad.y : (hd == 2) ? ad.z : ad.w;

    // pass 2: weighted message accumulation
    float2 hself = ((const float2*)h)[(size_t)d * 64 + lane];
    float asf = selfe * inv;
    float accx = hself.x * asf, accy = hself.y * asf;

    for (int i = lo; i < hi; i++) {
        int s = csr_src[i];
        float av = a_src[s * 4 + hd];
        float tt = av + adh; tt = tt > 0.f ? tt : 0.2f * tt;
        float al = __expf(tt) * inv;
        float2 hv = ((const float2*)h)[(size_t)s * 64 + lane];
        accx = fmaf(hv.x, al, accx);
        accy = fmaf(hv.y, al, accy);
    }
    float2 o2; o2.x = accx; o2.y = accy;
    ((float2*)agg)[(size_t)d * 64 + lane] = o2;
}

// ---------------- K4a: x1=elu(agg+b_gat); enc; x2=elu(dec) ---------------
__global__ __launch_bounds__(256) void k_mlp1(const float* __restrict__ agg,
        const float* __restrict__ b_gat, const float* __restrict__ W_enc,
        const float* __restrict__ b_enc, const float* __restrict__ W_dec,
        const float* __restrict__ b_dec, float* __restrict__ x2g) {
    __shared__ float sWe[128 * 64];
    __shared__ float sWd[64 * 128];
    __shared__ float sbg[128], sbe[64], sbd[128];
    __shared__ float sx1[2][128];
    __shared__ float senc[2][64];

    for (int i = threadIdx.x; i < 128 * 64; i += 256) sWe[i] = W_enc[i];
    for (int i = threadIdx.x; i < 64 * 128; i += 256) sWd[i] = W_dec[i];
    if (threadIdx.x < 128) sbg[threadIdx.x] = b_gat[threadIdx.x];
    if (threadIdx.x < 64)  sbe[threadIdx.x] = b_enc[threadIdx.x];
    if (threadIdx.x < 128) sbd[threadIdx.x] = b_dec[threadIdx.x];
    __syncthreads();

    const int half = threadIdx.x >> 7;
    const int t = threadIdx.x & 127;

    for (int pair = blockIdx.x; pair < N_NODES / 2; pair += gridDim.x) {
        int n = pair * 2 + half;
        {
            float v = agg[(size_t)n * 128 + t] + sbg[t];
            sx1[half][t] = (v > 0.f) ? v : (__expf(v) - 1.f);
        }
        __syncthreads();
        if (t < 64) {
            float acc = sbe[t];
            for (int k = 0; k < 128; k += 4) {
                float4 xv = *(const float4*)&sx1[half][k];
                acc = fmaf(xv.x, sWe[(k + 0) * 64 + t], acc);
                acc = fmaf(xv.y, sWe[(k + 1) * 64 + t], acc);
                acc = fmaf(xv.z, sWe[(k + 2) * 64 + t], acc);
                acc = fmaf(xv.w, sWe[(k + 3) * 64 + t], acc);
            }
            senc[half][t] = acc;
        }
        __syncthreads();
        {
            float acc = sbd[t];
            for (int k = 0; k < 64; k += 4) {
                float4 xv = *(const float4*)&senc[half][k];
                acc = fmaf(xv.x, sWd[(k + 0) * 128 + t], acc);
                acc = fmaf(xv.y, sWd[(k + 1) * 128 + t], acc);
                acc = fmaf(xv.z, sWd[(k + 2) * 128 + t], acc);
                acc = fmaf(xv.w, sWd[(k + 3) * 128 + t], acc);
            }
            float v = (acc > 0.f) ? acc : (__expf(acc) - 1.f);
            x2g[(size_t)n * 128 + t] = v;
        }
        __syncthreads();
    }
}

// ---------------- K4b: out = x2 @ W_out + b_out --------------------------
__global__ __launch_bounds__(256) void k_mlp2(const float* __restrict__ x2g,
        const float* __restrict__ W_out, const float* __restrict__ b_out,
        float* __restrict__ out) {
    __shared__ float sW[128 * 128];
    __shared__ float sb[128];
    __shared__ float sx[2][128];

    for (int i = threadIdx.x; i < 128 * 128; i += 256) sW[i] = W_out[i];
    if (threadIdx.x < 128) sb[threadIdx.x] = b_out[threadIdx.x];
    __syncthreads();

    const int half = threadIdx.x >> 7;
    const int t = threadIdx.x & 127;

    for (int pair = blockIdx.x; pair < N_NODES / 2; pair += gridDim.x) {
        int n = pair * 2 + half;
        sx[half][t] = x2g[(size_t)n * 128 + t];
        __syncthreads();
        float acc = sb[t];
        for (int k = 0; k < 128; k += 4) {
            float4 xv = *(const float4*)&sx[half][k];
            acc = fmaf(xv.x, sW[(k + 0) * 128 + t], acc);
            acc = fmaf(xv.y, sW[(k + 1) * 128 + t], acc);
            acc = fmaf(xv.z, sW[(k + 2) * 128 + t], acc);
            acc = fmaf(xv.w, sW[(k + 3) * 128 + t], acc);
        }
        out[(size_t)n * 128 + t] = acc;
        __syncthreads();
    }
}

extern "C" void kernel_launch(void* const* d_in, const int* in_sizes, int n_in,
                              void* d_out, int out_size, void* d_ws, size_t ws_size,
                              hipStream_t stream) {
    const float* x       = (const float*)d_in[0];
    const void*  e_raw   = d_in[1];
    const float* W_gat   = (const float*)d_in[2];
    const float* b_gat   = (const float*)d_in[3];
    const float* att_src = (const float*)d_in[4];
    const float* att_dst = (const float*)d_in[5];
    const float* W_enc   = (const float*)d_in[6];
    const float* b_enc   = (const float*)d_in[7];
    const float* W_dec   = (const float*)d_in[8];
    const float* b_dec   = (const float*)d_in[9];
    const float* W_out   = (const float*)d_in[10];
    const float* b_out   = (const float*)d_in[11];
    float* out = (float*)d_out;

    // workspace layout
    float* ws      = (float*)d_ws;
    float* h       = ws;                       // 6,400,000 f
    float* a_src   = h + 6400000;              // 200,000 f
    float* a_dst   = a_src + 200000;           // 200,000 f
    float* agg     = a_dst + 200000;           // 6,400,000 f
    int*   edges   = (int*)(agg + 6400000);    // 1,600,000 i
    int*   cnt     = edges + 1600000;          // 50,000 i
    int*   off     = cnt + 50000;              // 50,001 i
    int*   cursor  = off + 50001;              // 50,001 i
    int*   csr_src = cursor + 50001;           // 800,000 i
    int*   flag    = csr_src + 800000;         // 1 i
    float* x2g     = h;                        // reuse h after gather

    k_detect<<<1, 256, 0, stream>>>((const unsigned*)e_raw, flag);
    k_repack<<<(2 * N_EDGES + 255) / 256, 256, 0, stream>>>(e_raw, flag, edges);

    k_gat_lin<<<N_NODES / 8, 128, 0, stream>>>(x, W_gat, att_src, att_dst, h, a_src, a_dst);

    hipMemsetAsync(cnt, 0, 50000 * sizeof(int), stream);
    k_hist<<<(N_EDGES + 255) / 256, 256, 0, stream>>>(edges, cnt);
    k_scan<<<1, 256, 0, stream>>>(cnt, off, cursor);
    k_fill<<<(N_EDGES + 255) / 256, 256, 0, stream>>>(edges, cursor, csr_src);

    k_gather<<<(N_NODES + 3) / 4, 256, 0, stream>>>(off, csr_src, a_src, a_dst, h, agg);

    k_mlp1<<<512, 256, 0, stream>>>(agg, b_gat, W_enc, b_enc, W_dec, b_dec, x2g);
    k_mlp2<<<512, 256, 0, stream>>>(x2g, W_out, b_out, out);
}

// Round 3
// 499.200 us; speedup vs baseline: 2.4492x; 1.3168x over previous
//
#include <hip/hip_runtime.h>
#include <hip/hip_bf16.h>

#define N_NODES 50000
#define N_EDGES 800000
#define BM 64

__device__ __forceinline__ float elu_f(float v) {
    return (v > 0.f) ? v : (__expf(v) - 1.f);
}

// ---------------- edge-index dtype detection + repack ----------------
__global__ void k_detect(const unsigned* __restrict__ e_raw, int* __restrict__ flag) {
    __shared__ int nz;
    if (threadIdx.x == 0) nz = 0;
    __syncthreads();
    int cnt = 0;
    for (int i = threadIdx.x; i < 2048; i += 256)
        if (e_raw[2 * i + 1] != 0u) cnt = 1;
    if (cnt) atomicOr(&nz, 1);
    __syncthreads();
    if (threadIdx.x == 0) *flag = (nz == 0) ? 1 : 0;   // 1 == int64 layout
}

__global__ __launch_bounds__(256) void k_repack(const void* __restrict__ e_raw,
        const int* __restrict__ flag, int* __restrict__ edges) {
    int i = blockIdx.x * 256 + threadIdx.x;
    if (i >= 2 * N_EDGES) return;
    if (*flag) edges[i] = (int)((const long long*)e_raw)[i];
    else       edges[i] = ((const int*)e_raw)[i];
}

// ---------------- K1: h = x @ W_gat ; a_src/a_dst head dots --------------
// BM=64 rows/block, 256 threads, each thread 8 rows x 4 cols. K=128.
__global__ __launch_bounds__(256) void k_gat_lin(const float* __restrict__ x,
        const float* __restrict__ W, const float* __restrict__ att_s,
        const float* __restrict__ att_d, float* __restrict__ h,
        float* __restrict__ a_src, float* __restrict__ a_dst) {
    __shared__ float sx[BM][128];   // 32 KB
    const int m0 = blockIdx.x * BM;
    const int tid = threadIdx.x;

    for (int i = tid; i < BM * 32; i += 256) {
        int r = i >> 5, c4 = i & 31;
        int row = m0 + r; if (row >= N_NODES) row = N_NODES - 1;
        *(float4*)&sx[r][c4 * 4] = ((const float4*)(x + (size_t)row * 128))[c4];
    }
    __syncthreads();

    const int c0 = (tid & 31) * 4;
    const int r0 = (tid >> 5) * 8;
    float acc[8][4];
#pragma unroll
    for (int r = 0; r < 8; r++)
#pragma unroll
        for (int c = 0; c < 4; c++) acc[r][c] = 0.f;

    for (int k = 0; k < 128; k += 4) {
        float4 w0 = *(const float4*)&W[(k + 0) * 128 + c0];
        float4 w1 = *(const float4*)&W[(k + 1) * 128 + c0];
        float4 w2 = *(const float4*)&W[(k + 2) * 128 + c0];
        float4 w3 = *(const float4*)&W[(k + 3) * 128 + c0];
#pragma unroll
        for (int r = 0; r < 8; r++) {
            float4 xv = *(const float4*)&sx[r0 + r][k];
            acc[r][0] = fmaf(xv.x, w0.x, acc[r][0]);
            acc[r][0] = fmaf(xv.y, w1.x, acc[r][0]);
            acc[r][0] = fmaf(xv.z, w2.x, acc[r][0]);
            acc[r][0] = fmaf(xv.w, w3.x, acc[r][0]);
            acc[r][1] = fmaf(xv.x, w0.y, acc[r][1]);
            acc[r][1] = fmaf(xv.y, w1.y, acc[r][1]);
            acc[r][1] = fmaf(xv.z, w2.y, acc[r][1]);
            acc[r][1] = fmaf(xv.w, w3.y, acc[r][1]);
            acc[r][2] = fmaf(xv.x, w0.z, acc[r][2]);
            acc[r][2] = fmaf(xv.y, w1.z, acc[r][2]);
            acc[r][2] = fmaf(xv.z, w2.z, acc[r][2]);
            acc[r][2] = fmaf(xv.w, w3.z, acc[r][2]);
            acc[r][3] = fmaf(xv.x, w0.w, acc[r][3]);
            acc[r][3] = fmaf(xv.y, w1.w, acc[r][3]);
            acc[r][3] = fmaf(xv.z, w2.w, acc[r][3]);
            acc[r][3] = fmaf(xv.w, w3.w, acc[r][3]);
        }
    }

    // att vectors for this thread's 4 cols (flat idx == col; head = col>>5)
    float4 as4 = *(const float4*)&att_s[c0];
    float4 ad4 = *(const float4*)&att_d[c0];
    const int head = c0 >> 5;   // lanes (tid&31): 0-7 h0, 8-15 h1, 16-23 h2, 24-31 h3

#pragma unroll
    for (int r = 0; r < 8; r++) {
        int row = m0 + r0 + r;
        bool ok = row < N_NODES;
        if (ok) {
            float4 o; o.x = acc[r][0]; o.y = acc[r][1]; o.z = acc[r][2]; o.w = acc[r][3];
            *(float4*)&h[(size_t)row * 128 + c0] = o;
        }
        float vs = acc[r][0] * as4.x + acc[r][1] * as4.y + acc[r][2] * as4.z + acc[r][3] * as4.w;
        float vd = acc[r][0] * ad4.x + acc[r][1] * ad4.y + acc[r][2] * ad4.z + acc[r][3] * ad4.w;
#pragma unroll
        for (int o = 4; o >= 1; o >>= 1) {
            vs += __shfl_down(vs, o, 8);
            vd += __shfl_down(vd, o, 8);
        }
        if (ok && (tid & 7) == 0) {
            a_src[row * 4 + head] = vs;
            a_dst[row * 4 + head] = vd;
        }
    }
}

// ---------------- CSR build: histogram -> scan -> fill -------------------
__global__ __launch_bounds__(256) void k_hist(const int* __restrict__ edges,
        int* __restrict__ cnt) {
    int e = blockIdx.x * 256 + threadIdx.x;
    if (e >= N_EDGES) return;
    atomicAdd(&cnt[edges[N_EDGES + e]], 1);
}

__global__ __launch_bounds__(256) void k_scan(const int* __restrict__ cnt,
        int* __restrict__ off, int* __restrict__ cursor) {
    __shared__ int ssum[256];
    const int t = threadIdx.x;
    const int chunk = (N_NODES + 255) / 256;
    int lo = t * chunk;
    int hi = lo + chunk; if (hi > N_NODES) hi = N_NODES;
    if (lo > N_NODES) lo = N_NODES;
    int s = 0;
    for (int i = lo; i < hi; i++) s += cnt[i];
    ssum[t] = s;
    __syncthreads();
    for (int o = 1; o < 256; o <<= 1) {
        int v = (t >= o) ? ssum[t - o] : 0;
        __syncthreads();
        ssum[t] += v;
        __syncthreads();
    }
    int base = (t == 0) ? 0 : ssum[t - 1];
    for (int i = lo; i < hi; i++) {
        off[i] = base; cursor[i] = base;
        base += cnt[i];
    }
    if (t == 255) off[N_NODES] = base;
}

__global__ __launch_bounds__(256) void k_fill(const int* __restrict__ edges,
        int* __restrict__ cursor, int* __restrict__ csr_src) {
    int e = blockIdx.x * 256 + threadIdx.x;
    if (e >= N_EDGES) return;
    int s = edges[e], d = edges[N_EDGES + e];
    int pos = atomicAdd(&cursor[d], 1);
    csr_src[pos] = s;
}

// ---------------- K3: CSR gather — softmax + weighted aggregation --------
__global__ __launch_bounds__(256) void k_gather(const int* __restrict__ off,
        const int* __restrict__ csr_src, const float* __restrict__ a_src,
        const float* __restrict__ a_dst, const float* __restrict__ h,
        float* __restrict__ agg) {
    int d = blockIdx.x * 4 + (threadIdx.x >> 6);
    if (d >= N_NODES) return;
    const int lane = threadIdx.x & 63;
    const int hd = lane >> 4;
    const int lo = off[d], hi = off[d + 1];

    float4 ad = ((const float4*)a_dst)[d];

    float dx = 0.f, dy = 0.f, dz = 0.f, dw = 0.f;
    for (int i = lo + lane; i < hi; i += 64) {
        int s = csr_src[i];
        float4 as = ((const float4*)a_src)[s];
        float t;
        t = as.x + ad.x; t = t > 0.f ? t : 0.2f * t; dx += __expf(t);
        t = as.y + ad.y; t = t > 0.f ? t : 0.2f * t; dy += __expf(t);
        t = as.z + ad.z; t = t > 0.f ? t : 0.2f * t; dz += __expf(t);
        t = as.w + ad.w; t = t > 0.f ? t : 0.2f * t; dw += __expf(t);
    }
#pragma unroll
    for (int o = 32; o >= 1; o >>= 1) {
        dx += __shfl_down(dx, o); dy += __shfl_down(dy, o);
        dz += __shfl_down(dz, o); dw += __shfl_down(dw, o);
    }
    dx = __shfl(dx, 0); dy = __shfl(dy, 0);
    dz = __shfl(dz, 0); dw = __shfl(dw, 0);

    float4 asd = ((const float4*)a_src)[d];
    float t;
    t = asd.x + ad.x; t = t > 0.f ? t : 0.2f * t; float sx = __expf(t);
    t = asd.y + ad.y; t = t > 0.f ? t : 0.2f * t; float sy = __expf(t);
    t = asd.z + ad.z; t = t > 0.f ? t : 0.2f * t; float sz = __expf(t);
    t = asd.w + ad.w; t = t > 0.f ? t : 0.2f * t; float sw = __expf(t);
    dx += sx; dy += sy; dz += sz; dw += sw;

    float den = (hd == 0) ? dx : (hd == 1) ? dy : (hd == 2) ? dz : dw;
    float inv = 1.f / (den + 1e-16f);
    float selfe = (hd == 0) ? sx : (hd == 1) ? sy : (hd == 2) ? sz : sw;
    float adh = (hd == 0) ? ad.x : (hd == 1) ? ad.y : (hd == 2) ? ad.z : ad.w;

    float2 hself = ((const float2*)h)[(size_t)d * 64 + lane];
    float asf = selfe * inv;
    float accx = hself.x * asf, accy = hself.y * asf;

    for (int i = lo; i < hi; i++) {
        int s = csr_src[i];
        float av = a_src[s * 4 + hd];
        float tt = av + adh; tt = tt > 0.f ? tt : 0.2f * tt;
        float al = __expf(tt) * inv;
        float2 hv = ((const float2*)h)[(size_t)s * 64 + lane];
        accx = fmaf(hv.x, al, accx);
        accy = fmaf(hv.y, al, accy);
    }
    float2 o2; o2.x = accx; o2.y = accy;
    ((float2*)agg)[(size_t)d * 64 + lane] = o2;
}

// ---------------- K4a: x1=elu(agg+b_gat); enc; x2=elu(dec) ---------------
// BM=64 rows/block; stage2: 4x4 tile (N=64, K=128); stage3: 8x4 tile (N=128, K=64)
__global__ __launch_bounds__(256) void k_mlp1(const float* __restrict__ agg,
        const float* __restrict__ b_gat, const float* __restrict__ W_enc,
        const float* __restrict__ b_enc, const float* __restrict__ W_dec,
        const float* __restrict__ b_dec, float* __restrict__ x2g) {
    __shared__ float sx1[BM][132];    // padded: enc stage has 4 row-groups
    __shared__ float senc[BM][64];
    const int m0 = blockIdx.x * BM;
    const int tid = threadIdx.x;

    // stage 1: x1 = elu(agg + b_gat)
    for (int i = tid; i < BM * 32; i += 256) {
        int r = i >> 5, c4 = i & 31;
        int row = m0 + r; if (row >= N_NODES) row = N_NODES - 1;
        float4 v = ((const float4*)(agg + (size_t)row * 128))[c4];
        float4 bg = ((const float4*)b_gat)[c4];
        v.x = elu_f(v.x + bg.x); v.y = elu_f(v.y + bg.y);
        v.z = elu_f(v.z + bg.z); v.w = elu_f(v.w + bg.w);
        *(float4*)&sx1[r][c4 * 4] = v;
    }
    __syncthreads();

    // stage 2: enc = x1 @ W_enc + b_enc   [64x64], K=128
    {
        const int c0 = (tid & 15) * 4;
        const int r0 = (tid >> 4) * 4;
        float acc[4][4];
#pragma unroll
        for (int r = 0; r < 4; r++)
#pragma unroll
            for (int c = 0; c < 4; c++) acc[r][c] = 0.f;

        for (int k = 0; k < 128; k += 4) {
            float4 w0 = *(const float4*)&W_enc[(k + 0) * 64 + c0];
            float4 w1 = *(const float4*)&W_enc[(k + 1) * 64 + c0];
            float4 w2 = *(const float4*)&W_enc[(k + 2) * 64 + c0];
            float4 w3 = *(const float4*)&W_enc[(k + 3) * 64 + c0];
#pragma unroll
            for (int r = 0; r < 4; r++) {
                float4 xv = *(const float4*)&sx1[r0 + r][k];
                acc[r][0] = fmaf(xv.x, w0.x, acc[r][0]);
                acc[r][0] = fmaf(xv.y, w1.x, acc[r][0]);
                acc[r][0] = fmaf(xv.z, w2.x, acc[r][0]);
                acc[r][0] = fmaf(xv.w, w3.x, acc[r][0]);
                acc[r][1] = fmaf(xv.x, w0.y, acc[r][1]);
                acc[r][1] = fmaf(xv.y, w1.y, acc[r][1]);
                acc[r][1] = fmaf(xv.z, w2.y, acc[r][1]);
                acc[r][1] = fmaf(xv.w, w3.y, acc[r][1]);
                acc[r][2] = fmaf(xv.x, w0.z, acc[r][2]);
                acc[r][2] = fmaf(xv.y, w1.z, acc[r][2]);
                acc[r][2] = fmaf(xv.z, w2.z, acc[r][2]);
                acc[r][2] = fmaf(xv.w, w3.z, acc[r][2]);
                acc[r][3] = fmaf(xv.x, w0.w, acc[r][3]);
                acc[r][3] = fmaf(xv.y, w1.w, acc[r][3]);
                acc[r][3] = fmaf(xv.z, w2.w, acc[r][3]);
                acc[r][3] = fmaf(xv.w, w3.w, acc[r][3]);
            }
        }
        float4 be = *(const float4*)&b_enc[c0];
#pragma unroll
        for (int r = 0; r < 4; r++) {
            float4 o;
            o.x = acc[r][0] + be.x; o.y = acc[r][1] + be.y;
            o.z = acc[r][2] + be.z; o.w = acc[r][3] + be.w;
            *(float4*)&senc[r0 + r][c0] = o;
        }
    }
    __syncthreads();

    // stage 3: x2 = elu(enc @ W_dec + b_dec)   [64x128], K=64
    {
        const int c0 = (tid & 31) * 4;
        const int r0 = (tid >> 5) * 8;
        float acc[8][4];
#pragma unroll
        for (int r = 0; r < 8; r++)
#pragma unroll
            for (int c = 0; c < 4; c++) acc[r][c] = 0.f;

        for (int k = 0; k < 64; k += 4) {
            float4 w0 = *(const float4*)&W_dec[(k + 0) * 128 + c0];
            float4 w1 = *(const float4*)&W_dec[(k + 1) * 128 + c0];
            float4 w2 = *(const float4*)&W_dec[(k + 2) * 128 + c0];
            float4 w3 = *(const float4*)&W_dec[(k + 3) * 128 + c0];
#pragma unroll
            for (int r = 0; r < 8; r++) {
                float4 xv = *(const float4*)&senc[r0 + r][k];
                acc[r][0] = fmaf(xv.x, w0.x, acc[r][0]);
                acc[r][0] = fmaf(xv.y, w1.x, acc[r][0]);
                acc[r][0] = fmaf(xv.z, w2.x, acc[r][0]);
                acc[r][0] = fmaf(xv.w, w3.x, acc[r][0]);
                acc[r][1] = fmaf(xv.x, w0.y, acc[r][1]);
                acc[r][1] = fmaf(xv.y, w1.y, acc[r][1]);
                acc[r][1] = fmaf(xv.z, w2.y, acc[r][1]);
                acc[r][1] = fmaf(xv.w, w3.y, acc[r][1]);
                acc[r][2] = fmaf(xv.x, w0.z, acc[r][2]);
                acc[r][2] = fmaf(xv.y, w1.z, acc[r][2]);
                acc[r][2] = fmaf(xv.z, w2.z, acc[r][2]);
                acc[r][2] = fmaf(xv.w, w3.z, acc[r][2]);
                acc[r][3] = fmaf(xv.x, w0.w, acc[r][3]);
                acc[r][3] = fmaf(xv.y, w1.w, acc[r][3]);
                acc[r][3] = fmaf(xv.z, w2.w, acc[r][3]);
                acc[r][3] = fmaf(xv.w, w3.w, acc[r][3]);
            }
        }
        float4 bd = *(const float4*)&b_dec[c0];
#pragma unroll
        for (int r = 0; r < 8; r++) {
            int row = m0 + r0 + r;
            if (row < N_NODES) {
                float4 o;
                o.x = elu_f(acc[r][0] + bd.x); o.y = elu_f(acc[r][1] + bd.y);
                o.z = elu_f(acc[r][2] + bd.z); o.w = elu_f(acc[r][3] + bd.w);
                *(float4*)&x2g[(size_t)row * 128 + c0] = o;
            }
        }
    }
}

// ---------------- K4b: out = x2 @ W_out + b_out --------------------------
__global__ __launch_bounds__(256) void k_mlp2(const float* __restrict__ x2g,
        const float* __restrict__ W_out, const float* __restrict__ b_out,
        float* __restrict__ out) {
    __shared__ float sx[BM][128];
    const int m0 = blockIdx.x * BM;
    const int tid = threadIdx.x;

    for (int i = tid; i < BM * 32; i += 256) {
        int r = i >> 5, c4 = i & 31;
        int row = m0 + r; if (row >= N_NODES) row = N_NODES - 1;
        *(float4*)&sx[r][c4 * 4] = ((const float4*)(x2g + (size_t)row * 128))[c4];
    }
    __syncthreads();

    const int c0 = (tid & 31) * 4;
    const int r0 = (tid >> 5) * 8;
    float acc[8][4];
#pragma unroll
    for (int r = 0; r < 8; r++)
#pragma unroll
        for (int c = 0; c < 4; c++) acc[r][c] = 0.f;

    for (int k = 0; k < 128; k += 4) {
        float4 w0 = *(const float4*)&W_out[(k + 0) * 128 + c0];
        float4 w1 = *(const float4*)&W_out[(k + 1) * 128 + c0];
        float4 w2 = *(const float4*)&W_out[(k + 2) * 128 + c0];
        float4 w3 = *(const float4*)&W_out[(k + 3) * 128 + c0];
#pragma unroll
        for (int r = 0; r < 8; r++) {
            float4 xv = *(const float4*)&sx[r0 + r][k];
            acc[r][0] = fmaf(xv.x, w0.x, acc[r][0]);
            acc[r][0] = fmaf(xv.y, w1.x, acc[r][0]);
            acc[r][0] = fmaf(xv.z, w2.x, acc[r][0]);
            acc[r][0] = fmaf(xv.w, w3.x, acc[r][0]);
            acc[r][1] = fmaf(xv.x, w0.y, acc[r][1]);
            acc[r][1] = fmaf(xv.y, w1.y, acc[r][1]);
            acc[r][1] = fmaf(xv.z, w2.y, acc[r][1]);
            acc[r][1] = fmaf(xv.w, w3.y, acc[r][1]);
            acc[r][2] = fmaf(xv.x, w0.z, acc[r][2]);
            acc[r][2] = fmaf(xv.y, w1.z, acc[r][2]);
            acc[r][2] = fmaf(xv.z, w2.z, acc[r][2]);
            acc[r][2] = fmaf(xv.w, w3.z, acc[r][2]);
            acc[r][3] = fmaf(xv.x, w0.w, acc[r][3]);
            acc[r][3] = fmaf(xv.y, w1.w, acc[r][3]);
            acc[r][3] = fmaf(xv.z, w2.w, acc[r][3]);
            acc[r][3] = fmaf(xv.w, w3.w, acc[r][3]);
        }
    }
    float4 bo = *(const float4*)&b_out[c0];
#pragma unroll
    for (int r = 0; r < 8; r++) {
        int row = m0 + r0 + r;
        if (row < N_NODES) {
            float4 o;
            o.x = acc[r][0] + bo.x; o.y = acc[r][1] + bo.y;
            o.z = acc[r][2] + bo.z; o.w = acc[r][3] + bo.w;
            *(float4*)&out[(size_t)row * 128 + c0] = o;
        }
    }
}

extern "C" void kernel_launch(void* const* d_in, const int* in_sizes, int n_in,
                              void* d_out, int out_size, void* d_ws, size_t ws_size,
                              hipStream_t stream) {
    const float* x       = (const float*)d_in[0];
    const void*  e_raw   = d_in[1];
    const float* W_gat   = (const float*)d_in[2];
    const float* b_gat   = (const float*)d_in[3];
    const float* att_src = (const float*)d_in[4];
    const float* att_dst = (const float*)d_in[5];
    const float* W_enc   = (const float*)d_in[6];
    const float* b_enc   = (const float*)d_in[7];
    const float* W_dec   = (const float*)d_in[8];
    const float* b_dec   = (const float*)d_in[9];
    const float* W_out   = (const float*)d_in[10];
    const float* b_out   = (const float*)d_in[11];
    float* out = (float*)d_out;

    float* ws      = (float*)d_ws;
    float* h       = ws;                       // 6,400,000 f
    float* a_src   = h + 6400000;              // 200,000 f
    float* a_dst   = a_src + 200000;           // 200,000 f
    float* agg     = a_dst + 200000;           // 6,400,000 f
    int*   edges   = (int*)(agg + 6400000);    // 1,600,000 i
    int*   cnt     = edges + 1600000;          // 50,000 i
    int*   off     = cnt + 50000;              // 50,001 i
    int*   cursor  = off + 50001;              // 50,001 i
    int*   csr_src = cursor + 50001;           // 800,000 i
    int*   flag    = csr_src + 800000;         // 1 i
    float* x2g     = h;                        // reuse h after gather

    const int GBLK = (N_NODES + BM - 1) / BM;  // 782

    k_detect<<<1, 256, 0, stream>>>((const unsigned*)e_raw, flag);
    k_repack<<<(2 * N_EDGES + 255) / 256, 256, 0, stream>>>(e_raw, flag, edges);

    k_gat_lin<<<GBLK, 256, 0, stream>>>(x, W_gat, att_src, att_dst, h, a_src, a_dst);

    hipMemsetAsync(cnt, 0, 50000 * sizeof(int), stream);
    k_hist<<<(N_EDGES + 255) / 256, 256, 0, stream>>>(edges, cnt);
    k_scan<<<1, 256, 0, stream>>>(cnt, off, cursor);
    k_fill<<<(N_EDGES + 255) / 256, 256, 0, stream>>>(edges, cursor, csr_src);

    k_gather<<<(N_NODES + 3) / 4, 256, 0, stream>>>(off, csr_src, a_src, a_dst, h, agg);

    k_mlp1<<<GBLK, 256, 0, stream>>>(agg, b_gat, W_enc, b_enc, W_dec, b_dec, x2g);
    k_mlp2<<<GBLK, 256, 0, stream>>>(x2g, W_out, b_out, out);
}

// Round 4
// 394.375 us; speedup vs baseline: 3.1002x; 1.2658x over previous
//
#include <hip/hip_runtime.h>
#include <hip/hip_bf16.h>

#define N_NODES 50000
#define N_EDGES 800000
#define BM 64
#define SCAN_NB ((N_NODES + 255) / 256)   // 196

__device__ __forceinline__ float elu_f(float v) {
    return (v > 0.f) ? v : (__expf(v) - 1.f);
}

// ---------------- edge-index dtype detection + repack ----------------
__global__ void k_detect(const unsigned* __restrict__ e_raw, int* __restrict__ flag) {
    __shared__ int nz;
    if (threadIdx.x == 0) nz = 0;
    __syncthreads();
    int cnt = 0;
    for (int i = threadIdx.x; i < 2048; i += 256)
        if (e_raw[2 * i + 1] != 0u) cnt = 1;
    if (cnt) atomicOr(&nz, 1);
    __syncthreads();
    if (threadIdx.x == 0) *flag = (nz == 0) ? 1 : 0;   // 1 == int64 layout
}

__global__ __launch_bounds__(256) void k_repack(const void* __restrict__ e_raw,
        const int* __restrict__ flag, int* __restrict__ edges) {
    int i = blockIdx.x * 256 + threadIdx.x;
    if (i >= 2 * N_EDGES) return;
    if (*flag) edges[i] = (int)((const long long*)e_raw)[i];
    else       edges[i] = ((const int*)e_raw)[i];
}

// ---------------- K1: h = x @ W_gat ; a_src/a_dst head dots --------------
__global__ __launch_bounds__(256) void k_gat_lin(const float* __restrict__ x,
        const float* __restrict__ W, const float* __restrict__ att_s,
        const float* __restrict__ att_d, float* __restrict__ h,
        float* __restrict__ a_src, float* __restrict__ a_dst) {
    __shared__ float sx[BM][128];   // 32 KB
    const int m0 = blockIdx.x * BM;
    const int tid = threadIdx.x;

    for (int i = tid; i < BM * 32; i += 256) {
        int r = i >> 5, c4 = i & 31;
        int row = m0 + r; if (row >= N_NODES) row = N_NODES - 1;
        *(float4*)&sx[r][c4 * 4] = ((const float4*)(x + (size_t)row * 128))[c4];
    }
    __syncthreads();

    const int c0 = (tid & 31) * 4;
    const int r0 = (tid >> 5) * 8;
    float acc[8][4];
#pragma unroll
    for (int r = 0; r < 8; r++)
#pragma unroll
        for (int c = 0; c < 4; c++) acc[r][c] = 0.f;

    for (int k = 0; k < 128; k += 4) {
        float4 w0 = *(const float4*)&W[(k + 0) * 128 + c0];
        float4 w1 = *(const float4*)&W[(k + 1) * 128 + c0];
        float4 w2 = *(const float4*)&W[(k + 2) * 128 + c0];
        float4 w3 = *(const float4*)&W[(k + 3) * 128 + c0];
#pragma unroll
        for (int r = 0; r < 8; r++) {
            float4 xv = *(const float4*)&sx[r0 + r][k];
            acc[r][0] = fmaf(xv.x, w0.x, acc[r][0]);
            acc[r][0] = fmaf(xv.y, w1.x, acc[r][0]);
            acc[r][0] = fmaf(xv.z, w2.x, acc[r][0]);
            acc[r][0] = fmaf(xv.w, w3.x, acc[r][0]);
            acc[r][1] = fmaf(xv.x, w0.y, acc[r][1]);
            acc[r][1] = fmaf(xv.y, w1.y, acc[r][1]);
            acc[r][1] = fmaf(xv.z, w2.y, acc[r][1]);
            acc[r][1] = fmaf(xv.w, w3.y, acc[r][1]);
            acc[r][2] = fmaf(xv.x, w0.z, acc[r][2]);
            acc[r][2] = fmaf(xv.y, w1.z, acc[r][2]);
            acc[r][2] = fmaf(xv.z, w2.z, acc[r][2]);
            acc[r][2] = fmaf(xv.w, w3.z, acc[r][2]);
            acc[r][3] = fmaf(xv.x, w0.w, acc[r][3]);
            acc[r][3] = fmaf(xv.y, w1.w, acc[r][3]);
            acc[r][3] = fmaf(xv.z, w2.w, acc[r][3]);
            acc[r][3] = fmaf(xv.w, w3.w, acc[r][3]);
        }
    }

    float4 as4 = *(const float4*)&att_s[c0];
    float4 ad4 = *(const float4*)&att_d[c0];
    const int head = c0 >> 5;

#pragma unroll
    for (int r = 0; r < 8; r++) {
        int row = m0 + r0 + r;
        bool ok = row < N_NODES;
        if (ok) {
            float4 o; o.x = acc[r][0]; o.y = acc[r][1]; o.z = acc[r][2]; o.w = acc[r][3];
            *(float4*)&h[(size_t)row * 128 + c0] = o;
        }
        float vs = acc[r][0] * as4.x + acc[r][1] * as4.y + acc[r][2] * as4.z + acc[r][3] * as4.w;
        float vd = acc[r][0] * ad4.x + acc[r][1] * ad4.y + acc[r][2] * ad4.z + acc[r][3] * ad4.w;
#pragma unroll
        for (int o = 4; o >= 1; o >>= 1) {
            vs += __shfl_down(vs, o, 8);
            vd += __shfl_down(vd, o, 8);
        }
        if (ok && (tid & 7) == 0) {
            a_src[row * 4 + head] = vs;
            a_dst[row * 4 + head] = vd;
        }
    }
}

// ---------------- CSR build: histogram -> hierarchical scan -> fill ------
__global__ __launch_bounds__(256) void k_hist(const int* __restrict__ edges,
        int* __restrict__ cnt) {
    int e = blockIdx.x * 256 + threadIdx.x;
    if (e >= N_EDGES) return;
    atomicAdd(&cnt[edges[N_EDGES + e]], 1);
}

// per-block reduction of 256 counters
__global__ __launch_bounds__(256) void k_scan1(const int* __restrict__ cnt,
        int* __restrict__ bsum) {
    __shared__ int s[256];
    const int t = threadIdx.x;
    int i = blockIdx.x * 256 + t;
    s[t] = (i < N_NODES) ? cnt[i] : 0;
    __syncthreads();
    for (int o = 128; o >= 1; o >>= 1) {
        if (t < o) s[t] += s[t + o];
        __syncthreads();
    }
    if (t == 0) bsum[blockIdx.x] = s[0];
}

// single block: exclusive scan of SCAN_NB block sums
__global__ __launch_bounds__(256) void k_scan2(const int* __restrict__ bsum,
        int* __restrict__ boff) {
    __shared__ int s[256];
    const int t = threadIdx.x;
    int v = (t < SCAN_NB) ? bsum[t] : 0;
    s[t] = v;
    __syncthreads();
    for (int o = 1; o < 256; o <<= 1) {
        int u = (t >= o) ? s[t - o] : 0;
        __syncthreads();
        s[t] += u;
        __syncthreads();
    }
    if (t < SCAN_NB) boff[t] = s[t] - v;   // exclusive
}

// per-block inclusive scan + block offset -> off, cursor
__global__ __launch_bounds__(256) void k_scan3(const int* __restrict__ cnt,
        const int* __restrict__ boff, int* __restrict__ off,
        int* __restrict__ cursor) {
    __shared__ int s[256];
    const int t = threadIdx.x;
    int i = blockIdx.x * 256 + t;
    int v = (i < N_NODES) ? cnt[i] : 0;
    s[t] = v;
    __syncthreads();
    for (int o = 1; o < 256; o <<= 1) {
        int u = (t >= o) ? s[t - o] : 0;
        __syncthreads();
        s[t] += u;
        __syncthreads();
    }
    int ex = boff[blockIdx.x] + s[t] - v;
    if (i < N_NODES) { off[i] = ex; cursor[i] = ex; }
    if (i == 0) off[N_NODES] = N_EDGES;
}

__global__ __launch_bounds__(256) void k_fill(const int* __restrict__ edges,
        int* __restrict__ cursor, int* __restrict__ csr_src) {
    int e = blockIdx.x * 256 + threadIdx.x;
    if (e >= N_EDGES) return;
    int s = edges[e], d = edges[N_EDGES + e];
    int pos = atomicAdd(&cursor[d], 1);
    csr_src[pos] = s;
}

// ---------------- K3: CSR gather — softmax + weighted aggregation --------
__global__ __launch_bounds__(256) void k_gather(const int* __restrict__ off,
        const int* __restrict__ csr_src, const float* __restrict__ a_src,
        const float* __restrict__ a_dst, const float* __restrict__ h,
        float* __restrict__ agg) {
    int d = blockIdx.x * 4 + (threadIdx.x >> 6);
    if (d >= N_NODES) return;
    const int lane = threadIdx.x & 63;
    const int hd = lane >> 4;
    const int lo = off[d], hi = off[d + 1];

    float4 ad = ((const float4*)a_dst)[d];

    float dx = 0.f, dy = 0.f, dz = 0.f, dw = 0.f;
    for (int i = lo + lane; i < hi; i += 64) {
        int s = csr_src[i];
        float4 as = ((const float4*)a_src)[s];
        float t;
        t = as.x + ad.x; t = t > 0.f ? t : 0.2f * t; dx += __expf(t);
        t = as.y + ad.y; t = t > 0.f ? t : 0.2f * t; dy += __expf(t);
        t = as.z + ad.z; t = t > 0.f ? t : 0.2f * t; dz += __expf(t);
        t = as.w + ad.w; t = t > 0.f ? t : 0.2f * t; dw += __expf(t);
    }
#pragma unroll
    for (int o = 32; o >= 1; o >>= 1) {
        dx += __shfl_down(dx, o); dy += __shfl_down(dy, o);
        dz += __shfl_down(dz, o); dw += __shfl_down(dw, o);
    }
    dx = __shfl(dx, 0); dy = __shfl(dy, 0);
    dz = __shfl(dz, 0); dw = __shfl(dw, 0);

    float4 asd = ((const float4*)a_src)[d];
    float t;
    t = asd.x + ad.x; t = t > 0.f ? t : 0.2f * t; float sx = __expf(t);
    t = asd.y + ad.y; t = t > 0.f ? t : 0.2f * t; float sy = __expf(t);
    t = asd.z + ad.z; t = t > 0.f ? t : 0.2f * t; float sz = __expf(t);
    t = asd.w + ad.w; t = t > 0.f ? t : 0.2f * t; float sw = __expf(t);
    dx += sx; dy += sy; dz += sz; dw += sw;

    float den = (hd == 0) ? dx : (hd == 1) ? dy : (hd == 2) ? dz : dw;
    float inv = 1.f / (den + 1e-16f);
    float selfe = (hd == 0) ? sx : (hd == 1) ? sy : (hd == 2) ? sz : sw;
    float adh = (hd == 0) ? ad.x : (hd == 1) ? ad.y : (hd == 2) ? ad.z : ad.w;

    float2 hself = ((const float2*)h)[(size_t)d * 64 + lane];
    float asf = selfe * inv;
    float accx = hself.x * asf, accy = hself.y * asf;

    for (int i = lo; i < hi; i++) {
        int s = csr_src[i];
        float av = a_src[s * 4 + hd];
        float tt = av + adh; tt = tt > 0.f ? tt : 0.2f * tt;
        float al = __expf(tt) * inv;
        float2 hv = ((const float2*)h)[(size_t)s * 64 + lane];
        accx = fmaf(hv.x, al, accx);
        accy = fmaf(hv.y, al, accy);
    }
    float2 o2; o2.x = accx; o2.y = accy;
    ((float2*)agg)[(size_t)d * 64 + lane] = o2;
}

// ---------------- K4a: x1=elu(agg+b_gat); enc; x2=elu(dec) ---------------
__global__ __launch_bounds__(256) void k_mlp1(const float* __restrict__ agg,
        const float* __restrict__ b_gat, const float* __restrict__ W_enc,
        const float* __restrict__ b_enc, const float* __restrict__ W_dec,
        const float* __restrict__ b_dec, float* __restrict__ x2g) {
    __shared__ float sx1[BM][132];
    __shared__ float senc[BM][64];
    const int m0 = blockIdx.x * BM;
    const int tid = threadIdx.x;

    for (int i = tid; i < BM * 32; i += 256) {
        int r = i >> 5, c4 = i & 31;
        int row = m0 + r; if (row >= N_NODES) row = N_NODES - 1;
        float4 v = ((const float4*)(agg + (size_t)row * 128))[c4];
        float4 bg = ((const float4*)b_gat)[c4];
        v.x = elu_f(v.x + bg.x); v.y = elu_f(v.y + bg.y);
        v.z = elu_f(v.z + bg.z); v.w = elu_f(v.w + bg.w);
        *(float4*)&sx1[r][c4 * 4] = v;
    }
    __syncthreads();

    {
        const int c0 = (tid & 15) * 4;
        const int r0 = (tid >> 4) * 4;
        float acc[4][4];
#pragma unroll
        for (int r = 0; r < 4; r++)
#pragma unroll
            for (int c = 0; c < 4; c++) acc[r][c] = 0.f;

        for (int k = 0; k < 128; k += 4) {
            float4 w0 = *(const float4*)&W_enc[(k + 0) * 64 + c0];
            float4 w1 = *(const float4*)&W_enc[(k + 1) * 64 + c0];
            float4 w2 = *(const float4*)&W_enc[(k + 2) * 64 + c0];
            float4 w3 = *(const float4*)&W_enc[(k + 3) * 64 + c0];
#pragma unroll
            for (int r = 0; r < 4; r++) {
                float4 xv = *(const float4*)&sx1[r0 + r][k];
                acc[r][0] = fmaf(xv.x, w0.x, acc[r][0]);
                acc[r][0] = fmaf(xv.y, w1.x, acc[r][0]);
                acc[r][0] = fmaf(xv.z, w2.x, acc[r][0]);
                acc[r][0] = fmaf(xv.w, w3.x, acc[r][0]);
                acc[r][1] = fmaf(xv.x, w0.y, acc[r][1]);
                acc[r][1] = fmaf(xv.y, w1.y, acc[r][1]);
                acc[r][1] = fmaf(xv.z, w2.y, acc[r][1]);
                acc[r][1] = fmaf(xv.w, w3.y, acc[r][1]);
                acc[r][2] = fmaf(xv.x, w0.z, acc[r][2]);
                acc[r][2] = fmaf(xv.y, w1.z, acc[r][2]);
                acc[r][2] = fmaf(xv.z, w2.z, acc[r][2]);
                acc[r][2] = fmaf(xv.w, w3.z, acc[r][2]);
                acc[r][3] = fmaf(xv.x, w0.w, acc[r][3]);
                acc[r][3] = fmaf(xv.y, w1.w, acc[r][3]);
                acc[r][3] = fmaf(xv.z, w2.w, acc[r][3]);
                acc[r][3] = fmaf(xv.w, w3.w, acc[r][3]);
            }
        }
        float4 be = *(const float4*)&b_enc[c0];
#pragma unroll
        for (int r = 0; r < 4; r++) {
            float4 o;
            o.x = acc[r][0] + be.x; o.y = acc[r][1] + be.y;
            o.z = acc[r][2] + be.z; o.w = acc[r][3] + be.w;
            *(float4*)&senc[r0 + r][c0] = o;
        }
    }
    __syncthreads();

    {
        const int c0 = (tid & 31) * 4;
        const int r0 = (tid >> 5) * 8;
        float acc[8][4];
#pragma unroll
        for (int r = 0; r < 8; r++)
#pragma unroll
            for (int c = 0; c < 4; c++) acc[r][c] = 0.f;

        for (int k = 0; k < 64; k += 4) {
            float4 w0 = *(const float4*)&W_dec[(k + 0) * 128 + c0];
            float4 w1 = *(const float4*)&W_dec[(k + 1) * 128 + c0];
            float4 w2 = *(const float4*)&W_dec[(k + 2) * 128 + c0];
            float4 w3 = *(const float4*)&W_dec[(k + 3) * 128 + c0];
#pragma unroll
            for (int r = 0; r < 8; r++) {
                float4 xv = *(const float4*)&senc[r0 + r][k];
                acc[r][0] = fmaf(xv.x, w0.x, acc[r][0]);
                acc[r][0] = fmaf(xv.y, w1.x, acc[r][0]);
                acc[r][0] = fmaf(xv.z, w2.x, acc[r][0]);
                acc[r][0] = fmaf(xv.w, w3.x, acc[r][0]);
                acc[r][1] = fmaf(xv.x, w0.y, acc[r][1]);
                acc[r][1] = fmaf(xv.y, w1.y, acc[r][1]);
                acc[r][1] = fmaf(xv.z, w2.y, acc[r][1]);
                acc[r][1] = fmaf(xv.w, w3.y, acc[r][1]);
                acc[r][2] = fmaf(xv.x, w0.z, acc[r][2]);
                acc[r][2] = fmaf(xv.y, w1.z, acc[r][2]);
                acc[r][2] = fmaf(xv.z, w2.z, acc[r][2]);
                acc[r][2] = fmaf(xv.w, w3.z, acc[r][2]);
                acc[r][3] = fmaf(xv.x, w0.w, acc[r][3]);
                acc[r][3] = fmaf(xv.y, w1.w, acc[r][3]);
                acc[r][3] = fmaf(xv.z, w2.w, acc[r][3]);
                acc[r][3] = fmaf(xv.w, w3.w, acc[r][3]);
            }
        }
        float4 bd = *(const float4*)&b_dec[c0];
#pragma unroll
        for (int r = 0; r < 8; r++) {
            int row = m0 + r0 + r;
            if (row < N_NODES) {
                float4 o;
                o.x = elu_f(acc[r][0] + bd.x); o.y = elu_f(acc[r][1] + bd.y);
                o.z = elu_f(acc[r][2] + bd.z); o.w = elu_f(acc[r][3] + bd.w);
                *(float4*)&x2g[(size_t)row * 128 + c0] = o;
            }
        }
    }
}

// ---------------- K4b: out = x2 @ W_out + b_out --------------------------
__global__ __launch_bounds__(256) void k_mlp2(const float* __restrict__ x2g,
        const float* __restrict__ W_out, const float* __restrict__ b_out,
        float* __restrict__ out) {
    __shared__ float sx[BM][128];
    const int m0 = blockIdx.x * BM;
    const int tid = threadIdx.x;

    for (int i = tid; i < BM * 32; i += 256) {
        int r = i >> 5, c4 = i & 31;
        int row = m0 + r; if (row >= N_NODES) row = N_NODES - 1;
        *(float4*)&sx[r][c4 * 4] = ((const float4*)(x2g + (size_t)row * 128))[c4];
    }
    __syncthreads();

    const int c0 = (tid & 31) * 4;
    const int r0 = (tid >> 5) * 8;
    float acc[8][4];
#pragma unroll
    for (int r = 0; r < 8; r++)
#pragma unroll
        for (int c = 0; c < 4; c++) acc[r][c] = 0.f;

    for (int k = 0; k < 128; k += 4) {
        float4 w0 = *(const float4*)&W_out[(k + 0) * 128 + c0];
        float4 w1 = *(const float4*)&W_out[(k + 1) * 128 + c0];
        float4 w2 = *(const float4*)&W_out[(k + 2) * 128 + c0];
        float4 w3 = *(const float4*)&W_out[(k + 3) * 128 + c0];
#pragma unroll
        for (int r = 0; r < 8; r++) {
            float4 xv = *(const float4*)&sx[r0 + r][k];
            acc[r][0] = fmaf(xv.x, w0.x, acc[r][0]);
            acc[r][0] = fmaf(xv.y, w1.x, acc[r][0]);
            acc[r][0] = fmaf(xv.z, w2.x, acc[r][0]);
            acc[r][0] = fmaf(xv.w, w3.x, acc[r][0]);
            acc[r][1] = fmaf(xv.x, w0.y, acc[r][1]);
            acc[r][1] = fmaf(xv.y, w1.y, acc[r][1]);
            acc[r][1] = fmaf(xv.z, w2.y, acc[r][1]);
            acc[r][1] = fmaf(xv.w, w3.y, acc[r][1]);
            acc[r][2] = fmaf(xv.x, w0.z, acc[r][2]);
            acc[r][2] = fmaf(xv.y, w1.z, acc[r][2]);
            acc[r][2] = fmaf(xv.z, w2.z, acc[r][2]);
            acc[r][2] = fmaf(xv.w, w3.z, acc[r][2]);
            acc[r][3] = fmaf(xv.x, w0.w, acc[r][3]);
            acc[r][3] = fmaf(xv.y, w1.w, acc[r][3]);
            acc[r][3] = fmaf(xv.z, w2.w, acc[r][3]);
            acc[r][3] = fmaf(xv.w, w3.w, acc[r][3]);
        }
    }
    float4 bo = *(const float4*)&b_out[c0];
#pragma unroll
    for (int r = 0; r < 8; r++) {
        int row = m0 + r0 + r;
        if (row < N_NODES) {
            float4 o;
            o.x = acc[r][0] + bo.x; o.y = acc[r][1] + bo.y;
            o.z = acc[r][2] + bo.z; o.w = acc[r][3] + bo.w;
            *(float4*)&out[(size_t)row * 128 + c0] = o;
        }
    }
}

extern "C" void kernel_launch(void* const* d_in, const int* in_sizes, int n_in,
                              void* d_out, int out_size, void* d_ws, size_t ws_size,
                              hipStream_t stream) {
    const float* x       = (const float*)d_in[0];
    const void*  e_raw   = d_in[1];
    const float* W_gat   = (const float*)d_in[2];
    const float* b_gat   = (const float*)d_in[3];
    const float* att_src = (const float*)d_in[4];
    const float* att_dst = (const float*)d_in[5];
    const float* W_enc   = (const float*)d_in[6];
    const float* b_enc   = (const float*)d_in[7];
    const float* W_dec   = (const float*)d_in[8];
    const float* b_dec   = (const float*)d_in[9];
    const float* W_out   = (const float*)d_in[10];
    const float* b_out   = (const float*)d_in[11];
    float* out = (float*)d_out;

    float* ws      = (float*)d_ws;
    float* h       = ws;                       // 6,400,000 f
    float* a_src   = h + 6400000;              // 200,000 f
    float* a_dst   = a_src + 200000;           // 200,000 f
    float* agg     = a_dst + 200000;           // 6,400,000 f
    int*   edges   = (int*)(agg + 6400000);    // 1,600,000 i
    int*   cnt     = edges + 1600000;          // 50,000 i
    int*   off     = cnt + 50000;              // 50,001 i
    int*   cursor  = off + 50001;              // 50,001 i
    int*   csr_src = cursor + 50001;           // 800,000 i
    int*   flag    = csr_src + 800000;         // 1 i
    int*   bsum    = flag + 1;                 // 196 i
    int*   boff    = bsum + SCAN_NB;           // 196 i
    float* x2g     = h;                        // reuse h after gather

    const int GBLK = (N_NODES + BM - 1) / BM;  // 782

    k_detect<<<1, 256, 0, stream>>>((const unsigned*)e_raw, flag);
    k_repack<<<(2 * N_EDGES + 255) / 256, 256, 0, stream>>>(e_raw, flag, edges);

    k_gat_lin<<<GBLK, 256, 0, stream>>>(x, W_gat, att_src, att_dst, h, a_src, a_dst);

    hipMemsetAsync(cnt, 0, 50000 * sizeof(int), stream);
    k_hist<<<(N_EDGES + 255) / 256, 256, 0, stream>>>(edges, cnt);
    k_scan1<<<SCAN_NB, 256, 0, stream>>>(cnt, bsum);
    k_scan2<<<1, 256, 0, stream>>>(bsum, boff);
    k_scan3<<<SCAN_NB, 256, 0, stream>>>(cnt, boff, off, cursor);
    k_fill<<<(N_EDGES + 255) / 256, 256, 0, stream>>>(edges, cursor, csr_src);

    k_gather<<<(N_NODES + 3) / 4, 256, 0, stream>>>(off, csr_src, a_src, a_dst, h, agg);

    k_mlp1<<<GBLK, 256, 0, stream>>>(agg, b_gat, W_enc, b_enc, W_dec, b_dec, x2g);
    k_mlp2<<<GBLK, 256, 0, stream>>>(x2g, W_out, b_out, out);
}

// Round 5
// 381.025 us; speedup vs baseline: 3.2088x; 1.0350x over previous
//
#include <hip/hip_runtime.h>
#include <hip/hip_bf16.h>

#define N_NODES 50000
#define N_EDGES 800000
#define BM 64
#define SCAN_NB ((N_NODES + 255) / 256)   // 196

__device__ __forceinline__ float elu_f(float v) {
    return (v > 0.f) ? v : (__expf(v) - 1.f);
}

// pack two fp32 -> packed bf16x2 (RNE)
__device__ __forceinline__ unsigned f2bf2(float a, float b) {
    unsigned ua = __float_as_uint(a), ub = __float_as_uint(b);
    ua = (ua + 0x7FFFu + ((ua >> 16) & 1u)) >> 16;
    ub = (ub + 0x7FFFu + ((ub >> 16) & 1u)) >> 16;
    return ua | (ub << 16);
}
__device__ __forceinline__ float2 bf2f2(unsigned u) {
    float2 f;
    f.x = __uint_as_float(u << 16);
    f.y = __uint_as_float(u & 0xFFFF0000u);
    return f;
}

// ---------------- edge-index dtype detection + repack ----------------
__global__ void k_detect(const unsigned* __restrict__ e_raw, int* __restrict__ flag) {
    __shared__ int nz;
    if (threadIdx.x == 0) nz = 0;
    __syncthreads();
    int cnt = 0;
    for (int i = threadIdx.x; i < 2048; i += 256)
        if (e_raw[2 * i + 1] != 0u) cnt = 1;
    if (cnt) atomicOr(&nz, 1);
    __syncthreads();
    if (threadIdx.x == 0) *flag = (nz == 0) ? 1 : 0;   // 1 == int64 layout
}

__global__ __launch_bounds__(256) void k_repack(const void* __restrict__ e_raw,
        const int* __restrict__ flag, int* __restrict__ edges) {
    int i = blockIdx.x * 256 + threadIdx.x;
    if (i >= 2 * N_EDGES) return;
    if (*flag) edges[i] = (int)((const long long*)e_raw)[i];
    else       edges[i] = ((const int*)e_raw)[i];
}

// ---------------- K1: h(bf16) = x @ W_gat ; a_src/a_dst head dots --------
__global__ __launch_bounds__(256) void k_gat_lin(const float* __restrict__ x,
        const float* __restrict__ W, const float* __restrict__ att_s,
        const float* __restrict__ att_d, unsigned* __restrict__ h_bf,
        float* __restrict__ a_src, float* __restrict__ a_dst) {
    __shared__ float sx[BM][128];   // 32 KB
    const int m0 = blockIdx.x * BM;
    const int tid = threadIdx.x;

    for (int i = tid; i < BM * 32; i += 256) {
        int r = i >> 5, c4 = i & 31;
        int row = m0 + r; if (row >= N_NODES) row = N_NODES - 1;
        *(float4*)&sx[r][c4 * 4] = ((const float4*)(x + (size_t)row * 128))[c4];
    }
    __syncthreads();

    const int c0 = (tid & 31) * 4;
    const int r0 = (tid >> 5) * 8;
    float acc[8][4];
#pragma unroll
    for (int r = 0; r < 8; r++)
#pragma unroll
        for (int c = 0; c < 4; c++) acc[r][c] = 0.f;

    for (int k = 0; k < 128; k += 4) {
        float4 w0 = *(const float4*)&W[(k + 0) * 128 + c0];
        float4 w1 = *(const float4*)&W[(k + 1) * 128 + c0];
        float4 w2 = *(const float4*)&W[(k + 2) * 128 + c0];
        float4 w3 = *(const float4*)&W[(k + 3) * 128 + c0];
#pragma unroll
        for (int r = 0; r < 8; r++) {
            float4 xv = *(const float4*)&sx[r0 + r][k];
            acc[r][0] = fmaf(xv.x, w0.x, acc[r][0]);
            acc[r][0] = fmaf(xv.y, w1.x, acc[r][0]);
            acc[r][0] = fmaf(xv.z, w2.x, acc[r][0]);
            acc[r][0] = fmaf(xv.w, w3.x, acc[r][0]);
            acc[r][1] = fmaf(xv.x, w0.y, acc[r][1]);
            acc[r][1] = fmaf(xv.y, w1.y, acc[r][1]);
            acc[r][1] = fmaf(xv.z, w2.y, acc[r][1]);
            acc[r][1] = fmaf(xv.w, w3.y, acc[r][1]);
            acc[r][2] = fmaf(xv.x, w0.z, acc[r][2]);
            acc[r][2] = fmaf(xv.y, w1.z, acc[r][2]);
            acc[r][2] = fmaf(xv.z, w2.z, acc[r][2]);
            acc[r][2] = fmaf(xv.w, w3.z, acc[r][2]);
            acc[r][3] = fmaf(xv.x, w0.w, acc[r][3]);
            acc[r][3] = fmaf(xv.y, w1.w, acc[r][3]);
            acc[r][3] = fmaf(xv.z, w2.w, acc[r][3]);
            acc[r][3] = fmaf(xv.w, w3.w, acc[r][3]);
        }
    }

    float4 as4 = *(const float4*)&att_s[c0];
    float4 ad4 = *(const float4*)&att_d[c0];
    const int head = c0 >> 5;

#pragma unroll
    for (int r = 0; r < 8; r++) {
        int row = m0 + r0 + r;
        bool ok = row < N_NODES;
        if (ok) {
            uint2 p;
            p.x = f2bf2(acc[r][0], acc[r][1]);
            p.y = f2bf2(acc[r][2], acc[r][3]);
            // bf16 row stride 128 -> uint stride 64; c0/2 uints into row
            *(uint2*)&h_bf[(size_t)row * 64 + (c0 >> 1)] = p;
        }
        float vs = acc[r][0] * as4.x + acc[r][1] * as4.y + acc[r][2] * as4.z + acc[r][3] * as4.w;
        float vd = acc[r][0] * ad4.x + acc[r][1] * ad4.y + acc[r][2] * ad4.z + acc[r][3] * ad4.w;
#pragma unroll
        for (int o = 4; o >= 1; o >>= 1) {
            vs += __shfl_down(vs, o, 8);
            vd += __shfl_down(vd, o, 8);
        }
        if (ok && (tid & 7) == 0) {
            a_src[row * 4 + head] = vs;
            a_dst[row * 4 + head] = vd;
        }
    }
}

// ---------------- CSR build: histogram -> hierarchical scan -> fill ------
__global__ __launch_bounds__(256) void k_hist(const int* __restrict__ edges,
        int* __restrict__ cnt) {
    int e = blockIdx.x * 256 + threadIdx.x;
    if (e >= N_EDGES) return;
    atomicAdd(&cnt[edges[N_EDGES + e]], 1);
}

__global__ __launch_bounds__(256) void k_scan1(const int* __restrict__ cnt,
        int* __restrict__ bsum) {
    __shared__ int s[256];
    const int t = threadIdx.x;
    int i = blockIdx.x * 256 + t;
    s[t] = (i < N_NODES) ? cnt[i] : 0;
    __syncthreads();
    for (int o = 128; o >= 1; o >>= 1) {
        if (t < o) s[t] += s[t + o];
        __syncthreads();
    }
    if (t == 0) bsum[blockIdx.x] = s[0];
}

__global__ __launch_bounds__(256) void k_scan2(const int* __restrict__ bsum,
        int* __restrict__ boff) {
    __shared__ int s[256];
    const int t = threadIdx.x;
    int v = (t < SCAN_NB) ? bsum[t] : 0;
    s[t] = v;
    __syncthreads();
    for (int o = 1; o < 256; o <<= 1) {
        int u = (t >= o) ? s[t - o] : 0;
        __syncthreads();
        s[t] += u;
        __syncthreads();
    }
    if (t < SCAN_NB) boff[t] = s[t] - v;   // exclusive
}

__global__ __launch_bounds__(256) void k_scan3(const int* __restrict__ cnt,
        const int* __restrict__ boff, int* __restrict__ off,
        int* __restrict__ cursor) {
    __shared__ int s[256];
    const int t = threadIdx.x;
    int i = blockIdx.x * 256 + t;
    int v = (i < N_NODES) ? cnt[i] : 0;
    s[t] = v;
    __syncthreads();
    for (int o = 1; o < 256; o <<= 1) {
        int u = (t >= o) ? s[t - o] : 0;
        __syncthreads();
        s[t] += u;
        __syncthreads();
    }
    int ex = boff[blockIdx.x] + s[t] - v;
    if (i < N_NODES) { off[i] = ex; cursor[i] = ex; }
    if (i == 0) off[N_NODES] = N_EDGES;
}

__global__ __launch_bounds__(256) void k_fill(const int* __restrict__ edges,
        int* __restrict__ cursor, int* __restrict__ csr_src) {
    int e = blockIdx.x * 256 + threadIdx.x;
    if (e >= N_EDGES) return;
    int s = edges[e], d = edges[N_EDGES + e];
    int pos = atomicAdd(&cursor[d], 1);
    csr_src[pos] = s;
}

// ---------------- K3: CSR gather — single-pass softmax + aggregation -----
// one wave per destination node; 2 bf16 channels per lane.
__global__ __launch_bounds__(256) void k_gather(const int* __restrict__ off,
        const int* __restrict__ csr_src, const float* __restrict__ a_src,
        const float* __restrict__ a_dst, const unsigned* __restrict__ h_bf,
        float* __restrict__ agg) {
    int d = blockIdx.x * 4 + (threadIdx.x >> 6);
    if (d >= N_NODES) return;
    const int lane = threadIdx.x & 63;
    const int hd = lane >> 4;
    const int lo = off[d], hi = off[d + 1];

    const float adh = a_dst[d * 4 + hd];

    // self-loop
    float t = a_src[d * 4 + hd] + adh;
    t = t > 0.f ? t : 0.2f * t;
    float eself = __expf(t);
    float den = eself;
    float2 hs = bf2f2(h_bf[(size_t)d * 64 + lane]);
    float accx = hs.x * eself, accy = hs.y * eself;

    for (int i = lo; i < hi; i++) {
        int s = csr_src[i];
        float tt = a_src[s * 4 + hd] + adh;
        tt = tt > 0.f ? tt : 0.2f * tt;
        float e = __expf(tt);
        den += e;
        float2 hv = bf2f2(h_bf[(size_t)s * 64 + lane]);
        accx = fmaf(hv.x, e, accx);
        accy = fmaf(hv.y, e, accy);
    }
    float inv = 1.f / (den + 1e-16f);
    float2 o2; o2.x = accx * inv; o2.y = accy * inv;
    ((float2*)agg)[(size_t)d * 64 + lane] = o2;
}

// ---------------- K4a: x1=elu(agg+b_gat); enc; x2=elu(dec) ---------------
__global__ __launch_bounds__(256) void k_mlp1(const float* __restrict__ agg,
        const float* __restrict__ b_gat, const float* __restrict__ W_enc,
        const float* __restrict__ b_enc, const float* __restrict__ W_dec,
        const float* __restrict__ b_dec, float* __restrict__ x2g) {
    __shared__ float sx1[BM][132];
    __shared__ float senc[BM][64];
    const int m0 = blockIdx.x * BM;
    const int tid = threadIdx.x;

    for (int i = tid; i < BM * 32; i += 256) {
        int r = i >> 5, c4 = i & 31;
        int row = m0 + r; if (row >= N_NODES) row = N_NODES - 1;
        float4 v = ((const float4*)(agg + (size_t)row * 128))[c4];
        float4 bg = ((const float4*)b_gat)[c4];
        v.x = elu_f(v.x + bg.x); v.y = elu_f(v.y + bg.y);
        v.z = elu_f(v.z + bg.z); v.w = elu_f(v.w + bg.w);
        *(float4*)&sx1[r][c4 * 4] = v;
    }
    __syncthreads();

    {
        const int c0 = (tid & 15) * 4;
        const int r0 = (tid >> 4) * 4;
        float acc[4][4];
#pragma unroll
        for (int r = 0; r < 4; r++)
#pragma unroll
            for (int c = 0; c < 4; c++) acc[r][c] = 0.f;

        for (int k = 0; k < 128; k += 4) {
            float4 w0 = *(const float4*)&W_enc[(k + 0) * 64 + c0];
            float4 w1 = *(const float4*)&W_enc[(k + 1) * 64 + c0];
            float4 w2 = *(const float4*)&W_enc[(k + 2) * 64 + c0];
            float4 w3 = *(const float4*)&W_enc[(k + 3) * 64 + c0];
#pragma unroll
            for (int r = 0; r < 4; r++) {
                float4 xv = *(const float4*)&sx1[r0 + r][k];
                acc[r][0] = fmaf(xv.x, w0.x, acc[r][0]);
                acc[r][0] = fmaf(xv.y, w1.x, acc[r][0]);
                acc[r][0] = fmaf(xv.z, w2.x, acc[r][0]);
                acc[r][0] = fmaf(xv.w, w3.x, acc[r][0]);
                acc[r][1] = fmaf(xv.x, w0.y, acc[r][1]);
                acc[r][1] = fmaf(xv.y, w1.y, acc[r][1]);
                acc[r][1] = fmaf(xv.z, w2.y, acc[r][1]);
                acc[r][1] = fmaf(xv.w, w3.y, acc[r][1]);
                acc[r][2] = fmaf(xv.x, w0.z, acc[r][2]);
                acc[r][2] = fmaf(xv.y, w1.z, acc[r][2]);
                acc[r][2] = fmaf(xv.z, w2.z, acc[r][2]);
                acc[r][2] = fmaf(xv.w, w3.z, acc[r][2]);
                acc[r][3] = fmaf(xv.x, w0.w, acc[r][3]);
                acc[r][3] = fmaf(xv.y, w1.w, acc[r][3]);
                acc[r][3] = fmaf(xv.z, w2.w, acc[r][3]);
                acc[r][3] = fmaf(xv.w, w3.w, acc[r][3]);
            }
        }
        float4 be = *(const float4*)&b_enc[c0];
#pragma unroll
        for (int r = 0; r < 4; r++) {
            float4 o;
            o.x = acc[r][0] + be.x; o.y = acc[r][1] + be.y;
            o.z = acc[r][2] + be.z; o.w = acc[r][3] + be.w;
            *(float4*)&senc[r0 + r][c0] = o;
        }
    }
    __syncthreads();

    {
        const int c0 = (tid & 31) * 4;
        const int r0 = (tid >> 5) * 8;
        float acc[8][4];
#pragma unroll
        for (int r = 0; r < 8; r++)
#pragma unroll
            for (int c = 0; c < 4; c++) acc[r][c] = 0.f;

        for (int k = 0; k < 64; k += 4) {
            float4 w0 = *(const float4*)&W_dec[(k + 0) * 128 + c0];
            float4 w1 = *(const float4*)&W_dec[(k + 1) * 128 + c0];
            float4 w2 = *(const float4*)&W_dec[(k + 2) * 128 + c0];
            float4 w3 = *(const float4*)&W_dec[(k + 3) * 128 + c0];
#pragma unroll
            for (int r = 0; r < 8; r++) {
                float4 xv = *(const float4*)&senc[r0 + r][k];
                acc[r][0] = fmaf(xv.x, w0.x, acc[r][0]);
                acc[r][0] = fmaf(xv.y, w1.x, acc[r][0]);
                acc[r][0] = fmaf(xv.z, w2.x, acc[r][0]);
                acc[r][0] = fmaf(xv.w, w3.x, acc[r][0]);
                acc[r][1] = fmaf(xv.x, w0.y, acc[r][1]);
                acc[r][1] = fmaf(xv.y, w1.y, acc[r][1]);
                acc[r][1] = fmaf(xv.z, w2.y, acc[r][1]);
                acc[r][1] = fmaf(xv.w, w3.y, acc[r][1]);
                acc[r][2] = fmaf(xv.x, w0.z, acc[r][2]);
                acc[r][2] = fmaf(xv.y, w1.z, acc[r][2]);
                acc[r][2] = fmaf(xv.z, w2.z, acc[r][2]);
                acc[r][2] = fmaf(xv.w, w3.z, acc[r][2]);
                acc[r][3] = fmaf(xv.x, w0.w, acc[r][3]);
                acc[r][3] = fmaf(xv.y, w1.w, acc[r][3]);
                acc[r][3] = fmaf(xv.z, w2.w, acc[r][3]);
                acc[r][3] = fmaf(xv.w, w3.w, acc[r][3]);
            }
        }
        float4 bd = *(const float4*)&b_dec[c0];
#pragma unroll
        for (int r = 0; r < 8; r++) {
            int row = m0 + r0 + r;
            if (row < N_NODES) {
                float4 o;
                o.x = elu_f(acc[r][0] + bd.x); o.y = elu_f(acc[r][1] + bd.y);
                o.z = elu_f(acc[r][2] + bd.z); o.w = elu_f(acc[r][3] + bd.w);
                *(float4*)&x2g[(size_t)row * 128 + c0] = o;
            }
        }
    }
}

// ---------------- K4b: out = x2 @ W_out + b_out --------------------------
__global__ __launch_bounds__(256) void k_mlp2(const float* __restrict__ x2g,
        const float* __restrict__ W_out, const float* __restrict__ b_out,
        float* __restrict__ out) {
    __shared__ float sx[BM][128];
    const int m0 = blockIdx.x * BM;
    const int tid = threadIdx.x;

    for (int i = tid; i < BM * 32; i += 256) {
        int r = i >> 5, c4 = i & 31;
        int row = m0 + r; if (row >= N_NODES) row = N_NODES - 1;
        *(float4*)&sx[r][c4 * 4] = ((const float4*)(x2g + (size_t)row * 128))[c4];
    }
    __syncthreads();

    const int c0 = (tid & 31) * 4;
    const int r0 = (tid >> 5) * 8;
    float acc[8][4];
#pragma unroll
    for (int r = 0; r < 8; r++)
#pragma unroll
        for (int c = 0; c < 4; c++) acc[r][c] = 0.f;

    for (int k = 0; k < 128; k += 4) {
        float4 w0 = *(const float4*)&W_out[(k + 0) * 128 + c0];
        float4 w1 = *(const float4*)&W_out[(k + 1) * 128 + c0];
        float4 w2 = *(const float4*)&W_out[(k + 2) * 128 + c0];
        float4 w3 = *(const float4*)&W_out[(k + 3) * 128 + c0];
#pragma unroll
        for (int r = 0; r < 8; r++) {
            float4 xv = *(const float4*)&sx[r0 + r][k];
            acc[r][0] = fmaf(xv.x, w0.x, acc[r][0]);
            acc[r][0] = fmaf(xv.y, w1.x, acc[r][0]);
            acc[r][0] = fmaf(xv.z, w2.x, acc[r][0]);
            acc[r][0] = fmaf(xv.w, w3.x, acc[r][0]);
            acc[r][1] = fmaf(xv.x, w0.y, acc[r][1]);
            acc[r][1] = fmaf(xv.y, w1.y, acc[r][1]);
            acc[r][1] = fmaf(xv.z, w2.y, acc[r][1]);
            acc[r][1] = fmaf(xv.w, w3.y, acc[r][1]);
            acc[r][2] = fmaf(xv.x, w0.z, acc[r][2]);
            acc[r][2] = fmaf(xv.y, w1.z, acc[r][2]);
            acc[r][2] = fmaf(xv.z, w2.z, acc[r][2]);
            acc[r][2] = fmaf(xv.w, w3.z, acc[r][2]);
            acc[r][3] = fmaf(xv.x, w0.w, acc[r][3]);
            acc[r][3] = fmaf(xv.y, w1.w, acc[r][3]);
            acc[r][3] = fmaf(xv.z, w2.w, acc[r][3]);
            acc[r][3] = fmaf(xv.w, w3.w, acc[r][3]);
        }
    }
    float4 bo = *(const float4*)&b_out[c0];
#pragma unroll
    for (int r = 0; r < 8; r++) {
        int row = m0 + r0 + r;
        if (row < N_NODES) {
            float4 o;
            o.x = acc[r][0] + bo.x; o.y = acc[r][1] + bo.y;
            o.z = acc[r][2] + bo.z; o.w = acc[r][3] + bo.w;
            *(float4*)&out[(size_t)row * 128 + c0] = o;
        }
    }
}

extern "C" void kernel_launch(void* const* d_in, const int* in_sizes, int n_in,
                              void* d_out, int out_size, void* d_ws, size_t ws_size,
                              hipStream_t stream) {
    const float* x       = (const float*)d_in[0];
    const void*  e_raw   = d_in[1];
    const float* W_gat   = (const float*)d_in[2];
    const float* b_gat   = (const float*)d_in[3];
    const float* att_src = (const float*)d_in[4];
    const float* att_dst = (const float*)d_in[5];
    const float* W_enc   = (const float*)d_in[6];
    const float* b_enc   = (const float*)d_in[7];
    const float* W_dec   = (const float*)d_in[8];
    const float* b_dec   = (const float*)d_in[9];
    const float* W_out   = (const float*)d_in[10];
    const float* b_out   = (const float*)d_in[11];
    float* out = (float*)d_out;

    float* ws      = (float*)d_ws;
    float*   hreg  = ws;                       // 6,400,000 f (bf16 h uses half; x2g reuses as f32)
    unsigned* h_bf = (unsigned*)hreg;          // 3,200,000 u (50000 x 64)
    float* a_src   = hreg + 6400000;           // 200,000 f
    float* a_dst   = a_src + 200000;           // 200,000 f
    float* agg     = a_dst + 200000;           // 6,400,000 f
    int*   edges   = (int*)(agg + 6400000);    // 1,600,000 i
    int*   cnt     = edges + 1600000;          // 50,000 i
    int*   off     = cnt + 50000;              // 50,001 i
    int*   cursor  = off + 50001;              // 50,001 i
    int*   csr_src = cursor + 50001;           // 800,000 i
    int*   flag    = csr_src + 800000;         // 1 i
    int*   bsum    = flag + 1;                 // 196 i
    int*   boff    = bsum + SCAN_NB;           // 196 i
    float* x2g     = hreg;                     // reuse after gather (f32)

    const int GBLK = (N_NODES + BM - 1) / BM;  // 782

    k_detect<<<1, 256, 0, stream>>>((const unsigned*)e_raw, flag);
    k_repack<<<(2 * N_EDGES + 255) / 256, 256, 0, stream>>>(e_raw, flag, edges);

    k_gat_lin<<<GBLK, 256, 0, stream>>>(x, W_gat, att_src, att_dst, h_bf, a_src, a_dst);

    hipMemsetAsync(cnt, 0, 50000 * sizeof(int), stream);
    k_hist<<<(N_EDGES + 255) / 256, 256, 0, stream>>>(edges, cnt);
    k_scan1<<<SCAN_NB, 256, 0, stream>>>(cnt, bsum);
    k_scan2<<<1, 256, 0, stream>>>(bsum, boff);
    k_scan3<<<SCAN_NB, 256, 0, stream>>>(cnt, boff, off, cursor);
    k_fill<<<(N_EDGES + 255) / 256, 256, 0, stream>>>(edges, cursor, csr_src);

    k_gather<<<(N_NODES + 3) / 4, 256, 0, stream>>>(off, csr_src, a_src, a_dst, h_bf, agg);

    k_mlp1<<<GBLK, 256, 0, stream>>>(agg, b_gat, W_enc, b_enc, W_dec, b_dec, x2g);
    k_mlp2<<<GBLK, 256, 0, stream>>>(x2g, W_out, b_out, out);
}

// Round 6
// 335.948 us; speedup vs baseline: 3.6393x; 1.1342x over previous
//
#include <hip/hip_runtime.h>
#include <hip/hip_bf16.h>

#define N_NODES 50000
#define N_EDGES 800000
#define BM 64
#define SCAN_NB ((N_NODES + 255) / 256)   // 196

__device__ __forceinline__ float elu_f(float v) {
    return (v > 0.f) ? v : (__expf(v) - 1.f);
}

// pack two fp32 -> packed bf16x2 (RNE)
__device__ __forceinline__ unsigned f2bf2(float a, float b) {
    unsigned ua = __float_as_uint(a), ub = __float_as_uint(b);
    ua = (ua + 0x7FFFu + ((ua >> 16) & 1u)) >> 16;
    ub = (ub + 0x7FFFu + ((ub >> 16) & 1u)) >> 16;
    return ua | (ub << 16);
}
__device__ __forceinline__ float2 bf2f2(unsigned u) {
    float2 f;
    f.x = __uint_as_float(u << 16);
    f.y = __uint_as_float(u & 0xFFFF0000u);
    return f;
}

// ---------------- edge-index dtype detection + repack ----------------
__global__ void k_detect(const unsigned* __restrict__ e_raw, int* __restrict__ flag) {
    __shared__ int nz;
    if (threadIdx.x == 0) nz = 0;
    __syncthreads();
    int cnt = 0;
    for (int i = threadIdx.x; i < 2048; i += 256)
        if (e_raw[2 * i + 1] != 0u) cnt = 1;
    if (cnt) atomicOr(&nz, 1);
    __syncthreads();
    if (threadIdx.x == 0) *flag = (nz == 0) ? 1 : 0;   // 1 == int64 layout
}

__global__ __launch_bounds__(256) void k_repack(const void* __restrict__ e_raw,
        const int* __restrict__ flag, int* __restrict__ edges) {
    int i = blockIdx.x * 256 + threadIdx.x;
    if (i >= 2 * N_EDGES) return;
    if (*flag) edges[i] = (int)((const long long*)e_raw)[i];
    else       edges[i] = ((const int*)e_raw)[i];
}

// ---------------- K1: h(bf16) = x @ W_gat ; a_src/a_dst head dots --------
__global__ __launch_bounds__(256) void k_gat_lin(const float* __restrict__ x,
        const float* __restrict__ W, const float* __restrict__ att_s,
        const float* __restrict__ att_d, unsigned* __restrict__ h_bf,
        float* __restrict__ a_src, float* __restrict__ a_dst) {
    __shared__ float sx[BM][128];   // 32 KB
    const int m0 = blockIdx.x * BM;
    const int tid = threadIdx.x;

    for (int i = tid; i < BM * 32; i += 256) {
        int r = i >> 5, c4 = i & 31;
        int row = m0 + r; if (row >= N_NODES) row = N_NODES - 1;
        *(float4*)&sx[r][c4 * 4] = ((const float4*)(x + (size_t)row * 128))[c4];
    }
    __syncthreads();

    const int c0 = (tid & 31) * 4;
    const int r0 = (tid >> 5) * 8;
    float acc[8][4];
#pragma unroll
    for (int r = 0; r < 8; r++)
#pragma unroll
        for (int c = 0; c < 4; c++) acc[r][c] = 0.f;

    for (int k = 0; k < 128; k += 4) {
        float4 w0 = *(const float4*)&W[(k + 0) * 128 + c0];
        float4 w1 = *(const float4*)&W[(k + 1) * 128 + c0];
        float4 w2 = *(const float4*)&W[(k + 2) * 128 + c0];
        float4 w3 = *(const float4*)&W[(k + 3) * 128 + c0];
#pragma unroll
        for (int r = 0; r < 8; r++) {
            float4 xv = *(const float4*)&sx[r0 + r][k];
            acc[r][0] = fmaf(xv.x, w0.x, acc[r][0]);
            acc[r][0] = fmaf(xv.y, w1.x, acc[r][0]);
            acc[r][0] = fmaf(xv.z, w2.x, acc[r][0]);
            acc[r][0] = fmaf(xv.w, w3.x, acc[r][0]);
            acc[r][1] = fmaf(xv.x, w0.y, acc[r][1]);
            acc[r][1] = fmaf(xv.y, w1.y, acc[r][1]);
            acc[r][1] = fmaf(xv.z, w2.y, acc[r][1]);
            acc[r][1] = fmaf(xv.w, w3.y, acc[r][1]);
            acc[r][2] = fmaf(xv.x, w0.z, acc[r][2]);
            acc[r][2] = fmaf(xv.y, w1.z, acc[r][2]);
            acc[r][2] = fmaf(xv.z, w2.z, acc[r][2]);
            acc[r][2] = fmaf(xv.w, w3.z, acc[r][2]);
            acc[r][3] = fmaf(xv.x, w0.w, acc[r][3]);
            acc[r][3] = fmaf(xv.y, w1.w, acc[r][3]);
            acc[r][3] = fmaf(xv.z, w2.w, acc[r][3]);
            acc[r][3] = fmaf(xv.w, w3.w, acc[r][3]);
        }
    }

    float4 as4 = *(const float4*)&att_s[c0];
    float4 ad4 = *(const float4*)&att_d[c0];
    const int head = c0 >> 5;

#pragma unroll
    for (int r = 0; r < 8; r++) {
        int row = m0 + r0 + r;
        bool ok = row < N_NODES;
        if (ok) {
            uint2 p;
            p.x = f2bf2(acc[r][0], acc[r][1]);
            p.y = f2bf2(acc[r][2], acc[r][3]);
            *(uint2*)&h_bf[(size_t)row * 64 + (c0 >> 1)] = p;
        }
        float vs = acc[r][0] * as4.x + acc[r][1] * as4.y + acc[r][2] * as4.z + acc[r][3] * as4.w;
        float vd = acc[r][0] * ad4.x + acc[r][1] * ad4.y + acc[r][2] * ad4.z + acc[r][3] * ad4.w;
#pragma unroll
        for (int o = 4; o >= 1; o >>= 1) {
            vs += __shfl_down(vs, o, 8);
            vd += __shfl_down(vd, o, 8);
        }
        if (ok && (tid & 7) == 0) {
            a_src[row * 4 + head] = vs;
            a_dst[row * 4 + head] = vd;
        }
    }
}

// ---------------- CSR build: histogram -> hierarchical scan -> fill ------
__global__ __launch_bounds__(256) void k_hist(const int* __restrict__ edges,
        int* __restrict__ cnt) {
    int e = blockIdx.x * 256 + threadIdx.x;
    if (e >= N_EDGES) return;
    atomicAdd(&cnt[edges[N_EDGES + e]], 1);
}

__global__ __launch_bounds__(256) void k_scan1(const int* __restrict__ cnt,
        int* __restrict__ bsum) {
    __shared__ int s[256];
    const int t = threadIdx.x;
    int i = blockIdx.x * 256 + t;
    s[t] = (i < N_NODES) ? cnt[i] : 0;
    __syncthreads();
    for (int o = 128; o >= 1; o >>= 1) {
        if (t < o) s[t] += s[t + o];
        __syncthreads();
    }
    if (t == 0) bsum[blockIdx.x] = s[0];
}

__global__ __launch_bounds__(256) void k_scan2(const int* __restrict__ bsum,
        int* __restrict__ boff) {
    __shared__ int s[256];
    const int t = threadIdx.x;
    int v = (t < SCAN_NB) ? bsum[t] : 0;
    s[t] = v;
    __syncthreads();
    for (int o = 1; o < 256; o <<= 1) {
        int u = (t >= o) ? s[t - o] : 0;
        __syncthreads();
        s[t] += u;
        __syncthreads();
    }
    if (t < SCAN_NB) boff[t] = s[t] - v;   // exclusive
}

__global__ __launch_bounds__(256) void k_scan3(const int* __restrict__ cnt,
        const int* __restrict__ boff, int* __restrict__ off,
        int* __restrict__ cursor) {
    __shared__ int s[256];
    const int t = threadIdx.x;
    int i = blockIdx.x * 256 + t;
    int v = (i < N_NODES) ? cnt[i] : 0;
    s[t] = v;
    __syncthreads();
    for (int o = 1; o < 256; o <<= 1) {
        int u = (t >= o) ? s[t - o] : 0;
        __syncthreads();
        s[t] += u;
        __syncthreads();
    }
    int ex = boff[blockIdx.x] + s[t] - v;
    if (i < N_NODES) { off[i] = ex; cursor[i] = ex; }
    if (i == 0) off[N_NODES] = N_EDGES;
}

__global__ __launch_bounds__(256) void k_fill(const int* __restrict__ edges,
        int* __restrict__ cursor, int* __restrict__ csr_src) {
    int e = blockIdx.x * 256 + threadIdx.x;
    if (e >= N_EDGES) return;
    int s = edges[e], d = edges[N_EDGES + e];
    int pos = atomicAdd(&cursor[d], 1);
    csr_src[pos] = s;
}

// ---------------- K3: CSR gather — single-pass softmax, 4x unrolled ------
// one wave per destination node; 2 bf16 channels per lane.
__global__ __launch_bounds__(256) void k_gather(const int* __restrict__ off,
        const int* __restrict__ csr_src, const float* __restrict__ a_src,
        const float* __restrict__ a_dst, const unsigned* __restrict__ h_bf,
        float* __restrict__ agg) {
    int d = blockIdx.x * 4 + (threadIdx.x >> 6);
    if (d >= N_NODES) return;
    const int lane = threadIdx.x & 63;
    const int hd = lane >> 4;
    const int lo = off[d], hi = off[d + 1];

    const float adh = a_dst[d * 4 + hd];

    // self-loop
    float t = a_src[d * 4 + hd] + adh;
    t = t > 0.f ? t : 0.2f * t;
    float eself = __expf(t);
    float den = eself;
    float2 hs = bf2f2(h_bf[(size_t)d * 64 + lane]);
    float accx = hs.x * eself, accy = hs.y * eself;

    int i = lo;
    for (; i + 4 <= hi; i += 4) {
        // batch the index loads, then 4 independent gathers in flight
        int s0 = csr_src[i + 0];
        int s1 = csr_src[i + 1];
        int s2 = csr_src[i + 2];
        int s3 = csr_src[i + 3];
        unsigned u0 = h_bf[(size_t)s0 * 64 + lane];
        unsigned u1 = h_bf[(size_t)s1 * 64 + lane];
        unsigned u2 = h_bf[(size_t)s2 * 64 + lane];
        unsigned u3 = h_bf[(size_t)s3 * 64 + lane];
        float a0 = a_src[s0 * 4 + hd];
        float a1 = a_src[s1 * 4 + hd];
        float a2 = a_src[s2 * 4 + hd];
        float a3 = a_src[s3 * 4 + hd];

        float t0 = a0 + adh; t0 = t0 > 0.f ? t0 : 0.2f * t0;
        float t1 = a1 + adh; t1 = t1 > 0.f ? t1 : 0.2f * t1;
        float t2 = a2 + adh; t2 = t2 > 0.f ? t2 : 0.2f * t2;
        float t3 = a3 + adh; t3 = t3 > 0.f ? t3 : 0.2f * t3;
        float e0 = __expf(t0);
        float e1 = __expf(t1);
        float e2 = __expf(t2);
        float e3 = __expf(t3);
        den += (e0 + e1) + (e2 + e3);

        float2 h0 = bf2f2(u0);
        float2 h1 = bf2f2(u1);
        float2 h2 = bf2f2(u2);
        float2 h3 = bf2f2(u3);
        accx = fmaf(h0.x, e0, accx);
        accy = fmaf(h0.y, e0, accy);
        accx = fmaf(h1.x, e1, accx);
        accy = fmaf(h1.y, e1, accy);
        accx = fmaf(h2.x, e2, accx);
        accy = fmaf(h2.y, e2, accy);
        accx = fmaf(h3.x, e3, accx);
        accy = fmaf(h3.y, e3, accy);
    }
    for (; i < hi; i++) {
        int s = csr_src[i];
        float tt = a_src[s * 4 + hd] + adh;
        tt = tt > 0.f ? tt : 0.2f * tt;
        float e = __expf(tt);
        den += e;
        float2 hv = bf2f2(h_bf[(size_t)s * 64 + lane]);
        accx = fmaf(hv.x, e, accx);
        accy = fmaf(hv.y, e, accy);
    }
    float inv = 1.f / (den + 1e-16f);
    float2 o2; o2.x = accx * inv; o2.y = accy * inv;
    ((float2*)agg)[(size_t)d * 64 + lane] = o2;
}

// ---------------- K4a: x1=elu(agg+b_gat); enc; x2=elu(dec) ---------------
__global__ __launch_bounds__(256) void k_mlp1(const float* __restrict__ agg,
        const float* __restrict__ b_gat, const float* __restrict__ W_enc,
        const float* __restrict__ b_enc, const float* __restrict__ W_dec,
        const float* __restrict__ b_dec, float* __restrict__ x2g) {
    __shared__ float sx1[BM][132];
    __shared__ float senc[BM][64];
    const int m0 = blockIdx.x * BM;
    const int tid = threadIdx.x;

    for (int i = tid; i < BM * 32; i += 256) {
        int r = i >> 5, c4 = i & 31;
        int row = m0 + r; if (row >= N_NODES) row = N_NODES - 1;
        float4 v = ((const float4*)(agg + (size_t)row * 128))[c4];
        float4 bg = ((const float4*)b_gat)[c4];
        v.x = elu_f(v.x + bg.x); v.y = elu_f(v.y + bg.y);
        v.z = elu_f(v.z + bg.z); v.w = elu_f(v.w + bg.w);
        *(float4*)&sx1[r][c4 * 4] = v;
    }
    __syncthreads();

    {
        const int c0 = (tid & 15) * 4;
        const int r0 = (tid >> 4) * 4;
        float acc[4][4];
#pragma unroll
        for (int r = 0; r < 4; r++)
#pragma unroll
            for (int c = 0; c < 4; c++) acc[r][c] = 0.f;

        for (int k = 0; k < 128; k += 4) {
            float4 w0 = *(const float4*)&W_enc[(k + 0) * 64 + c0];
            float4 w1 = *(const float4*)&W_enc[(k + 1) * 64 + c0];
            float4 w2 = *(const float4*)&W_enc[(k + 2) * 64 + c0];
            float4 w3 = *(const float4*)&W_enc[(k + 3) * 64 + c0];
#pragma unroll
            for (int r = 0; r < 4; r++) {
                float4 xv = *(const float4*)&sx1[r0 + r][k];
                acc[r][0] = fmaf(xv.x, w0.x, acc[r][0]);
                acc[r][0] = fmaf(xv.y, w1.x, acc[r][0]);
                acc[r][0] = fmaf(xv.z, w2.x, acc[r][0]);
                acc[r][0] = fmaf(xv.w, w3.x, acc[r][0]);
                acc[r][1] = fmaf(xv.x, w0.y, acc[r][1]);
                acc[r][1] = fmaf(xv.y, w1.y, acc[r][1]);
                acc[r][1] = fmaf(xv.z, w2.y, acc[r][1]);
                acc[r][1] = fmaf(xv.w, w3.y, acc[r][1]);
                acc[r][2] = fmaf(xv.x, w0.z, acc[r][2]);
                acc[r][2] = fmaf(xv.y, w1.z, acc[r][2]);
                acc[r][2] = fmaf(xv.z, w2.z, acc[r][2]);
                acc[r][2] = fmaf(xv.w, w3.z, acc[r][2]);
                acc[r][3] = fmaf(xv.x, w0.w, acc[r][3]);
                acc[r][3] = fmaf(xv.y, w1.w, acc[r][3]);
                acc[r][3] = fmaf(xv.z, w2.w, acc[r][3]);
                acc[r][3] = fmaf(xv.w, w3.w, acc[r][3]);
            }
        }
        float4 be = *(const float4*)&b_enc[c0];
#pragma unroll
        for (int r = 0; r < 4; r++) {
            float4 o;
            o.x = acc[r][0] + be.x; o.y = acc[r][1] + be.y;
            o.z = acc[r][2] + be.z; o.w = acc[r][3] + be.w;
            *(float4*)&senc[r0 + r][c0] = o;
        }
    }
    __syncthreads();

    {
        const int c0 = (tid & 31) * 4;
        const int r0 = (tid >> 5) * 8;
        float acc[8][4];
#pragma unroll
        for (int r = 0; r < 8; r++)
#pragma unroll
            for (int c = 0; c < 4; c++) acc[r][c] = 0.f;

        for (int k = 0; k < 64; k += 4) {
            float4 w0 = *(const float4*)&W_dec[(k + 0) * 128 + c0];
            float4 w1 = *(const float4*)&W_dec[(k + 1) * 128 + c0];
            float4 w2 = *(const float4*)&W_dec[(k + 2) * 128 + c0];
            float4 w3 = *(const float4*)&W_dec[(k + 3) * 128 + c0];
#pragma unroll
            for (int r = 0; r < 8; r++) {
                float4 xv = *(const float4*)&senc[r0 + r][k];
                acc[r][0] = fmaf(xv.x, w0.x, acc[r][0]);
                acc[r][0] = fmaf(xv.y, w1.x, acc[r][0]);
                acc[r][0] = fmaf(xv.z, w2.x, acc[r][0]);
                acc[r][0] = fmaf(xv.w, w3.x, acc[r][0]);
                acc[r][1] = fmaf(xv.x, w0.y, acc[r][1]);
                acc[r][1] = fmaf(xv.y, w1.y, acc[r][1]);
                acc[r][1] = fmaf(xv.z, w2.y, acc[r][1]);
                acc[r][1] = fmaf(xv.w, w3.y, acc[r][1]);
                acc[r][2] = fmaf(xv.x, w0.z, acc[r][2]);
                acc[r][2] = fmaf(xv.y, w1.z, acc[r][2]);
                acc[r][2] = fmaf(xv.z, w2.z, acc[r][2]);
                acc[r][2] = fmaf(xv.w, w3.z, acc[r][2]);
                acc[r][3] = fmaf(xv.x, w0.w, acc[r][3]);
                acc[r][3] = fmaf(xv.y, w1.w, acc[r][3]);
                acc[r][3] = fmaf(xv.z, w2.w, acc[r][3]);
                acc[r][3] = fmaf(xv.w, w3.w, acc[r][3]);
            }
        }
        float4 bd = *(const float4*)&b_dec[c0];
#pragma unroll
        for (int r = 0; r < 8; r++) {
            int row = m0 + r0 + r;
            if (row < N_NODES) {
                float4 o;
                o.x = elu_f(acc[r][0] + bd.x); o.y = elu_f(acc[r][1] + bd.y);
                o.z = elu_f(acc[r][2] + bd.z); o.w = elu_f(acc[r][3] + bd.w);
                *(float4*)&x2g[(size_t)row * 128 + c0] = o;
            }
        }
    }
}

// ---------------- K4b: out = x2 @ W_out + b_out --------------------------
__global__ __launch_bounds__(256) void k_mlp2(const float* __restrict__ x2g,
        const float* __restrict__ W_out, const float* __restrict__ b_out,
        float* __restrict__ out) {
    __shared__ float sx[BM][128];
    const int m0 = blockIdx.x * BM;
    const int tid = threadIdx.x;

    for (int i = tid; i < BM * 32; i += 256) {
        int r = i >> 5, c4 = i & 31;
        int row = m0 + r; if (row >= N_NODES) row = N_NODES - 1;
        *(float4*)&sx[r][c4 * 4] = ((const float4*)(x2g + (size_t)row * 128))[c4];
    }
    __syncthreads();

    const int c0 = (tid & 31) * 4;
    const int r0 = (tid >> 5) * 8;
    float acc[8][4];
#pragma unroll
    for (int r = 0; r < 8; r++)
#pragma unroll
        for (int c = 0; c < 4; c++) acc[r][c] = 0.f;

    for (int k = 0; k < 128; k += 4) {
        float4 w0 = *(const float4*)&W_out[(k + 0) * 128 + c0];
        float4 w1 = *(const float4*)&W_out[(k + 1) * 128 + c0];
        float4 w2 = *(const float4*)&W_out[(k + 2) * 128 + c0];
        float4 w3 = *(const float4*)&W_out[(k + 3) * 128 + c0];
#pragma unroll
        for (int r = 0; r < 8; r++) {
            float4 xv = *(const float4*)&sx[r0 + r][k];
            acc[r][0] = fmaf(xv.x, w0.x, acc[r][0]);
            acc[r][0] = fmaf(xv.y, w1.x, acc[r][0]);
            acc[r][0] = fmaf(xv.z, w2.x, acc[r][0]);
            acc[r][0] = fmaf(xv.w, w3.x, acc[r][0]);
            acc[r][1] = fmaf(xv.x, w0.y, acc[r][1]);
            acc[r][1] = fmaf(xv.y, w1.y, acc[r][1]);
            acc[r][1] = fmaf(xv.z, w2.y, acc[r][1]);
            acc[r][1] = fmaf(xv.w, w3.y, acc[r][1]);
            acc[r][2] = fmaf(xv.x, w0.z, acc[r][2]);
            acc[r][2] = fmaf(xv.y, w1.z, acc[r][2]);
            acc[r][2] = fmaf(xv.z, w2.z, acc[r][2]);
            acc[r][2] = fmaf(xv.w, w3.z, acc[r][2]);
            acc[r][3] = fmaf(xv.x, w0.w, acc[r][3]);
            acc[r][3] = fmaf(xv.y, w1.w, acc[r][3]);
            acc[r][3] = fmaf(xv.z, w2.w, acc[r][3]);
            acc[r][3] = fmaf(xv.w, w3.w, acc[r][3]);
        }
    }
    float4 bo = *(const float4*)&b_out[c0];
#pragma unroll
    for (int r = 0; r < 8; r++) {
        int row = m0 + r0 + r;
        if (row < N_NODES) {
            float4 o;
            o.x = acc[r][0] + bo.x; o.y = acc[r][1] + bo.y;
            o.z = acc[r][2] + bo.z; o.w = acc[r][3] + bo.w;
            *(float4*)&out[(size_t)row * 128 + c0] = o;
        }
    }
}

extern "C" void kernel_launch(void* const* d_in, const int* in_sizes, int n_in,
                              void* d_out, int out_size, void* d_ws, size_t ws_size,
                              hipStream_t stream) {
    const float* x       = (const float*)d_in[0];
    const void*  e_raw   = d_in[1];
    const float* W_gat   = (const float*)d_in[2];
    const float* b_gat   = (const float*)d_in[3];
    const float* att_src = (const float*)d_in[4];
    const float* att_dst = (const float*)d_in[5];
    const float* W_enc   = (const float*)d_in[6];
    const float* b_enc   = (const float*)d_in[7];
    const float* W_dec   = (const float*)d_in[8];
    const float* b_dec   = (const float*)d_in[9];
    const float* W_out   = (const float*)d_in[10];
    const float* b_out   = (const float*)d_in[11];
    float* out = (float*)d_out;

    float* ws      = (float*)d_ws;
    float*   hreg  = ws;                       // 6,400,000 f
    unsigned* h_bf = (unsigned*)hreg;          // 3,200,000 u (50000 x 64)
    float* a_src   = hreg + 6400000;           // 200,000 f
    float* a_dst   = a_src + 200000;           // 200,000 f
    float* agg     = a_dst + 200000;           // 6,400,000 f
    int*   edges   = (int*)(agg + 6400000);    // 1,600,000 i
    int*   cnt     = edges + 1600000;          // 50,000 i
    int*   off     = cnt + 50000;              // 50,001 i
    int*   cursor  = off + 50001;              // 50,001 i
    int*   csr_src = cursor + 50001;           // 800,000 i
    int*   flag    = csr_src + 800000;         // 1 i
    int*   bsum    = flag + 1;                 // 196 i
    int*   boff    = bsum + SCAN_NB;           // 196 i
    float* x2g     = hreg;                     // reuse after gather (f32)

    const int GBLK = (N_NODES + BM - 1) / BM;  // 782

    k_detect<<<1, 256, 0, stream>>>((const unsigned*)e_raw, flag);
    k_repack<<<(2 * N_EDGES + 255) / 256, 256, 0, stream>>>(e_raw, flag, edges);

    k_gat_lin<<<GBLK, 256, 0, stream>>>(x, W_gat, att_src, att_dst, h_bf, a_src, a_dst);

    hipMemsetAsync(cnt, 0, 50000 * sizeof(int), stream);
    k_hist<<<(N_EDGES + 255) / 256, 256, 0, stream>>>(edges, cnt);
    k_scan1<<<SCAN_NB, 256, 0, stream>>>(cnt, bsum);
    k_scan2<<<1, 256, 0, stream>>>(bsum, boff);
    k_scan3<<<SCAN_NB, 256, 0, stream>>>(cnt, boff, off, cursor);
    k_fill<<<(N_EDGES + 255) / 256, 256, 0, stream>>>(edges, cursor, csr_src);

    k_gather<<<(N_NODES + 3) / 4, 256, 0, stream>>>(off, csr_src, a_src, a_dst, h_bf, agg);

    k_mlp1<<<GBLK, 256, 0, stream>>>(agg, b_gat, W_enc, b_enc, W_dec, b_dec, x2g);
    k_mlp2<<<GBLK, 256, 0, stream>>>(x2g, W_out, b_out, out);
}

// Round 7
// 295.675 us; speedup vs baseline: 4.1350x; 1.1362x over previous
//
#include <hip/hip_runtime.h>
#include <hip/hip_bf16.h>

#define N_NODES 50000
#define N_EDGES 800000
#define BM 64
#define NBUCK 196            // buckets of 256 nodes: d >> 8
#define CHUNK 8192           // edges per block in bucket pass
#define NB_BUCKET_BLOCKS ((N_EDGES + CHUNK - 1) / CHUNK)   // 98

__device__ __forceinline__ float elu_f(float v) {
    return (v > 0.f) ? v : (__expf(v) - 1.f);
}

// pack two fp32 -> packed bf16x2 (RNE)
__device__ __forceinline__ unsigned f2bf2(float a, float b) {
    unsigned ua = __float_as_uint(a), ub = __float_as_uint(b);
    ua = (ua + 0x7FFFu + ((ua >> 16) & 1u)) >> 16;
    ub = (ub + 0x7FFFu + ((ub >> 16) & 1u)) >> 16;
    return ua | (ub << 16);
}
__device__ __forceinline__ float2 bf2f2(unsigned u) {
    float2 f;
    f.x = __uint_as_float(u << 16);
    f.y = __uint_as_float(u & 0xFFFF0000u);
    return f;
}

// ---------------- edge-index dtype detection + repack ----------------
__global__ void k_detect(const unsigned* __restrict__ e_raw, int* __restrict__ flag) {
    __shared__ int nz;
    if (threadIdx.x == 0) nz = 0;
    __syncthreads();
    int cnt = 0;
    for (int i = threadIdx.x; i < 2048; i += 256)
        if (e_raw[2 * i + 1] != 0u) cnt = 1;
    if (cnt) atomicOr(&nz, 1);
    __syncthreads();
    if (threadIdx.x == 0) *flag = (nz == 0) ? 1 : 0;   // 1 == int64 layout
}

__global__ __launch_bounds__(256) void k_repack(const void* __restrict__ e_raw,
        const int* __restrict__ flag, int* __restrict__ edges) {
    int i = blockIdx.x * 256 + threadIdx.x;
    if (i >= 2 * N_EDGES) return;
    if (*flag) edges[i] = (int)((const long long*)e_raw)[i];
    else       edges[i] = ((const int*)e_raw)[i];
}

// ---------------- K1: h(bf16) = x @ W_gat ; a_src/a_dst head dots --------
__global__ __launch_bounds__(256) void k_gat_lin(const float* __restrict__ x,
        const float* __restrict__ W, const float* __restrict__ att_s,
        const float* __restrict__ att_d, unsigned* __restrict__ h_bf,
        float* __restrict__ a_src, float* __restrict__ a_dst) {
    __shared__ float sx[BM][128];   // 32 KB
    const int m0 = blockIdx.x * BM;
    const int tid = threadIdx.x;

    for (int i = tid; i < BM * 32; i += 256) {
        int r = i >> 5, c4 = i & 31;
        int row = m0 + r; if (row >= N_NODES) row = N_NODES - 1;
        *(float4*)&sx[r][c4 * 4] = ((const float4*)(x + (size_t)row * 128))[c4];
    }
    __syncthreads();

    const int c0 = (tid & 31) * 4;
    const int r0 = (tid >> 5) * 8;
    float acc[8][4];
#pragma unroll
    for (int r = 0; r < 8; r++)
#pragma unroll
        for (int c = 0; c < 4; c++) acc[r][c] = 0.f;

    for (int k = 0; k < 128; k += 4) {
        float4 w0 = *(const float4*)&W[(k + 0) * 128 + c0];
        float4 w1 = *(const float4*)&W[(k + 1) * 128 + c0];
        float4 w2 = *(const float4*)&W[(k + 2) * 128 + c0];
        float4 w3 = *(const float4*)&W[(k + 3) * 128 + c0];
#pragma unroll
        for (int r = 0; r < 8; r++) {
            float4 xv = *(const float4*)&sx[r0 + r][k];
            acc[r][0] = fmaf(xv.x, w0.x, acc[r][0]);
            acc[r][0] = fmaf(xv.y, w1.x, acc[r][0]);
            acc[r][0] = fmaf(xv.z, w2.x, acc[r][0]);
            acc[r][0] = fmaf(xv.w, w3.x, acc[r][0]);
            acc[r][1] = fmaf(xv.x, w0.y, acc[r][1]);
            acc[r][1] = fmaf(xv.y, w1.y, acc[r][1]);
            acc[r][1] = fmaf(xv.z, w2.y, acc[r][1]);
            acc[r][1] = fmaf(xv.w, w3.y, acc[r][1]);
            acc[r][2] = fmaf(xv.x, w0.z, acc[r][2]);
            acc[r][2] = fmaf(xv.y, w1.z, acc[r][2]);
            acc[r][2] = fmaf(xv.z, w2.z, acc[r][2]);
            acc[r][2] = fmaf(xv.w, w3.z, acc[r][2]);
            acc[r][3] = fmaf(xv.x, w0.w, acc[r][3]);
            acc[r][3] = fmaf(xv.y, w1.w, acc[r][3]);
            acc[r][3] = fmaf(xv.z, w2.w, acc[r][3]);
            acc[r][3] = fmaf(xv.w, w3.w, acc[r][3]);
        }
    }

    float4 as4 = *(const float4*)&att_s[c0];
    float4 ad4 = *(const float4*)&att_d[c0];
    const int head = c0 >> 5;

#pragma unroll
    for (int r = 0; r < 8; r++) {
        int row = m0 + r0 + r;
        bool ok = row < N_NODES;
        if (ok) {
            uint2 p;
            p.x = f2bf2(acc[r][0], acc[r][1]);
            p.y = f2bf2(acc[r][2], acc[r][3]);
            *(uint2*)&h_bf[(size_t)row * 64 + (c0 >> 1)] = p;
        }
        float vs = acc[r][0] * as4.x + acc[r][1] * as4.y + acc[r][2] * as4.z + acc[r][3] * as4.w;
        float vd = acc[r][0] * ad4.x + acc[r][1] * ad4.y + acc[r][2] * ad4.z + acc[r][3] * ad4.w;
#pragma unroll
        for (int o = 4; o >= 1; o >>= 1) {
            vs += __shfl_down(vs, o, 8);
            vd += __shfl_down(vd, o, 8);
        }
        if (ok && (tid & 7) == 0) {
            a_src[row * 4 + head] = vs;
            a_dst[row * 4 + head] = vd;
        }
    }
}

// ---------------- CSR build v2: bucket sort with block-owned regions -----
// Stage 1: bucket histogram (bucket = d >> 8, 196 buckets)
__global__ __launch_bounds__(256) void k_bhist(const int* __restrict__ edges,
        int* __restrict__ bcnt) {
    __shared__ int lh[256];
    const int tid = threadIdx.x;
    lh[tid] = 0;
    __syncthreads();
    const int base = blockIdx.x * CHUNK;
#pragma unroll 4
    for (int j = 0; j < CHUNK / 256; j++) {
        int e = base + j * 256 + tid;
        if (e < N_EDGES) {
            int d = edges[N_EDGES + e];
            atomicAdd(&lh[d >> 8], 1);
        }
    }
    __syncthreads();
    if (lh[tid]) atomicAdd(&bcnt[tid], lh[tid]);
}

// Stage 2: single block exclusive scan of bucket counts -> bbase, bcursor
__global__ __launch_bounds__(256) void k_bscan(const int* __restrict__ bcnt,
        int* __restrict__ bbase, int* __restrict__ bcursor,
        int* __restrict__ off) {
    __shared__ int s[256];
    const int t = threadIdx.x;
    int v = bcnt[t];   // buckets >= NBUCK are zero (memset)
    s[t] = v;
    __syncthreads();
    for (int o = 1; o < 256; o <<= 1) {
        int u = (t >= o) ? s[t - o] : 0;
        __syncthreads();
        s[t] += u;
        __syncthreads();
    }
    int exc = s[t] - v;
    bbase[t] = exc;
    bcursor[t] = exc;
    if (t == 0) {
        off[N_NODES] = N_EDGES;
    }
}

// Stage 3: scatter (s,d) pairs into bucket regions; per-block run reservation
__global__ __launch_bounds__(256) void k_bucket(const int* __restrict__ edges,
        int* __restrict__ bcursor, uint2* __restrict__ ebuck) {
    __shared__ int lh[256];
    __shared__ int gbase[256];
    __shared__ int lcur[256];
    const int tid = threadIdx.x;
    const int base = blockIdx.x * CHUNK;

    lh[tid] = 0;
    __syncthreads();
#pragma unroll 4
    for (int j = 0; j < CHUNK / 256; j++) {
        int e = base + j * 256 + tid;
        if (e < N_EDGES) {
            int d = edges[N_EDGES + e];
            atomicAdd(&lh[d >> 8], 1);
        }
    }
    __syncthreads();
    // reserve contiguous runs in each bucket
    if (lh[tid]) gbase[tid] = atomicAdd(&bcursor[tid], lh[tid]);
    lcur[tid] = 0;
    __syncthreads();
#pragma unroll 4
    for (int j = 0; j < CHUNK / 256; j++) {
        int e = base + j * 256 + tid;
        if (e < N_EDGES) {
            int sN = edges[e];
            int d  = edges[N_EDGES + e];
            int b  = d >> 8;
            int p  = gbase[b] + atomicAdd(&lcur[b], 1);
            uint2 pr; pr.x = (unsigned)sN; pr.y = (unsigned)d;
            ebuck[p] = pr;
        }
    }
}

// Stage 4: per-bucket fine sort -> off[] + csr_src. One block owns one
// bucket's 256 nodes and its contiguous csr region (compact writeback).
__global__ __launch_bounds__(256) void k_bfill(const uint2* __restrict__ ebuck,
        const int* __restrict__ bbase, int* __restrict__ off,
        int* __restrict__ csr_src) {
    __shared__ int lh[256];
    __shared__ int lexc[256];
    __shared__ int lcur[256];
    const int tid = threadIdx.x;
    const int b = blockIdx.x;
    const int lo = bbase[b], hi = bbase[b + 1];
    const int n0 = b << 8;

    lh[tid] = 0;
    lcur[tid] = 0;
    __syncthreads();
    for (int i = lo + tid; i < hi; i += 256)
        atomicAdd(&lh[ebuck[i].y & 255], 1);
    __syncthreads();
    {   // exclusive scan of lh
        int v = lh[tid];
        int s = v;
        lexc[tid] = v;
        __syncthreads();
        for (int o = 1; o < 256; o <<= 1) {
            int u = (tid >= o) ? lexc[tid - o] : 0;
            __syncthreads();
            lexc[tid] += u;
            __syncthreads();
        }
        s = lexc[tid] - v;   // exclusive
        __syncthreads();
        lexc[tid] = s;
        int node = n0 + tid;
        if (node < N_NODES) off[node] = lo + s;
    }
    __syncthreads();
    for (int i = lo + tid; i < hi; i += 256) {
        uint2 pr = ebuck[i];
        int li = (int)(pr.y & 255);
        int p = atomicAdd(&lcur[li], 1);
        csr_src[lo + lexc[li] + p] = (int)pr.x;
    }
}

// ---------------- K3: CSR gather — single-pass softmax, 4x unrolled ------
__global__ __launch_bounds__(256) void k_gather(const int* __restrict__ off,
        const int* __restrict__ csr_src, const float* __restrict__ a_src,
        const float* __restrict__ a_dst, const unsigned* __restrict__ h_bf,
        float* __restrict__ agg) {
    int d = blockIdx.x * 4 + (threadIdx.x >> 6);
    if (d >= N_NODES) return;
    const int lane = threadIdx.x & 63;
    const int hd = lane >> 4;
    const int lo = off[d], hi = off[d + 1];

    const float adh = a_dst[d * 4 + hd];

    float t = a_src[d * 4 + hd] + adh;
    t = t > 0.f ? t : 0.2f * t;
    float eself = __expf(t);
    float den = eself;
    float2 hs = bf2f2(h_bf[(size_t)d * 64 + lane]);
    float accx = hs.x * eself, accy = hs.y * eself;

    int i = lo;
    for (; i + 4 <= hi; i += 4) {
        int s0 = csr_src[i + 0];
        int s1 = csr_src[i + 1];
        int s2 = csr_src[i + 2];
        int s3 = csr_src[i + 3];
        unsigned u0 = h_bf[(size_t)s0 * 64 + lane];
        unsigned u1 = h_bf[(size_t)s1 * 64 + lane];
        unsigned u2 = h_bf[(size_t)s2 * 64 + lane];
        unsigned u3 = h_bf[(size_t)s3 * 64 + lane];
        float a0 = a_src[s0 * 4 + hd];
        float a1 = a_src[s1 * 4 + hd];
        float a2 = a_src[s2 * 4 + hd];
        float a3 = a_src[s3 * 4 + hd];

        float t0 = a0 + adh; t0 = t0 > 0.f ? t0 : 0.2f * t0;
        float t1 = a1 + adh; t1 = t1 > 0.f ? t1 : 0.2f * t1;
        float t2 = a2 + adh; t2 = t2 > 0.f ? t2 : 0.2f * t2;
        float t3 = a3 + adh; t3 = t3 > 0.f ? t3 : 0.2f * t3;
        float e0 = __expf(t0);
        float e1 = __expf(t1);
        float e2 = __expf(t2);
        float e3 = __expf(t3);
        den += (e0 + e1) + (e2 + e3);

        float2 h0 = bf2f2(u0);
        float2 h1 = bf2f2(u1);
        float2 h2 = bf2f2(u2);
        float2 h3 = bf2f2(u3);
        accx = fmaf(h0.x, e0, accx);
        accy = fmaf(h0.y, e0, accy);
        accx = fmaf(h1.x, e1, accx);
        accy = fmaf(h1.y, e1, accy);
        accx = fmaf(h2.x, e2, accx);
        accy = fmaf(h2.y, e2, accy);
        accx = fmaf(h3.x, e3, accx);
        accy = fmaf(h3.y, e3, accy);
    }
    for (; i < hi; i++) {
        int s = csr_src[i];
        float tt = a_src[s * 4 + hd] + adh;
        tt = tt > 0.f ? tt : 0.2f * tt;
        float e = __expf(tt);
        den += e;
        float2 hv = bf2f2(h_bf[(size_t)s * 64 + lane]);
        accx = fmaf(hv.x, e, accx);
        accy = fmaf(hv.y, e, accy);
    }
    float inv = 1.f / (den + 1e-16f);
    float2 o2; o2.x = accx * inv; o2.y = accy * inv;
    ((float2*)agg)[(size_t)d * 64 + lane] = o2;
}

// ---------------- K4a: x1=elu(agg+b_gat); enc; x2=elu(dec) ---------------
__global__ __launch_bounds__(256) void k_mlp1(const float* __restrict__ agg,
        const float* __restrict__ b_gat, const float* __restrict__ W_enc,
        const float* __restrict__ b_enc, const float* __restrict__ W_dec,
        const float* __restrict__ b_dec, float* __restrict__ x2g) {
    __shared__ float sx1[BM][132];
    __shared__ float senc[BM][64];
    const int m0 = blockIdx.x * BM;
    const int tid = threadIdx.x;

    for (int i = tid; i < BM * 32; i += 256) {
        int r = i >> 5, c4 = i & 31;
        int row = m0 + r; if (row >= N_NODES) row = N_NODES - 1;
        float4 v = ((const float4*)(agg + (size_t)row * 128))[c4];
        float4 bg = ((const float4*)b_gat)[c4];
        v.x = elu_f(v.x + bg.x); v.y = elu_f(v.y + bg.y);
        v.z = elu_f(v.z + bg.z); v.w = elu_f(v.w + bg.w);
        *(float4*)&sx1[r][c4 * 4] = v;
    }
    __syncthreads();

    {
        const int c0 = (tid & 15) * 4;
        const int r0 = (tid >> 4) * 4;
        float acc[4][4];
#pragma unroll
        for (int r = 0; r < 4; r++)
#pragma unroll
            for (int c = 0; c < 4; c++) acc[r][c] = 0.f;

        for (int k = 0; k < 128; k += 4) {
            float4 w0 = *(const float4*)&W_enc[(k + 0) * 64 + c0];
            float4 w1 = *(const float4*)&W_enc[(k + 1) * 64 + c0];
            float4 w2 = *(const float4*)&W_enc[(k + 2) * 64 + c0];
            float4 w3 = *(const float4*)&W_enc[(k + 3) * 64 + c0];
#pragma unroll
            for (int r = 0; r < 4; r++) {
                float4 xv = *(const float4*)&sx1[r0 + r][k];
                acc[r][0] = fmaf(xv.x, w0.x, acc[r][0]);
                acc[r][0] = fmaf(xv.y, w1.x, acc[r][0]);
                acc[r][0] = fmaf(xv.z, w2.x, acc[r][0]);
                acc[r][0] = fmaf(xv.w, w3.x, acc[r][0]);
                acc[r][1] = fmaf(xv.x, w0.y, acc[r][1]);
                acc[r][1] = fmaf(xv.y, w1.y, acc[r][1]);
                acc[r][1] = fmaf(xv.z, w2.y, acc[r][1]);
                acc[r][1] = fmaf(xv.w, w3.y, acc[r][1]);
                acc[r][2] = fmaf(xv.x, w0.z, acc[r][2]);
                acc[r][2] = fmaf(xv.y, w1.z, acc[r][2]);
                acc[r][2] = fmaf(xv.z, w2.z, acc[r][2]);
                acc[r][2] = fmaf(xv.w, w3.z, acc[r][2]);
                acc[r][3] = fmaf(xv.x, w0.w, acc[r][3]);
                acc[r][3] = fmaf(xv.y, w1.w, acc[r][3]);
                acc[r][3] = fmaf(xv.z, w2.w, acc[r][3]);
                acc[r][3] = fmaf(xv.w, w3.w, acc[r][3]);
            }
        }
        float4 be = *(const float4*)&b_enc[c0];
#pragma unroll
        for (int r = 0; r < 4; r++) {
            float4 o;
            o.x = acc[r][0] + be.x; o.y = acc[r][1] + be.y;
            o.z = acc[r][2] + be.z; o.w = acc[r][3] + be.w;
            *(float4*)&senc[r0 + r][c0] = o;
        }
    }
    __syncthreads();

    {
        const int c0 = (tid & 31) * 4;
        const int r0 = (tid >> 5) * 8;
        float acc[8][4];
#pragma unroll
        for (int r = 0; r < 8; r++)
#pragma unroll
            for (int c = 0; c < 4; c++) acc[r][c] = 0.f;

        for (int k = 0; k < 64; k += 4) {
            float4 w0 = *(const float4*)&W_dec[(k + 0) * 128 + c0];
            float4 w1 = *(const float4*)&W_dec[(k + 1) * 128 + c0];
            float4 w2 = *(const float4*)&W_dec[(k + 2) * 128 + c0];
            float4 w3 = *(const float4*)&W_dec[(k + 3) * 128 + c0];
#pragma unroll
            for (int r = 0; r < 8; r++) {
                float4 xv = *(const float4*)&senc[r0 + r][k];
                acc[r][0] = fmaf(xv.x, w0.x, acc[r][0]);
                acc[r][0] = fmaf(xv.y, w1.x, acc[r][0]);
                acc[r][0] = fmaf(xv.z, w2.x, acc[r][0]);
                acc[r][0] = fmaf(xv.w, w3.x, acc[r][0]);
                acc[r][1] = fmaf(xv.x, w0.y, acc[r][1]);
                acc[r][1] = fmaf(xv.y, w1.y, acc[r][1]);
                acc[r][1] = fmaf(xv.z, w2.y, acc[r][1]);
                acc[r][1] = fmaf(xv.w, w3.y, acc[r][1]);
                acc[r][2] = fmaf(xv.x, w0.z, acc[r][2]);
                acc[r][2] = fmaf(xv.y, w1.z, acc[r][2]);
                acc[r][2] = fmaf(xv.z, w2.z, acc[r][2]);
                acc[r][2] = fmaf(xv.w, w3.z, acc[r][2]);
                acc[r][3] = fmaf(xv.x, w0.w, acc[r][3]);
                acc[r][3] = fmaf(xv.y, w1.w, acc[r][3]);
                acc[r][3] = fmaf(xv.z, w2.w, acc[r][3]);
                acc[r][3] = fmaf(xv.w, w3.w, acc[r][3]);
            }
        }
        float4 bd = *(const float4*)&b_dec[c0];
#pragma unroll
        for (int r = 0; r < 8; r++) {
            int row = m0 + r0 + r;
            if (row < N_NODES) {
                float4 o;
                o.x = elu_f(acc[r][0] + bd.x); o.y = elu_f(acc[r][1] + bd.y);
                o.z = elu_f(acc[r][2] + bd.z); o.w = elu_f(acc[r][3] + bd.w);
                *(float4*)&x2g[(size_t)row * 128 + c0] = o;
            }
        }
    }
}

// ---------------- K4b: out = x2 @ W_out + b_out --------------------------
__global__ __launch_bounds__(256) void k_mlp2(const float* __restrict__ x2g,
        const float* __restrict__ W_out, const float* __restrict__ b_out,
        float* __restrict__ out) {
    __shared__ float sx[BM][128];
    const int m0 = blockIdx.x * BM;
    const int tid = threadIdx.x;

    for (int i = tid; i < BM * 32; i += 256) {
        int r = i >> 5, c4 = i & 31;
        int row = m0 + r; if (row >= N_NODES) row = N_NODES - 1;
        *(float4*)&sx[r][c4 * 4] = ((const float4*)(x2g + (size_t)row * 128))[c4];
    }
    __syncthreads();

    const int c0 = (tid & 31) * 4;
    const int r0 = (tid >> 5) * 8;
    float acc[8][4];
#pragma unroll
    for (int r = 0; r < 8; r++)
#pragma unroll
        for (int c = 0; c < 4; c++) acc[r][c] = 0.f;

    for (int k = 0; k < 128; k += 4) {
        float4 w0 = *(const float4*)&W_out[(k + 0) * 128 + c0];
        float4 w1 = *(const float4*)&W_out[(k + 1) * 128 + c0];
        float4 w2 = *(const float4*)&W_out[(k + 2) * 128 + c0];
        float4 w3 = *(const float4*)&W_out[(k + 3) * 128 + c0];
#pragma unroll
        for (int r = 0; r < 8; r++) {
            float4 xv = *(const float4*)&sx[r0 + r][k];
            acc[r][0] = fmaf(xv.x, w0.x, acc[r][0]);
            acc[r][0] = fmaf(xv.y, w1.x, acc[r][0]);
            acc[r][0] = fmaf(xv.z, w2.x, acc[r][0]);
            acc[r][0] = fmaf(xv.w, w3.x, acc[r][0]);
            acc[r][1] = fmaf(xv.x, w0.y, acc[r][1]);
            acc[r][1] = fmaf(xv.y, w1.y, acc[r][1]);
            acc[r][1] = fmaf(xv.z, w2.y, acc[r][1]);
            acc[r][1] = fmaf(xv.w, w3.y, acc[r][1]);
            acc[r][2] = fmaf(xv.x, w0.z, acc[r][2]);
            acc[r][2] = fmaf(xv.y, w1.z, acc[r][2]);
            acc[r][2] = fmaf(xv.z, w2.z, acc[r][2]);
            acc[r][2] = fmaf(xv.w, w3.z, acc[r][2]);
            acc[r][3] = fmaf(xv.x, w0.w, acc[r][3]);
            acc[r][3] = fmaf(xv.y, w1.w, acc[r][3]);
            acc[r][3] = fmaf(xv.z, w2.w, acc[r][3]);
            acc[r][3] = fmaf(xv.w, w3.w, acc[r][3]);
        }
    }
    float4 bo = *(const float4*)&b_out[c0];
#pragma unroll
    for (int r = 0; r < 8; r++) {
        int row = m0 + r0 + r;
        if (row < N_NODES) {
            float4 o;
            o.x = acc[r][0] + bo.x; o.y = acc[r][1] + bo.y;
            o.z = acc[r][2] + bo.z; o.w = acc[r][3] + bo.w;
            *(float4*)&out[(size_t)row * 128 + c0] = o;
        }
    }
}

extern "C" void kernel_launch(void* const* d_in, const int* in_sizes, int n_in,
                              void* d_out, int out_size, void* d_ws, size_t ws_size,
                              hipStream_t stream) {
    const float* x       = (const float*)d_in[0];
    const void*  e_raw   = d_in[1];
    const float* W_gat   = (const float*)d_in[2];
    const float* b_gat   = (const float*)d_in[3];
    const float* att_src = (const float*)d_in[4];
    const float* att_dst = (const float*)d_in[5];
    const float* W_enc   = (const float*)d_in[6];
    const float* b_enc   = (const float*)d_in[7];
    const float* W_dec   = (const float*)d_in[8];
    const float* b_dec   = (const float*)d_in[9];
    const float* W_out   = (const float*)d_in[10];
    const float* b_out   = (const float*)d_in[11];
    float* out = (float*)d_out;

    float* ws      = (float*)d_ws;
    float*   hreg  = ws;                       // 6,400,000 f
    unsigned* h_bf = (unsigned*)hreg;          // 3,200,000 u (50000 x 64)
    float* a_src   = hreg + 6400000;           // 200,000 f
    float* a_dst   = a_src + 200000;           // 200,000 f
    float* agg     = a_dst + 200000;           // 6,400,000 f
    uint2* ebuck   = (uint2*)agg;              // 800,000 x 8B — aliases agg (dead before k_gather)
    int*   edges   = (int*)(agg + 6400000);    // 1,600,000 i
    int*   csr_src = edges + 1600000;          // 800,000 i
    int*   off     = csr_src + 800000;         // 50,001 i
    int*   flag    = off + 50001;              // 1 i
    int*   bcnt    = flag + 1;                 // 256 i
    int*   bbase   = bcnt + 256;               // 257 i
    int*   bcursor = bbase + 257;              // 256 i
    float* x2g     = hreg;                     // reuse after gather (f32)

    const int GBLK = (N_NODES + BM - 1) / BM;  // 782

    k_detect<<<1, 256, 0, stream>>>((const unsigned*)e_raw, flag);
    k_repack<<<(2 * N_EDGES + 255) / 256, 256, 0, stream>>>(e_raw, flag, edges);

    k_gat_lin<<<GBLK, 256, 0, stream>>>(x, W_gat, att_src, att_dst, h_bf, a_src, a_dst);

    hipMemsetAsync(bcnt, 0, 256 * sizeof(int), stream);
    k_bhist<<<NB_BUCKET_BLOCKS, 256, 0, stream>>>(edges, bcnt);
    k_bscan<<<1, 256, 0, stream>>>(bcnt, bbase, bcursor, off);
    k_bucket<<<NB_BUCKET_BLOCKS, 256, 0, stream>>>(edges, bcursor, ebuck);
    k_bfill<<<NBUCK, 256, 0, stream>>>(ebuck, bbase, off, csr_src);

    k_gather<<<(N_NODES + 3) / 4, 256, 0, stream>>>(off, csr_src, a_src, a_dst, h_bf, agg);

    k_mlp1<<<GBLK, 256, 0, stream>>>(agg, b_gat, W_enc, b_enc, W_dec, b_dec, x2g);
    k_mlp2<<<GBLK, 256, 0, stream>>>(x2g, W_out, b_out, out);
}

// Round 8
// 294.559 us; speedup vs baseline: 4.1507x; 1.0038x over previous
//
#include <hip/hip_runtime.h>
#include <hip/hip_bf16.h>

#define N_NODES 50000
#define N_EDGES 800000
#define BM 64
#define NBUCK 196            // buckets of 256 nodes: d >> 8
#define CHUNK 8192           // edges per block in bucket pass
#define NB_BUCKET_BLOCKS ((N_EDGES + CHUNK - 1) / CHUNK)   // 98

__device__ __forceinline__ float elu_f(float v) {
    return (v > 0.f) ? v : (__expf(v) - 1.f);
}

// pack two fp32 -> packed bf16x2 (RNE)
__device__ __forceinline__ unsigned f2bf2(float a, float b) {
    unsigned ua = __float_as_uint(a), ub = __float_as_uint(b);
    ua = (ua + 0x7FFFu + ((ua >> 16) & 1u)) >> 16;
    ub = (ub + 0x7FFFu + ((ub >> 16) & 1u)) >> 16;
    return ua | (ub << 16);
}
__device__ __forceinline__ float2 bf2f2(unsigned u) {
    float2 f;
    f.x = __uint_as_float(u << 16);
    f.y = __uint_as_float(u & 0xFFFF0000u);
    return f;
}

// ---------------- edge-index dtype detection + repack ----------------
__global__ void k_detect(const unsigned* __restrict__ e_raw, int* __restrict__ flag) {
    __shared__ int nz;
    if (threadIdx.x == 0) nz = 0;
    __syncthreads();
    int cnt = 0;
    for (int i = threadIdx.x; i < 2048; i += 256)
        if (e_raw[2 * i + 1] != 0u) cnt = 1;
    if (cnt) atomicOr(&nz, 1);
    __syncthreads();
    if (threadIdx.x == 0) *flag = (nz == 0) ? 1 : 0;   // 1 == int64 layout
}

__global__ __launch_bounds__(256) void k_repack(const void* __restrict__ e_raw,
        const int* __restrict__ flag, int* __restrict__ edges) {
    int i = blockIdx.x * 256 + threadIdx.x;
    if (i >= 2 * N_EDGES) return;
    if (*flag) edges[i] = (int)((const long long*)e_raw)[i];
    else       edges[i] = ((const int*)e_raw)[i];
}

// ---------------- K1: h(bf16) = x @ W_gat ; a_src/a_dst head dots --------
__global__ __launch_bounds__(256) void k_gat_lin(const float* __restrict__ x,
        const float* __restrict__ W, const float* __restrict__ att_s,
        const float* __restrict__ att_d, unsigned* __restrict__ h_bf,
        float* __restrict__ a_src, float* __restrict__ a_dst) {
    __shared__ float sx[BM][128];   // 32 KB
    const int m0 = blockIdx.x * BM;
    const int tid = threadIdx.x;

    for (int i = tid; i < BM * 32; i += 256) {
        int r = i >> 5, c4 = i & 31;
        int row = m0 + r; if (row >= N_NODES) row = N_NODES - 1;
        *(float4*)&sx[r][c4 * 4] = ((const float4*)(x + (size_t)row * 128))[c4];
    }
    __syncthreads();

    const int c0 = (tid & 31) * 4;
    const int r0 = (tid >> 5) * 8;
    float acc[8][4];
#pragma unroll
    for (int r = 0; r < 8; r++)
#pragma unroll
        for (int c = 0; c < 4; c++) acc[r][c] = 0.f;

    for (int k = 0; k < 128; k += 4) {
        float4 w0 = *(const float4*)&W[(k + 0) * 128 + c0];
        float4 w1 = *(const float4*)&W[(k + 1) * 128 + c0];
        float4 w2 = *(const float4*)&W[(k + 2) * 128 + c0];
        float4 w3 = *(const float4*)&W[(k + 3) * 128 + c0];
#pragma unroll
        for (int r = 0; r < 8; r++) {
            float4 xv = *(const float4*)&sx[r0 + r][k];
            acc[r][0] = fmaf(xv.x, w0.x, acc[r][0]);
            acc[r][0] = fmaf(xv.y, w1.x, acc[r][0]);
            acc[r][0] = fmaf(xv.z, w2.x, acc[r][0]);
            acc[r][0] = fmaf(xv.w, w3.x, acc[r][0]);
            acc[r][1] = fmaf(xv.x, w0.y, acc[r][1]);
            acc[r][1] = fmaf(xv.y, w1.y, acc[r][1]);
            acc[r][1] = fmaf(xv.z, w2.y, acc[r][1]);
            acc[r][1] = fmaf(xv.w, w3.y, acc[r][1]);
            acc[r][2] = fmaf(xv.x, w0.z, acc[r][2]);
            acc[r][2] = fmaf(xv.y, w1.z, acc[r][2]);
            acc[r][2] = fmaf(xv.z, w2.z, acc[r][2]);
            acc[r][2] = fmaf(xv.w, w3.z, acc[r][2]);
            acc[r][3] = fmaf(xv.x, w0.w, acc[r][3]);
            acc[r][3] = fmaf(xv.y, w1.w, acc[r][3]);
            acc[r][3] = fmaf(xv.z, w2.w, acc[r][3]);
            acc[r][3] = fmaf(xv.w, w3.w, acc[r][3]);
        }
    }

    float4 as4 = *(const float4*)&att_s[c0];
    float4 ad4 = *(const float4*)&att_d[c0];
    const int head = c0 >> 5;

#pragma unroll
    for (int r = 0; r < 8; r++) {
        int row = m0 + r0 + r;
        bool ok = row < N_NODES;
        if (ok) {
            uint2 p;
            p.x = f2bf2(acc[r][0], acc[r][1]);
            p.y = f2bf2(acc[r][2], acc[r][3]);
            *(uint2*)&h_bf[(size_t)row * 64 + (c0 >> 1)] = p;
        }
        float vs = acc[r][0] * as4.x + acc[r][1] * as4.y + acc[r][2] * as4.z + acc[r][3] * as4.w;
        float vd = acc[r][0] * ad4.x + acc[r][1] * ad4.y + acc[r][2] * ad4.z + acc[r][3] * ad4.w;
#pragma unroll
        for (int o = 4; o >= 1; o >>= 1) {
            vs += __shfl_down(vs, o, 8);
            vd += __shfl_down(vd, o, 8);
        }
        if (ok && (tid & 7) == 0) {
            a_src[row * 4 + head] = vs;
            a_dst[row * 4 + head] = vd;
        }
    }
}

// ---------------- CSR build v2: bucket sort with block-owned regions -----
__global__ __launch_bounds__(256) void k_bhist(const int* __restrict__ edges,
        int* __restrict__ bcnt) {
    __shared__ int lh[256];
    const int tid = threadIdx.x;
    lh[tid] = 0;
    __syncthreads();
    const int base = blockIdx.x * CHUNK;
#pragma unroll 4
    for (int j = 0; j < CHUNK / 256; j++) {
        int e = base + j * 256 + tid;
        if (e < N_EDGES) {
            int d = edges[N_EDGES + e];
            atomicAdd(&lh[d >> 8], 1);
        }
    }
    __syncthreads();
    if (lh[tid]) atomicAdd(&bcnt[tid], lh[tid]);
}

__global__ __launch_bounds__(256) void k_bscan(const int* __restrict__ bcnt,
        int* __restrict__ bbase, int* __restrict__ bcursor,
        int* __restrict__ off) {
    __shared__ int s[256];
    const int t = threadIdx.x;
    int v = bcnt[t];
    s[t] = v;
    __syncthreads();
    for (int o = 1; o < 256; o <<= 1) {
        int u = (t >= o) ? s[t - o] : 0;
        __syncthreads();
        s[t] += u;
        __syncthreads();
    }
    int exc = s[t] - v;
    bbase[t] = exc;
    bcursor[t] = exc;
    if (t == 0) {
        off[N_NODES] = N_EDGES;
    }
}

__global__ __launch_bounds__(256) void k_bucket(const int* __restrict__ edges,
        int* __restrict__ bcursor, uint2* __restrict__ ebuck) {
    __shared__ int lh[256];
    __shared__ int gbase[256];
    __shared__ int lcur[256];
    const int tid = threadIdx.x;
    const int base = blockIdx.x * CHUNK;

    lh[tid] = 0;
    __syncthreads();
#pragma unroll 4
    for (int j = 0; j < CHUNK / 256; j++) {
        int e = base + j * 256 + tid;
        if (e < N_EDGES) {
            int d = edges[N_EDGES + e];
            atomicAdd(&lh[d >> 8], 1);
        }
    }
    __syncthreads();
    if (lh[tid]) gbase[tid] = atomicAdd(&bcursor[tid], lh[tid]);
    lcur[tid] = 0;
    __syncthreads();
#pragma unroll 4
    for (int j = 0; j < CHUNK / 256; j++) {
        int e = base + j * 256 + tid;
        if (e < N_EDGES) {
            int sN = edges[e];
            int d  = edges[N_EDGES + e];
            int b  = d >> 8;
            int p  = gbase[b] + atomicAdd(&lcur[b], 1);
            uint2 pr; pr.x = (unsigned)sN; pr.y = (unsigned)d;
            ebuck[p] = pr;
        }
    }
}

__global__ __launch_bounds__(256) void k_bfill(const uint2* __restrict__ ebuck,
        const int* __restrict__ bbase, int* __restrict__ off,
        int* __restrict__ csr_src) {
    __shared__ int lh[256];
    __shared__ int lexc[256];
    __shared__ int lcur[256];
    const int tid = threadIdx.x;
    const int b = blockIdx.x;
    const int lo = bbase[b], hi = bbase[b + 1];
    const int n0 = b << 8;

    lh[tid] = 0;
    lcur[tid] = 0;
    __syncthreads();
    for (int i = lo + tid; i < hi; i += 256)
        atomicAdd(&lh[ebuck[i].y & 255], 1);
    __syncthreads();
    {
        int v = lh[tid];
        int s = v;
        lexc[tid] = v;
        __syncthreads();
        for (int o = 1; o < 256; o <<= 1) {
            int u = (tid >= o) ? lexc[tid - o] : 0;
            __syncthreads();
            lexc[tid] += u;
            __syncthreads();
        }
        s = lexc[tid] - v;
        __syncthreads();
        lexc[tid] = s;
        int node = n0 + tid;
        if (node < N_NODES) off[node] = lo + s;
    }
    __syncthreads();
    for (int i = lo + tid; i < hi; i += 256) {
        uint2 pr = ebuck[i];
        int li = (int)(pr.y & 255);
        int p = atomicAdd(&lcur[li], 1);
        csr_src[lo + lexc[li] + p] = (int)pr.x;
    }
}

// ---------------- K3: CSR gather — single-pass softmax, 4x unrolled ------
__global__ __launch_bounds__(256) void k_gather(const int* __restrict__ off,
        const int* __restrict__ csr_src, const float* __restrict__ a_src,
        const float* __restrict__ a_dst, const unsigned* __restrict__ h_bf,
        float* __restrict__ agg) {
    int d = blockIdx.x * 4 + (threadIdx.x >> 6);
    if (d >= N_NODES) return;
    const int lane = threadIdx.x & 63;
    const int hd = lane >> 4;
    const int lo = off[d], hi = off[d + 1];

    const float adh = a_dst[d * 4 + hd];

    float t = a_src[d * 4 + hd] + adh;
    t = t > 0.f ? t : 0.2f * t;
    float eself = __expf(t);
    float den = eself;
    float2 hs = bf2f2(h_bf[(size_t)d * 64 + lane]);
    float accx = hs.x * eself, accy = hs.y * eself;

    int i = lo;
    for (; i + 4 <= hi; i += 4) {
        int s0 = csr_src[i + 0];
        int s1 = csr_src[i + 1];
        int s2 = csr_src[i + 2];
        int s3 = csr_src[i + 3];
        unsigned u0 = h_bf[(size_t)s0 * 64 + lane];
        unsigned u1 = h_bf[(size_t)s1 * 64 + lane];
        unsigned u2 = h_bf[(size_t)s2 * 64 + lane];
        unsigned u3 = h_bf[(size_t)s3 * 64 + lane];
        float a0 = a_src[s0 * 4 + hd];
        float a1 = a_src[s1 * 4 + hd];
        float a2 = a_src[s2 * 4 + hd];
        float a3 = a_src[s3 * 4 + hd];

        float t0 = a0 + adh; t0 = t0 > 0.f ? t0 : 0.2f * t0;
        float t1 = a1 + adh; t1 = t1 > 0.f ? t1 : 0.2f * t1;
        float t2 = a2 + adh; t2 = t2 > 0.f ? t2 : 0.2f * t2;
        float t3 = a3 + adh; t3 = t3 > 0.f ? t3 : 0.2f * t3;
        float e0 = __expf(t0);
        float e1 = __expf(t1);
        float e2 = __expf(t2);
        float e3 = __expf(t3);
        den += (e0 + e1) + (e2 + e3);

        float2 h0 = bf2f2(u0);
        float2 h1 = bf2f2(u1);
        float2 h2 = bf2f2(u2);
        float2 h3 = bf2f2(u3);
        accx = fmaf(h0.x, e0, accx);
        accy = fmaf(h0.y, e0, accy);
        accx = fmaf(h1.x, e1, accx);
        accy = fmaf(h1.y, e1, accy);
        accx = fmaf(h2.x, e2, accx);
        accy = fmaf(h2.y, e2, accy);
        accx = fmaf(h3.x, e3, accx);
        accy = fmaf(h3.y, e3, accy);
    }
    for (; i < hi; i++) {
        int s = csr_src[i];
        float tt = a_src[s * 4 + hd] + adh;
        tt = tt > 0.f ? tt : 0.2f * tt;
        float e = __expf(tt);
        den += e;
        float2 hv = bf2f2(h_bf[(size_t)s * 64 + lane]);
        accx = fmaf(hv.x, e, accx);
        accy = fmaf(hv.y, e, accy);
    }
    float inv = 1.f / (den + 1e-16f);
    float2 o2; o2.x = accx * inv; o2.y = accy * inv;
    ((float2*)agg)[(size_t)d * 64 + lane] = o2;
}

// ---------------- K4: fused MLP: elu(agg+b)->enc->elu(dec)->out ----------
// BM=32 rows/block. LDS: sx 32x132 (x1, later x2) + senc 32x68 = ~25.3 KB
// -> 6 blocks/CU. 1563 blocks.
__global__ __launch_bounds__(256) void k_mlp(const float* __restrict__ agg,
        const float* __restrict__ b_gat, const float* __restrict__ W_enc,
        const float* __restrict__ b_enc, const float* __restrict__ W_dec,
        const float* __restrict__ b_dec, const float* __restrict__ W_out,
        const float* __restrict__ b_out, float* __restrict__ out) {
    __shared__ float sx[32][132];    // x1 then x2
    __shared__ float senc[32][68];
    const int m0 = blockIdx.x * 32;
    const int tid = threadIdx.x;

    // stage 1: x1 = elu(agg + b_gat) -> sx
    for (int i = tid; i < 32 * 32; i += 256) {
        int r = i >> 5, c4 = i & 31;
        int row = m0 + r; if (row >= N_NODES) row = N_NODES - 1;
        float4 v = ((const float4*)(agg + (size_t)row * 128))[c4];
        float4 bg = ((const float4*)b_gat)[c4];
        v.x = elu_f(v.x + bg.x); v.y = elu_f(v.y + bg.y);
        v.z = elu_f(v.z + bg.z); v.w = elu_f(v.w + bg.w);
        *(float4*)&sx[r][c4 * 4] = v;
    }
    __syncthreads();

    // stage 2: enc = x1 @ W_enc + b_enc   [32x64], K=128  (2 rows x 4 cols)
    {
        const int c0 = (tid & 15) * 4;
        const int r0 = (tid >> 4) * 2;
        float acc[2][4];
#pragma unroll
        for (int r = 0; r < 2; r++)
#pragma unroll
            for (int c = 0; c < 4; c++) acc[r][c] = 0.f;

        for (int k = 0; k < 128; k += 4) {
            float4 w0 = *(const float4*)&W_enc[(k + 0) * 64 + c0];
            float4 w1 = *(const float4*)&W_enc[(k + 1) * 64 + c0];
            float4 w2 = *(const float4*)&W_enc[(k + 2) * 64 + c0];
            float4 w3 = *(const float4*)&W_enc[(k + 3) * 64 + c0];
#pragma unroll
            for (int r = 0; r < 2; r++) {
                float4 xv = *(const float4*)&sx[r0 + r][k];
                acc[r][0] = fmaf(xv.x, w0.x, acc[r][0]);
                acc[r][0] = fmaf(xv.y, w1.x, acc[r][0]);
                acc[r][0] = fmaf(xv.z, w2.x, acc[r][0]);
                acc[r][0] = fmaf(xv.w, w3.x, acc[r][0]);
                acc[r][1] = fmaf(xv.x, w0.y, acc[r][1]);
                acc[r][1] = fmaf(xv.y, w1.y, acc[r][1]);
                acc[r][1] = fmaf(xv.z, w2.y, acc[r][1]);
                acc[r][1] = fmaf(xv.w, w3.y, acc[r][1]);
                acc[r][2] = fmaf(xv.x, w0.z, acc[r][2]);
                acc[r][2] = fmaf(xv.y, w1.z, acc[r][2]);
                acc[r][2] = fmaf(xv.z, w2.z, acc[r][2]);
                acc[r][2] = fmaf(xv.w, w3.z, acc[r][2]);
                acc[r][3] = fmaf(xv.x, w0.w, acc[r][3]);
                acc[r][3] = fmaf(xv.y, w1.w, acc[r][3]);
                acc[r][3] = fmaf(xv.z, w2.w, acc[r][3]);
                acc[r][3] = fmaf(xv.w, w3.w, acc[r][3]);
            }
        }
        float4 be = *(const float4*)&b_enc[c0];
#pragma unroll
        for (int r = 0; r < 2; r++) {
            float4 o;
            o.x = acc[r][0] + be.x; o.y = acc[r][1] + be.y;
            o.z = acc[r][2] + be.z; o.w = acc[r][3] + be.w;
            *(float4*)&senc[r0 + r][c0] = o;
        }
    }
    __syncthreads();

    // stage 3: x2 = elu(enc @ W_dec + b_dec)  [32x128], K=64 (4 rows x 4 cols)
    {
        const int c0 = (tid & 31) * 4;
        const int r0 = (tid >> 5) * 4;
        float acc[4][4];
#pragma unroll
        for (int r = 0; r < 4; r++)
#pragma unroll
            for (int c = 0; c < 4; c++) acc[r][c] = 0.f;

        for (int k = 0; k < 64; k += 4) {
            float4 w0 = *(const float4*)&W_dec[(k + 0) * 128 + c0];
            float4 w1 = *(const float4*)&W_dec[(k + 1) * 128 + c0];
            float4 w2 = *(const float4*)&W_dec[(k + 2) * 128 + c0];
            float4 w3 = *(const float4*)&W_dec[(k + 3) * 128 + c0];
#pragma unroll
            for (int r = 0; r < 4; r++) {
                float4 xv = *(const float4*)&senc[r0 + r][k];
                acc[r][0] = fmaf(xv.x, w0.x, acc[r][0]);
                acc[r][0] = fmaf(xv.y, w1.x, acc[r][0]);
                acc[r][0] = fmaf(xv.z, w2.x, acc[r][0]);
                acc[r][0] = fmaf(xv.w, w3.x, acc[r][0]);
                acc[r][1] = fmaf(xv.x, w0.y, acc[r][1]);
                acc[r][1] = fmaf(xv.y, w1.y, acc[r][1]);
                acc[r][1] = fmaf(xv.z, w2.y, acc[r][1]);
                acc[r][1] = fmaf(xv.w, w3.y, acc[r][1]);
                acc[r][2] = fmaf(xv.x, w0.z, acc[r][2]);
                acc[r][2] = fmaf(xv.y, w1.z, acc[r][2]);
                acc[r][2] = fmaf(xv.z, w2.z, acc[r][2]);
                acc[r][2] = fmaf(xv.w, w3.z, acc[r][2]);
                acc[r][3] = fmaf(xv.x, w0.w, acc[r][3]);
                acc[r][3] = fmaf(xv.y, w1.w, acc[r][3]);
                acc[r][3] = fmaf(xv.z, w2.w, acc[r][3]);
                acc[r][3] = fmaf(xv.w, w3.w, acc[r][3]);
            }
        }
        float4 bd = *(const float4*)&b_dec[c0];
#pragma unroll
        for (int r = 0; r < 4; r++) {
            float4 o;
            o.x = elu_f(acc[r][0] + bd.x); o.y = elu_f(acc[r][1] + bd.y);
            o.z = elu_f(acc[r][2] + bd.z); o.w = elu_f(acc[r][3] + bd.w);
            *(float4*)&sx[r0 + r][c0] = o;   // sx now holds x2
        }
    }
    __syncthreads();

    // stage 4: out = x2 @ W_out + b_out   [32x128], K=128 (4 rows x 4 cols)
    {
        const int c0 = (tid & 31) * 4;
        const int r0 = (tid >> 5) * 4;
        float acc[4][4];
#pragma unroll
        for (int r = 0; r < 4; r++)
#pragma unroll
            for (int c = 0; c < 4; c++) acc[r][c] = 0.f;

        for (int k = 0; k < 128; k += 4) {
            float4 w0 = *(const float4*)&W_out[(k + 0) * 128 + c0];
            float4 w1 = *(const float4*)&W_out[(k + 1) * 128 + c0];
            float4 w2 = *(const float4*)&W_out[(k + 2) * 128 + c0];
            float4 w3 = *(const float4*)&W_out[(k + 3) * 128 + c0];
#pragma unroll
            for (int r = 0; r < 4; r++) {
                float4 xv = *(const float4*)&sx[r0 + r][k];
                acc[r][0] = fmaf(xv.x, w0.x, acc[r][0]);
                acc[r][0] = fmaf(xv.y, w1.x, acc[r][0]);
                acc[r][0] = fmaf(xv.z, w2.x, acc[r][0]);
                acc[r][0] = fmaf(xv.w, w3.x, acc[r][0]);
                acc[r][1] = fmaf(xv.x, w0.y, acc[r][1]);
                acc[r][1] = fmaf(xv.y, w1.y, acc[r][1]);
                acc[r][1] = fmaf(xv.z, w2.y, acc[r][1]);
                acc[r][1] = fmaf(xv.w, w3.y, acc[r][1]);
                acc[r][2] = fmaf(xv.x, w0.z, acc[r][2]);
                acc[r][2] = fmaf(xv.y, w1.z, acc[r][2]);
                acc[r][2] = fmaf(xv.z, w2.z, acc[r][2]);
                acc[r][2] = fmaf(xv.w, w3.z, acc[r][2]);
                acc[r][3] = fmaf(xv.x, w0.w, acc[r][3]);
                acc[r][3] = fmaf(xv.y, w1.w, acc[r][3]);
                acc[r][3] = fmaf(xv.z, w2.w, acc[r][3]);
                acc[r][3] = fmaf(xv.w, w3.w, acc[r][3]);
            }
        }
        float4 bo = *(const float4*)&b_out[c0];
#pragma unroll
        for (int r = 0; r < 4; r++) {
            int row = m0 + r0 + r;
            if (row < N_NODES) {
                float4 o;
                o.x = acc[r][0] + bo.x; o.y = acc[r][1] + bo.y;
                o.z = acc[r][2] + bo.z; o.w = acc[r][3] + bo.w;
                *(float4*)&out[(size_t)row * 128 + c0] = o;
            }
        }
    }
}

extern "C" void kernel_launch(void* const* d_in, const int* in_sizes, int n_in,
                              void* d_out, int out_size, void* d_ws, size_t ws_size,
                              hipStream_t stream) {
    const float* x       = (const float*)d_in[0];
    const void*  e_raw   = d_in[1];
    const float* W_gat   = (const float*)d_in[2];
    const float* b_gat   = (const float*)d_in[3];
    const float* att_src = (const float*)d_in[4];
    const float* att_dst = (const float*)d_in[5];
    const float* W_enc   = (const float*)d_in[6];
    const float* b_enc   = (const float*)d_in[7];
    const float* W_dec   = (const float*)d_in[8];
    const float* b_dec   = (const float*)d_in[9];
    const float* W_out   = (const float*)d_in[10];
    const float* b_out   = (const float*)d_in[11];
    float* out = (float*)d_out;

    float* ws      = (float*)d_ws;
    float*   hreg  = ws;                       // 6,400,000 f
    unsigned* h_bf = (unsigned*)hreg;          // 3,200,000 u (50000 x 64)
    float* a_src   = hreg + 6400000;           // 200,000 f
    float* a_dst   = a_src + 200000;           // 200,000 f
    float* agg     = a_dst + 200000;           // 6,400,000 f
    uint2* ebuck   = (uint2*)agg;              // aliases agg (dead before k_gather)
    int*   edges   = (int*)(agg + 6400000);    // 1,600,000 i
    int*   csr_src = edges + 1600000;          // 800,000 i
    int*   off     = csr_src + 800000;         // 50,001 i
    int*   flag    = off + 50001;              // 1 i
    int*   bcnt    = flag + 1;                 // 256 i
    int*   bbase   = bcnt + 256;               // 257 i
    int*   bcursor = bbase + 257;              // 256 i

    const int GBLK = (N_NODES + BM - 1) / BM;  // 782

    k_detect<<<1, 256, 0, stream>>>((const unsigned*)e_raw, flag);
    k_repack<<<(2 * N_EDGES + 255) / 256, 256, 0, stream>>>(e_raw, flag, edges);

    k_gat_lin<<<GBLK, 256, 0, stream>>>(x, W_gat, att_src, att_dst, h_bf, a_src, a_dst);

    hipMemsetAsync(bcnt, 0, 256 * sizeof(int), stream);
    k_bhist<<<NB_BUCKET_BLOCKS, 256, 0, stream>>>(edges, bcnt);
    k_bscan<<<1, 256, 0, stream>>>(bcnt, bbase, bcursor, off);
    k_bucket<<<NB_BUCKET_BLOCKS, 256, 0, stream>>>(edges, bcursor, ebuck);
    k_bfill<<<NBUCK, 256, 0, stream>>>(ebuck, bbase, off, csr_src);

    k_gather<<<(N_NODES + 3) / 4, 256, 0, stream>>>(off, csr_src, a_src, a_dst, h_bf, agg);

    k_mlp<<<(N_NODES + 31) / 32, 256, 0, stream>>>(agg, b_gat, W_enc, b_enc,
                                                   W_dec, b_dec, W_out, b_out, out);
}

// Round 9
// 245.914 us; speedup vs baseline: 4.9718x; 1.1978x over previous
//
#include <hip/hip_runtime.h>
#include <hip/hip_bf16.h>

#define N_NODES 50000
#define N_EDGES 800000
#define BM 64
#define NBUCK 196            // buckets of 256 nodes: d >> 8
#define CHUNK 8192           // edges per block in bucket pass
#define NB_BUCKET_BLOCKS ((N_EDGES + CHUNK - 1) / CHUNK)   // 98

typedef _Float16 half4v __attribute__((ext_vector_type(4)));
typedef _Float16 half8  __attribute__((ext_vector_type(8)));
typedef float    float4v __attribute__((ext_vector_type(4)));

__device__ __forceinline__ float elu_f(float v) {
    return (v > 0.f) ? v : (__expf(v) - 1.f);
}

// pack two fp32 -> packed bf16x2 (RNE)
__device__ __forceinline__ unsigned f2bf2(float a, float b) {
    unsigned ua = __float_as_uint(a), ub = __float_as_uint(b);
    ua = (ua + 0x7FFFu + ((ua >> 16) & 1u)) >> 16;
    ub = (ub + 0x7FFFu + ((ub >> 16) & 1u)) >> 16;
    return ua | (ub << 16);
}
__device__ __forceinline__ float2 bf2f2(unsigned u) {
    float2 f;
    f.x = __uint_as_float(u << 16);
    f.y = __uint_as_float(u & 0xFFFF0000u);
    return f;
}

// ---------------- edge-index dtype detection + repack ----------------
__global__ void k_detect(const unsigned* __restrict__ e_raw, int* __restrict__ flag) {
    __shared__ int nz;
    if (threadIdx.x == 0) nz = 0;
    __syncthreads();
    int cnt = 0;
    for (int i = threadIdx.x; i < 2048; i += 256)
        if (e_raw[2 * i + 1] != 0u) cnt = 1;
    if (cnt) atomicOr(&nz, 1);
    __syncthreads();
    if (threadIdx.x == 0) *flag = (nz == 0) ? 1 : 0;   // 1 == int64 layout
}

__global__ __launch_bounds__(256) void k_repack(const void* __restrict__ e_raw,
        const int* __restrict__ flag, int* __restrict__ edges) {
    int i = blockIdx.x * 256 + threadIdx.x;
    if (i >= 2 * N_EDGES) return;
    if (*flag) edges[i] = (int)((const long long*)e_raw)[i];
    else       edges[i] = ((const int*)e_raw)[i];
}

// ---------------- weight pre-swizzle: fp32 -> f16 B-fragment layout ------
// dest half index t within a matrix: frag = t>>9 (512 halves = 64 lanes x 8),
// lane = (t&511)>>3, j = t&7. frag = kc*nnt + nt.
// B[k][n]: k = kc*32 + (lane>>4)*8 + j, n = nt*16 + (lane&15).
__global__ __launch_bounds__(256) void k_wswz(const float* __restrict__ We,
        const float* __restrict__ Wd, const float* __restrict__ Wo,
        _Float16* __restrict__ swz) {
    int t = blockIdx.x * 256 + threadIdx.x;
    if (t >= 32768) return;
    const float* W; int base, N;
    if (t < 8192)       { W = We; base = 0;     N = 64;  }
    else if (t < 16384) { W = Wd; base = 8192;  N = 128; }
    else                { W = Wo; base = 16384; N = 128; }
    int loc = t - base;
    int nnt = N >> 4;
    int frag = loc >> 9, r = loc & 511, lane = r >> 3, j = r & 7;
    int kc = frag / nnt, nt = frag - kc * nnt;
    int k = kc * 32 + ((lane >> 4) << 3) + j;
    int n = nt * 16 + (lane & 15);
    swz[t] = (_Float16)W[k * N + n];
}

// ---------------- K1: h(bf16) = x @ W_gat ; a_src/a_dst head dots --------
__global__ __launch_bounds__(256) void k_gat_lin(const float* __restrict__ x,
        const float* __restrict__ W, const float* __restrict__ att_s,
        const float* __restrict__ att_d, unsigned* __restrict__ h_bf,
        float* __restrict__ a_src, float* __restrict__ a_dst) {
    __shared__ float sx[BM][128];   // 32 KB
    const int m0 = blockIdx.x * BM;
    const int tid = threadIdx.x;

    for (int i = tid; i < BM * 32; i += 256) {
        int r = i >> 5, c4 = i & 31;
        int row = m0 + r; if (row >= N_NODES) row = N_NODES - 1;
        *(float4*)&sx[r][c4 * 4] = ((const float4*)(x + (size_t)row * 128))[c4];
    }
    __syncthreads();

    const int c0 = (tid & 31) * 4;
    const int r0 = (tid >> 5) * 8;
    float acc[8][4];
#pragma unroll
    for (int r = 0; r < 8; r++)
#pragma unroll
        for (int c = 0; c < 4; c++) acc[r][c] = 0.f;

    for (int k = 0; k < 128; k += 4) {
        float4 w0 = *(const float4*)&W[(k + 0) * 128 + c0];
        float4 w1 = *(const float4*)&W[(k + 1) * 128 + c0];
        float4 w2 = *(const float4*)&W[(k + 2) * 128 + c0];
        float4 w3 = *(const float4*)&W[(k + 3) * 128 + c0];
#pragma unroll
        for (int r = 0; r < 8; r++) {
            float4 xv = *(const float4*)&sx[r0 + r][k];
            acc[r][0] = fmaf(xv.x, w0.x, acc[r][0]);
            acc[r][0] = fmaf(xv.y, w1.x, acc[r][0]);
            acc[r][0] = fmaf(xv.z, w2.x, acc[r][0]);
            acc[r][0] = fmaf(xv.w, w3.x, acc[r][0]);
            acc[r][1] = fmaf(xv.x, w0.y, acc[r][1]);
            acc[r][1] = fmaf(xv.y, w1.y, acc[r][1]);
            acc[r][1] = fmaf(xv.z, w2.y, acc[r][1]);
            acc[r][1] = fmaf(xv.w, w3.y, acc[r][1]);
            acc[r][2] = fmaf(xv.x, w0.z, acc[r][2]);
            acc[r][2] = fmaf(xv.y, w1.z, acc[r][2]);
            acc[r][2] = fmaf(xv.z, w2.z, acc[r][2]);
            acc[r][2] = fmaf(xv.w, w3.z, acc[r][2]);
            acc[r][3] = fmaf(xv.x, w0.w, acc[r][3]);
            acc[r][3] = fmaf(xv.y, w1.w, acc[r][3]);
            acc[r][3] = fmaf(xv.z, w2.w, acc[r][3]);
            acc[r][3] = fmaf(xv.w, w3.w, acc[r][3]);
        }
    }

    float4 as4 = *(const float4*)&att_s[c0];
    float4 ad4 = *(const float4*)&att_d[c0];
    const int head = c0 >> 5;

#pragma unroll
    for (int r = 0; r < 8; r++) {
        int row = m0 + r0 + r;
        bool ok = row < N_NODES;
        if (ok) {
            uint2 p;
            p.x = f2bf2(acc[r][0], acc[r][1]);
            p.y = f2bf2(acc[r][2], acc[r][3]);
            *(uint2*)&h_bf[(size_t)row * 64 + (c0 >> 1)] = p;
        }
        float vs = acc[r][0] * as4.x + acc[r][1] * as4.y + acc[r][2] * as4.z + acc[r][3] * as4.w;
        float vd = acc[r][0] * ad4.x + acc[r][1] * ad4.y + acc[r][2] * ad4.z + acc[r][3] * ad4.w;
#pragma unroll
        for (int o = 4; o >= 1; o >>= 1) {
            vs += __shfl_down(vs, o, 8);
            vd += __shfl_down(vd, o, 8);
        }
        if (ok && (tid & 7) == 0) {
            a_src[row * 4 + head] = vs;
            a_dst[row * 4 + head] = vd;
        }
    }
}

// ---------------- CSR build v2: bucket sort with block-owned regions -----
__global__ __launch_bounds__(256) void k_bhist(const int* __restrict__ edges,
        int* __restrict__ bcnt) {
    __shared__ int lh[256];
    const int tid = threadIdx.x;
    lh[tid] = 0;
    __syncthreads();
    const int base = blockIdx.x * CHUNK;
#pragma unroll 4
    for (int j = 0; j < CHUNK / 256; j++) {
        int e = base + j * 256 + tid;
        if (e < N_EDGES) {
            int d = edges[N_EDGES + e];
            atomicAdd(&lh[d >> 8], 1);
        }
    }
    __syncthreads();
    if (lh[tid]) atomicAdd(&bcnt[tid], lh[tid]);
}

__global__ __launch_bounds__(256) void k_bscan(const int* __restrict__ bcnt,
        int* __restrict__ bbase, int* __restrict__ bcursor,
        int* __restrict__ off) {
    __shared__ int s[256];
    const int t = threadIdx.x;
    int v = bcnt[t];
    s[t] = v;
    __syncthreads();
    for (int o = 1; o < 256; o <<= 1) {
        int u = (t >= o) ? s[t - o] : 0;
        __syncthreads();
        s[t] += u;
        __syncthreads();
    }
    int exc = s[t] - v;
    bbase[t] = exc;
    bcursor[t] = exc;
    if (t == 0) {
        off[N_NODES] = N_EDGES;
    }
}

__global__ __launch_bounds__(256) void k_bucket(const int* __restrict__ edges,
        int* __restrict__ bcursor, uint2* __restrict__ ebuck) {
    __shared__ int lh[256];
    __shared__ int gbase[256];
    __shared__ int lcur[256];
    const int tid = threadIdx.x;
    const int base = blockIdx.x * CHUNK;

    lh[tid] = 0;
    __syncthreads();
#pragma unroll 4
    for (int j = 0; j < CHUNK / 256; j++) {
        int e = base + j * 256 + tid;
        if (e < N_EDGES) {
            int d = edges[N_EDGES + e];
            atomicAdd(&lh[d >> 8], 1);
        }
    }
    __syncthreads();
    if (lh[tid]) gbase[tid] = atomicAdd(&bcursor[tid], lh[tid]);
    lcur[tid] = 0;
    __syncthreads();
#pragma unroll 4
    for (int j = 0; j < CHUNK / 256; j++) {
        int e = base + j * 256 + tid;
        if (e < N_EDGES) {
            int sN = edges[e];
            int d  = edges[N_EDGES + e];
            int b  = d >> 8;
            int p  = gbase[b] + atomicAdd(&lcur[b], 1);
            uint2 pr; pr.x = (unsigned)sN; pr.y = (unsigned)d;
            ebuck[p] = pr;
        }
    }
}

__global__ __launch_bounds__(256) void k_bfill(const uint2* __restrict__ ebuck,
        const int* __restrict__ bbase, int* __restrict__ off,
        int* __restrict__ csr_src) {
    __shared__ int lh[256];
    __shared__ int lexc[256];
    __shared__ int lcur[256];
    const int tid = threadIdx.x;
    const int b = blockIdx.x;
    const int lo = bbase[b], hi = bbase[b + 1];
    const int n0 = b << 8;

    lh[tid] = 0;
    lcur[tid] = 0;
    __syncthreads();
    for (int i = lo + tid; i < hi; i += 256)
        atomicAdd(&lh[ebuck[i].y & 255], 1);
    __syncthreads();
    {
        int v = lh[tid];
        int s = v;
        lexc[tid] = v;
        __syncthreads();
        for (int o = 1; o < 256; o <<= 1) {
            int u = (tid >= o) ? lexc[tid - o] : 0;
            __syncthreads();
            lexc[tid] += u;
            __syncthreads();
        }
        s = lexc[tid] - v;
        __syncthreads();
        lexc[tid] = s;
        int node = n0 + tid;
        if (node < N_NODES) off[node] = lo + s;
    }
    __syncthreads();
    for (int i = lo + tid; i < hi; i += 256) {
        uint2 pr = ebuck[i];
        int li = (int)(pr.y & 255);
        int p = atomicAdd(&lcur[li], 1);
        csr_src[lo + lexc[li] + p] = (int)pr.x;
    }
}

// ---------------- K3: CSR gather — single-pass softmax, 4x unrolled ------
__global__ __launch_bounds__(256) void k_gather(const int* __restrict__ off,
        const int* __restrict__ csr_src, const float* __restrict__ a_src,
        const float* __restrict__ a_dst, const unsigned* __restrict__ h_bf,
        float* __restrict__ agg) {
    int d = blockIdx.x * 4 + (threadIdx.x >> 6);
    if (d >= N_NODES) return;
    const int lane = threadIdx.x & 63;
    const int hd = lane >> 4;
    const int lo = off[d], hi = off[d + 1];

    const float adh = a_dst[d * 4 + hd];

    float t = a_src[d * 4 + hd] + adh;
    t = t > 0.f ? t : 0.2f * t;
    float eself = __expf(t);
    float den = eself;
    float2 hs = bf2f2(h_bf[(size_t)d * 64 + lane]);
    float accx = hs.x * eself, accy = hs.y * eself;

    int i = lo;
    for (; i + 4 <= hi; i += 4) {
        int s0 = csr_src[i + 0];
        int s1 = csr_src[i + 1];
        int s2 = csr_src[i + 2];
        int s3 = csr_src[i + 3];
        unsigned u0 = h_bf[(size_t)s0 * 64 + lane];
        unsigned u1 = h_bf[(size_t)s1 * 64 + lane];
        unsigned u2 = h_bf[(size_t)s2 * 64 + lane];
        unsigned u3 = h_bf[(size_t)s3 * 64 + lane];
        float a0 = a_src[s0 * 4 + hd];
        float a1 = a_src[s1 * 4 + hd];
        float a2 = a_src[s2 * 4 + hd];
        float a3 = a_src[s3 * 4 + hd];

        float t0 = a0 + adh; t0 = t0 > 0.f ? t0 : 0.2f * t0;
        float t1 = a1 + adh; t1 = t1 > 0.f ? t1 : 0.2f * t1;
        float t2 = a2 + adh; t2 = t2 > 0.f ? t2 : 0.2f * t2;
        float t3 = a3 + adh; t3 = t3 > 0.f ? t3 : 0.2f * t3;
        float e0 = __expf(t0);
        float e1 = __expf(t1);
        float e2 = __expf(t2);
        float e3 = __expf(t3);
        den += (e0 + e1) + (e2 + e3);

        float2 h0 = bf2f2(u0);
        float2 h1 = bf2f2(u1);
        float2 h2 = bf2f2(u2);
        float2 h3 = bf2f2(u3);
        accx = fmaf(h0.x, e0, accx);
        accy = fmaf(h0.y, e0, accy);
        accx = fmaf(h1.x, e1, accx);
        accy = fmaf(h1.y, e1, accy);
        accx = fmaf(h2.x, e2, accx);
        accy = fmaf(h2.y, e2, accy);
        accx = fmaf(h3.x, e3, accx);
        accy = fmaf(h3.y, e3, accy);
    }
    for (; i < hi; i++) {
        int s = csr_src[i];
        float tt = a_src[s * 4 + hd] + adh;
        tt = tt > 0.f ? tt : 0.2f * tt;
        float e = __expf(tt);
        den += e;
        float2 hv = bf2f2(h_bf[(size_t)s * 64 + lane]);
        accx = fmaf(hv.x, e, accx);
        accy = fmaf(hv.y, e, accy);
    }
    float inv = 1.f / (den + 1e-16f);
    float2 o2; o2.x = accx * inv; o2.y = accy * inv;
    ((float2*)agg)[(size_t)d * 64 + lane] = o2;
}

// ---------------- K4: fused MLP via MFMA f16 -----------------------------
// 64 rows/block, 4 waves; wave w owns rows w*16..w*16+15 (slab).
// A-layout (16x16x32): lane holds A[m=lane&15][k=(lane>>4)*8+j], j=0..7.
// C/D layout: col=lane&15, row=(lane>>4)*4+reg.
// sx: x1 (f16, row-major [64][128]) then overwritten per-slab by x2.
// se: E slabs [wave][16][64] f16. One __syncthreads (after stage 0);
// all later LDS traffic is wave-local.
__global__ __launch_bounds__(256) void k_mlp(const float* __restrict__ agg,
        const float* __restrict__ b_gat, const _Float16* __restrict__ swz,
        const float* __restrict__ b_enc, const float* __restrict__ b_dec,
        const float* __restrict__ b_out, float* __restrict__ out) {
    __shared__ _Float16 sx[64 * 128];    // 16 KB
    __shared__ _Float16 se[4 * 16 * 64]; // 8 KB
    const int tid = threadIdx.x;
    const int m0 = blockIdx.x * 64;

    // stage 0: x1 = elu(agg + b_gat) -> sx (f16)
#pragma unroll
    for (int i = 0; i < 8; i++) {
        int idx = tid + i * 256;        // float4 index over 64x32
        int r = idx >> 5, c4 = idx & 31;
        int row = m0 + r; if (row >= N_NODES) row = N_NODES - 1;
        float4 v = ((const float4*)(agg + (size_t)row * 128))[c4];
        float4 bg = ((const float4*)b_gat)[c4];
        half4v h;
        h[0] = (_Float16)elu_f(v.x + bg.x);
        h[1] = (_Float16)elu_f(v.y + bg.y);
        h[2] = (_Float16)elu_f(v.z + bg.z);
        h[3] = (_Float16)elu_f(v.w + bg.w);
        *(half4v*)&sx[r * 128 + c4 * 4] = h;
    }
    __syncthreads();

    const int wave = tid >> 6, lane = tid & 63;
    const int lm = lane & 15, lq = lane >> 4;
    const int wrow = wave * 16;
    _Float16* eslab = &se[wave * 16 * 64];

    // L1: E = X1 @ W_enc + b_enc   (16x64 per wave, K=128)
    {
        float4v acc[4];
#pragma unroll
        for (int nt = 0; nt < 4; nt++) acc[nt] = (float4v){0.f, 0.f, 0.f, 0.f};
#pragma unroll
        for (int kc = 0; kc < 4; kc++) {
            half8 a = *(const half8*)&sx[(wrow + lm) * 128 + kc * 32 + lq * 8];
#pragma unroll
            for (int nt = 0; nt < 4; nt++) {
                half8 b = *(const half8*)&swz[(kc * 4 + nt) * 512 + lane * 8];
                acc[nt] = __builtin_amdgcn_mfma_f32_16x16x32_f16(a, b, acc[nt], 0, 0, 0);
            }
        }
#pragma unroll
        for (int nt = 0; nt < 4; nt++) {
            float be = b_enc[nt * 16 + lm];
#pragma unroll
            for (int r = 0; r < 4; r++)
                eslab[(lq * 4 + r) * 64 + nt * 16 + lm] = (_Float16)(acc[nt][r] + be);
        }
    }

    // L2: X2 = elu(E @ W_dec + b_dec)  (16x128 per wave, K=64) -> sx slab
    {
        float4v acc[8];
#pragma unroll
        for (int nt = 0; nt < 8; nt++) acc[nt] = (float4v){0.f, 0.f, 0.f, 0.f};
#pragma unroll
        for (int kc = 0; kc < 2; kc++) {
            half8 a = *(const half8*)&eslab[lm * 64 + kc * 32 + lq * 8];
#pragma unroll
            for (int nt = 0; nt < 8; nt++) {
                half8 b = *(const half8*)&swz[8192 + (kc * 8 + nt) * 512 + lane * 8];
                acc[nt] = __builtin_amdgcn_mfma_f32_16x16x32_f16(a, b, acc[nt], 0, 0, 0);
            }
        }
#pragma unroll
        for (int nt = 0; nt < 8; nt++) {
            float bd = b_dec[nt * 16 + lm];
#pragma unroll
            for (int r = 0; r < 4; r++)
                sx[(wrow + lq * 4 + r) * 128 + nt * 16 + lm] =
                    (_Float16)elu_f(acc[nt][r] + bd);
        }
    }

    // L3: OUT = X2 @ W_out + b_out  (16x128 per wave, K=128)
    {
        float4v acc[8];
#pragma unroll
        for (int nt = 0; nt < 8; nt++) acc[nt] = (float4v){0.f, 0.f, 0.f, 0.f};
#pragma unroll
        for (int kc = 0; kc < 4; kc++) {
            half8 a = *(const half8*)&sx[(wrow + lm) * 128 + kc * 32 + lq * 8];
#pragma unroll
            for (int nt = 0; nt < 8; nt++) {
                half8 b = *(const half8*)&swz[16384 + (kc * 8 + nt) * 512 + lane * 8];
                acc[nt] = __builtin_amdgcn_mfma_f32_16x16x32_f16(a, b, acc[nt], 0, 0, 0);
            }
        }
#pragma unroll
        for (int nt = 0; nt < 8; nt++) {
            float bo = b_out[nt * 16 + lm];
#pragma unroll
            for (int r = 0; r < 4; r++) {
                int row = m0 + wrow + lq * 4 + r;
                if (row < N_NODES)
                    out[(size_t)row * 128 + nt * 16 + lm] = acc[nt][r] + bo;
            }
        }
    }
}

extern "C" void kernel_launch(void* const* d_in, const int* in_sizes, int n_in,
                              void* d_out, int out_size, void* d_ws, size_t ws_size,
                              hipStream_t stream) {
    const float* x       = (const float*)d_in[0];
    const void*  e_raw   = d_in[1];
    const float* W_gat   = (const float*)d_in[2];
    const float* b_gat   = (const float*)d_in[3];
    const float* att_src = (const float*)d_in[4];
    const float* att_dst = (const float*)d_in[5];
    const float* W_enc   = (const float*)d_in[6];
    const float* b_enc   = (const float*)d_in[7];
    const float* W_dec   = (const float*)d_in[8];
    const float* b_dec   = (const float*)d_in[9];
    const float* W_out   = (const float*)d_in[10];
    const float* b_out   = (const float*)d_in[11];
    float* out = (float*)d_out;

    float* ws      = (float*)d_ws;
    float*   hreg  = ws;                       // 6,400,000 f
    unsigned* h_bf = (unsigned*)hreg;          // 3,200,000 u (50000 x 64)
    float* a_src   = hreg + 6400000;           // 200,000 f
    float* a_dst   = a_src + 200000;           // 200,000 f
    float* agg     = a_dst + 200000;           // 6,400,000 f
    uint2* ebuck   = (uint2*)agg;              // aliases agg (dead before k_gather)
    int*   edges   = (int*)(agg + 6400000);    // 1,600,000 i
    int*   csr_src = edges + 1600000;          // 800,000 i
    int*   off     = csr_src + 800000;         // 50,001 i
    int*   flag    = off + 50001;              // 1 i
    int*   bcnt    = flag + 1;                 // 256 i
    int*   bbase   = bcnt + 256;               // 257 i
    int*   bcursor = bbase + 257;              // 256 i
    _Float16* swz  = (_Float16*)(((uintptr_t)(bcursor + 256) + 15) & ~(uintptr_t)15); // 32768 f16

    const int GBLK = (N_NODES + BM - 1) / BM;  // 782

    k_detect<<<1, 256, 0, stream>>>((const unsigned*)e_raw, flag);
    k_repack<<<(2 * N_EDGES + 255) / 256, 256, 0, stream>>>(e_raw, flag, edges);
    k_wswz<<<128, 256, 0, stream>>>(W_enc, W_dec, W_out, swz);

    k_gat_lin<<<GBLK, 256, 0, stream>>>(x, W_gat, att_src, att_dst, h_bf, a_src, a_dst);

    hipMemsetAsync(bcnt, 0, 256 * sizeof(int), stream);
    k_bhist<<<NB_BUCKET_BLOCKS, 256, 0, stream>>>(edges, bcnt);
    k_bscan<<<1, 256, 0, stream>>>(bcnt, bbase, bcursor, off);
    k_bucket<<<NB_BUCKET_BLOCKS, 256, 0, stream>>>(edges, bcursor, ebuck);
    k_bfill<<<NBUCK, 256, 0, stream>>>(ebuck, bbase, off, csr_src);

    k_gather<<<(N_NODES + 3) / 4, 256, 0, stream>>>(off, csr_src, a_src, a_dst, h_bf, agg);

    k_mlp<<<GBLK, 256, 0, stream>>>(agg, b_gat, swz, b_enc, b_dec, b_out, out);
}

// Round 10
// 229.257 us; speedup vs baseline: 5.3330x; 1.0727x over previous
//
#include <hip/hip_runtime.h>
#include <hip/hip_bf16.h>

#define N_NODES 50000
#define N_EDGES 800000
#define BM 64
#define NBUCK 196            // buckets of 256 nodes: d >> 8
#define CAP 6144             // fixed capacity per bucket (mean 4081, >30 sigma)
#define CHUNK 8192           // edges per block in bucket pass
#define NB_BUCKET_BLOCKS ((N_EDGES + CHUNK - 1) / CHUNK)   // 98
#define REPACK_BLOCKS (2 * N_EDGES / 256)                  // 6250

typedef _Float16 half4v __attribute__((ext_vector_type(4)));
typedef _Float16 half8  __attribute__((ext_vector_type(8)));
typedef float    float4v __attribute__((ext_vector_type(4)));

__device__ __forceinline__ float elu_f(float v) {
    return (v > 0.f) ? v : (__expf(v) - 1.f);
}

// pack two fp32 -> packed bf16x2 (RNE)
__device__ __forceinline__ unsigned f2bf2(float a, float b) {
    unsigned ua = __float_as_uint(a), ub = __float_as_uint(b);
    ua = (ua + 0x7FFFu + ((ua >> 16) & 1u)) >> 16;
    ub = (ub + 0x7FFFu + ((ub >> 16) & 1u)) >> 16;
    return ua | (ub << 16);
}
__device__ __forceinline__ float2 bf2f2(unsigned u) {
    float2 f;
    f.x = __uint_as_float(u << 16);
    f.y = __uint_as_float(u & 0xFFFF0000u);
    return f;
}

// ---------------- edge-index dtype detection ----------------
__global__ void k_detect(const unsigned* __restrict__ e_raw, int* __restrict__ flag) {
    __shared__ int nz;
    if (threadIdx.x == 0) nz = 0;
    __syncthreads();
    int cnt = 0;
    for (int i = threadIdx.x; i < 2048; i += 256)
        if (e_raw[2 * i + 1] != 0u) cnt = 1;
    if (cnt) atomicOr(&nz, 1);
    __syncthreads();
    if (threadIdx.x == 0) *flag = (nz == 0) ? 1 : 0;   // 1 == int64 layout
}

// ---------------- fused pre-pass: repack + weight swizzle + bcursor zero --
__global__ __launch_bounds__(256) void k_pre(const void* __restrict__ e_raw,
        const int* __restrict__ flag, int* __restrict__ edges,
        const float* __restrict__ We, const float* __restrict__ Wd,
        const float* __restrict__ Wo, _Float16* __restrict__ swz,
        int* __restrict__ bcursor) {
    const int b = blockIdx.x;
    const int tid = threadIdx.x;
    if (b < REPACK_BLOCKS) {
        int i = b * 256 + tid;
        if (*flag) edges[i] = (int)((const long long*)e_raw)[i];
        else       edges[i] = ((const int*)e_raw)[i];
    } else if (b < REPACK_BLOCKS + 128) {
        int t = (b - REPACK_BLOCKS) * 256 + tid;
        const float* W; int base, N;
        if (t < 8192)       { W = We; base = 0;     N = 64;  }
        else if (t < 16384) { W = Wd; base = 8192;  N = 128; }
        else                { W = Wo; base = 16384; N = 128; }
        int loc = t - base;
        int nnt = N >> 4;
        int frag = loc >> 9, r = loc & 511, lane = r >> 3, j = r & 7;
        int kc = frag / nnt, nt = frag - kc * nnt;
        int k = kc * 32 + ((lane >> 4) << 3) + j;
        int n = nt * 16 + (lane & 15);
        swz[t] = (_Float16)W[k * N + n];
    } else {
        bcursor[tid] = 0;
    }
}

// ---------------- K1: h(bf16) = x @ W_gat ; a_src/a_dst head dots --------
__global__ __launch_bounds__(256) void k_gat_lin(const float* __restrict__ x,
        const float* __restrict__ W, const float* __restrict__ att_s,
        const float* __restrict__ att_d, unsigned* __restrict__ h_bf,
        float* __restrict__ a_src, float* __restrict__ a_dst) {
    __shared__ float sx[BM][128];   // 32 KB
    const int m0 = blockIdx.x * BM;
    const int tid = threadIdx.x;

    for (int i = tid; i < BM * 32; i += 256) {
        int r = i >> 5, c4 = i & 31;
        int row = m0 + r; if (row >= N_NODES) row = N_NODES - 1;
        *(float4*)&sx[r][c4 * 4] = ((const float4*)(x + (size_t)row * 128))[c4];
    }
    __syncthreads();

    const int c0 = (tid & 31) * 4;
    const int r0 = (tid >> 5) * 8;
    float acc[8][4];
#pragma unroll
    for (int r = 0; r < 8; r++)
#pragma unroll
        for (int c = 0; c < 4; c++) acc[r][c] = 0.f;

    for (int k = 0; k < 128; k += 4) {
        float4 w0 = *(const float4*)&W[(k + 0) * 128 + c0];
        float4 w1 = *(const float4*)&W[(k + 1) * 128 + c0];
        float4 w2 = *(const float4*)&W[(k + 2) * 128 + c0];
        float4 w3 = *(const float4*)&W[(k + 3) * 128 + c0];
#pragma unroll
        for (int r = 0; r < 8; r++) {
            float4 xv = *(const float4*)&sx[r0 + r][k];
            acc[r][0] = fmaf(xv.x, w0.x, acc[r][0]);
            acc[r][0] = fmaf(xv.y, w1.x, acc[r][0]);
            acc[r][0] = fmaf(xv.z, w2.x, acc[r][0]);
            acc[r][0] = fmaf(xv.w, w3.x, acc[r][0]);
            acc[r][1] = fmaf(xv.x, w0.y, acc[r][1]);
            acc[r][1] = fmaf(xv.y, w1.y, acc[r][1]);
            acc[r][1] = fmaf(xv.z, w2.y, acc[r][1]);
            acc[r][1] = fmaf(xv.w, w3.y, acc[r][1]);
            acc[r][2] = fmaf(xv.x, w0.z, acc[r][2]);
            acc[r][2] = fmaf(xv.y, w1.z, acc[r][2]);
            acc[r][2] = fmaf(xv.z, w2.z, acc[r][2]);
            acc[r][2] = fmaf(xv.w, w3.z, acc[r][2]);
            acc[r][3] = fmaf(xv.x, w0.w, acc[r][3]);
            acc[r][3] = fmaf(xv.y, w1.w, acc[r][3]);
            acc[r][3] = fmaf(xv.z, w2.w, acc[r][3]);
            acc[r][3] = fmaf(xv.w, w3.w, acc[r][3]);
        }
    }

    float4 as4 = *(const float4*)&att_s[c0];
    float4 ad4 = *(const float4*)&att_d[c0];
    const int head = c0 >> 5;

#pragma unroll
    for (int r = 0; r < 8; r++) {
        int row = m0 + r0 + r;
        bool ok = row < N_NODES;
        if (ok) {
            uint2 p;
            p.x = f2bf2(acc[r][0], acc[r][1]);
            p.y = f2bf2(acc[r][2], acc[r][3]);
            *(uint2*)&h_bf[(size_t)row * 64 + (c0 >> 1)] = p;
        }
        float vs = acc[r][0] * as4.x + acc[r][1] * as4.y + acc[r][2] * as4.z + acc[r][3] * as4.w;
        float vd = acc[r][0] * ad4.x + acc[r][1] * ad4.y + acc[r][2] * ad4.z + acc[r][3] * ad4.w;
#pragma unroll
        for (int o = 4; o >= 1; o >>= 1) {
            vs += __shfl_down(vs, o, 8);
            vd += __shfl_down(vd, o, 8);
        }
        if (ok && (tid & 7) == 0) {
            a_src[row * 4 + head] = vs;
            a_dst[row * 4 + head] = vd;
        }
    }
}

// ---------------- CSR build v3: single-pass fixed-cap bucket sort --------
__global__ __launch_bounds__(256) void k_bucket(const int* __restrict__ edges,
        int* __restrict__ bcursor, uint2* __restrict__ ebuck) {
    __shared__ int lh[256];
    __shared__ int gbase[256];
    __shared__ int lcur[256];
    const int tid = threadIdx.x;
    const int base = blockIdx.x * CHUNK;

    lh[tid] = 0;
    __syncthreads();
#pragma unroll 4
    for (int j = 0; j < CHUNK / 256; j++) {
        int e = base + j * 256 + tid;
        if (e < N_EDGES) {
            int d = edges[N_EDGES + e];
            atomicAdd(&lh[d >> 8], 1);
        }
    }
    __syncthreads();
    if (lh[tid]) gbase[tid] = atomicAdd(&bcursor[tid], lh[tid]);
    lcur[tid] = 0;
    __syncthreads();
#pragma unroll 4
    for (int j = 0; j < CHUNK / 256; j++) {
        int e = base + j * 256 + tid;
        if (e < N_EDGES) {
            int sN = edges[e];
            int d  = edges[N_EDGES + e];
            int b  = d >> 8;
            int idx = gbase[b] + atomicAdd(&lcur[b], 1);
            if (idx < CAP) {    // defensive; statistically impossible to trip
                uint2 pr; pr.x = (unsigned)sN; pr.y = (unsigned)d;
                ebuck[b * CAP + idx] = pr;
            }
        }
    }
}

// per-bucket fine sort -> nodeoff(start,deg) + csr_src (block-owned region)
__global__ __launch_bounds__(256) void k_bfill(const uint2* __restrict__ ebuck,
        const int* __restrict__ bcursor, int2* __restrict__ nodeoff,
        int* __restrict__ csr_src) {
    __shared__ int lh[256];
    __shared__ int lexc[256];
    __shared__ int lcur[256];
    const int tid = threadIdx.x;
    const int b = blockIdx.x;
    const int lo = b * CAP;
    int cnt = bcursor[b]; if (cnt > CAP) cnt = CAP;
    const int hi = lo + cnt;
    const int n0 = b << 8;

    lh[tid] = 0;
    lcur[tid] = 0;
    __syncthreads();
    for (int i = lo + tid; i < hi; i += 256)
        atomicAdd(&lh[ebuck[i].y & 255], 1);
    __syncthreads();
    {
        int v = lh[tid];
        lexc[tid] = v;
        __syncthreads();
        for (int o = 1; o < 256; o <<= 1) {
            int u = (tid >= o) ? lexc[tid - o] : 0;
            __syncthreads();
            lexc[tid] += u;
            __syncthreads();
        }
        int s = lexc[tid] - v;   // exclusive
        __syncthreads();
        lexc[tid] = s;
        int node = n0 + tid;
        if (node < N_NODES) {
            int2 no; no.x = lo + s; no.y = v;
            nodeoff[node] = no;
        }
    }
    __syncthreads();
    for (int i = lo + tid; i < hi; i += 256) {
        uint2 pr = ebuck[i];
        int li = (int)(pr.y & 255);
        int p = atomicAdd(&lcur[li], 1);
        csr_src[lo + lexc[li] + p] = (int)pr.x;
    }
}

// ---------------- K3: CSR gather — 2 edges/wave, 4 ch/lane ---------------
// wave per node; lanes 0-31 even edges, 32-63 odd edges.
__global__ __launch_bounds__(256) void k_gather(const int2* __restrict__ nodeoff,
        const int* __restrict__ csr_src, const float* __restrict__ a_src,
        const float* __restrict__ a_dst, const unsigned* __restrict__ h_bf,
        float* __restrict__ agg) {
    int d = blockIdx.x * 4 + (threadIdx.x >> 6);
    if (d >= N_NODES) return;
    const int lane = threadIdx.x & 63;
    const int half = lane >> 5;
    const int l32 = lane & 31;
    const int hd = l32 >> 3;             // head of channels 4*l32..+3
    int2 nd = nodeoff[d];
    const int lo = nd.x, hi = nd.x + nd.y;

    const float adh = a_dst[d * 4 + hd];

    float den = 0.f;
    float ax = 0.f, ay = 0.f, az = 0.f, aw = 0.f;

    if (half == 0) {   // self-loop on half 0
        float t = a_src[d * 4 + hd] + adh;
        t = t > 0.f ? t : 0.2f * t;
        float es = __expf(t);
        den = es;
        uint2 hu = ((const uint2*)(h_bf + (size_t)d * 64))[l32];
        float2 c01 = bf2f2(hu.x), c23 = bf2f2(hu.y);
        ax = c01.x * es; ay = c01.y * es;
        az = c23.x * es; aw = c23.y * es;
    }

    int base = lo;
    for (; base + 8 <= hi; base += 8) {
        int i0 = base + half;
        int s0 = csr_src[i0 + 0];
        int s1 = csr_src[i0 + 2];
        int s2 = csr_src[i0 + 4];
        int s3 = csr_src[i0 + 6];
        uint2 u0 = ((const uint2*)(h_bf + (size_t)s0 * 64))[l32];
        uint2 u1 = ((const uint2*)(h_bf + (size_t)s1 * 64))[l32];
        uint2 u2 = ((const uint2*)(h_bf + (size_t)s2 * 64))[l32];
        uint2 u3 = ((const uint2*)(h_bf + (size_t)s3 * 64))[l32];
        float a0 = a_src[s0 * 4 + hd];
        float a1 = a_src[s1 * 4 + hd];
        float a2 = a_src[s2 * 4 + hd];
        float a3 = a_src[s3 * 4 + hd];

        float t0 = a0 + adh; t0 = t0 > 0.f ? t0 : 0.2f * t0;
        float t1 = a1 + adh; t1 = t1 > 0.f ? t1 : 0.2f * t1;
        float t2 = a2 + adh; t2 = t2 > 0.f ? t2 : 0.2f * t2;
        float t3 = a3 + adh; t3 = t3 > 0.f ? t3 : 0.2f * t3;
        float e0 = __expf(t0);
        float e1 = __expf(t1);
        float e2 = __expf(t2);
        float e3 = __expf(t3);
        den += (e0 + e1) + (e2 + e3);

        float2 p, q;
        p = bf2f2(u0.x); q = bf2f2(u0.y);
        ax = fmaf(p.x, e0, ax); ay = fmaf(p.y, e0, ay);
        az = fmaf(q.x, e0, az); aw = fmaf(q.y, e0, aw);
        p = bf2f2(u1.x); q = bf2f2(u1.y);
        ax = fmaf(p.x, e1, ax); ay = fmaf(p.y, e1, ay);
        az = fmaf(q.x, e1, az); aw = fmaf(q.y, e1, aw);
        p = bf2f2(u2.x); q = bf2f2(u2.y);
        ax = fmaf(p.x, e2, ax); ay = fmaf(p.y, e2, ay);
        az = fmaf(q.x, e2, az); aw = fmaf(q.y, e2, aw);
        p = bf2f2(u3.x); q = bf2f2(u3.y);
        ax = fmaf(p.x, e3, ax); ay = fmaf(p.y, e3, ay);
        az = fmaf(q.x, e3, az); aw = fmaf(q.y, e3, aw);
    }
    for (int i = base + half; i < hi; i += 2) {
        int s = csr_src[i];
        float tt = a_src[s * 4 + hd] + adh;
        tt = tt > 0.f ? tt : 0.2f * tt;
        float e = __expf(tt);
        den += e;
        uint2 hu = ((const uint2*)(h_bf + (size_t)s * 64))[l32];
        float2 p = bf2f2(hu.x), q = bf2f2(hu.y);
        ax = fmaf(p.x, e, ax); ay = fmaf(p.y, e, ay);
        az = fmaf(q.x, e, az); aw = fmaf(q.y, e, aw);
    }

    // merge halves
    den += __shfl_xor(den, 32);
    ax += __shfl_xor(ax, 32);
    ay += __shfl_xor(ay, 32);
    az += __shfl_xor(az, 32);
    aw += __shfl_xor(aw, 32);

    if (half == 0) {
        float inv = 1.f / (den + 1e-16f);
        float4 o; o.x = ax * inv; o.y = ay * inv; o.z = az * inv; o.w = aw * inv;
        ((float4*)(agg + (size_t)d * 128))[l32] = o;
    }
}

// ---------------- K4: fused MLP via MFMA f16 -----------------------------
__global__ __launch_bounds__(256) void k_mlp(const float* __restrict__ agg,
        const float* __restrict__ b_gat, const _Float16* __restrict__ swz,
        const float* __restrict__ b_enc, const float* __restrict__ b_dec,
        const float* __restrict__ b_out, float* __restrict__ out) {
    __shared__ _Float16 sx[64 * 128];    // 16 KB
    __shared__ _Float16 se[4 * 16 * 64]; // 8 KB
    const int tid = threadIdx.x;
    const int m0 = blockIdx.x * 64;

#pragma unroll
    for (int i = 0; i < 8; i++) {
        int idx = tid + i * 256;
        int r = idx >> 5, c4 = idx & 31;
        int row = m0 + r; if (row >= N_NODES) row = N_NODES - 1;
        float4 v = ((const float4*)(agg + (size_t)row * 128))[c4];
        float4 bg = ((const float4*)b_gat)[c4];
        half4v h;
        h[0] = (_Float16)elu_f(v.x + bg.x);
        h[1] = (_Float16)elu_f(v.y + bg.y);
        h[2] = (_Float16)elu_f(v.z + bg.z);
        h[3] = (_Float16)elu_f(v.w + bg.w);
        *(half4v*)&sx[r * 128 + c4 * 4] = h;
    }
    __syncthreads();

    const int wave = tid >> 6, lane = tid & 63;
    const int lm = lane & 15, lq = lane >> 4;
    const int wrow = wave * 16;
    _Float16* eslab = &se[wave * 16 * 64];

    // L1: E = X1 @ W_enc + b_enc
    {
        float4v acc[4];
#pragma unroll
        for (int nt = 0; nt < 4; nt++) acc[nt] = (float4v){0.f, 0.f, 0.f, 0.f};
#pragma unroll
        for (int kc = 0; kc < 4; kc++) {
            half8 a = *(const half8*)&sx[(wrow + lm) * 128 + kc * 32 + lq * 8];
#pragma unroll
            for (int nt = 0; nt < 4; nt++) {
                half8 b = *(const half8*)&swz[(kc * 4 + nt) * 512 + lane * 8];
                acc[nt] = __builtin_amdgcn_mfma_f32_16x16x32_f16(a, b, acc[nt], 0, 0, 0);
            }
        }
#pragma unroll
        for (int nt = 0; nt < 4; nt++) {
            float be = b_enc[nt * 16 + lm];
#pragma unroll
            for (int r = 0; r < 4; r++)
                eslab[(lq * 4 + r) * 64 + nt * 16 + lm] = (_Float16)(acc[nt][r] + be);
        }
    }

    // L2: X2 = elu(E @ W_dec + b_dec) -> sx slab
    {
        float4v acc[8];
#pragma unroll
        for (int nt = 0; nt < 8; nt++) acc[nt] = (float4v){0.f, 0.f, 0.f, 0.f};
#pragma unroll
        for (int kc = 0; kc < 2; kc++) {
            half8 a = *(const half8*)&eslab[lm * 64 + kc * 32 + lq * 8];
#pragma unroll
            for (int nt = 0; nt < 8; nt++) {
                half8 b = *(const half8*)&swz[8192 + (kc * 8 + nt) * 512 + lane * 8];
                acc[nt] = __builtin_amdgcn_mfma_f32_16x16x32_f16(a, b, acc[nt], 0, 0, 0);
            }
        }
#pragma unroll
        for (int nt = 0; nt < 8; nt++) {
            float bd = b_dec[nt * 16 + lm];
#pragma unroll
            for (int r = 0; r < 4; r++)
                sx[(wrow + lq * 4 + r) * 128 + nt * 16 + lm] =
                    (_Float16)elu_f(acc[nt][r] + bd);
        }
    }

    // L3: OUT = X2 @ W_out + b_out
    {
        float4v acc[8];
#pragma unroll
        for (int nt = 0; nt < 8; nt++) acc[nt] = (float4v){0.f, 0.f, 0.f, 0.f};
#pragma unroll
        for (int kc = 0; kc < 4; kc++) {
            half8 a = *(const half8*)&sx[(wrow + lm) * 128 + kc * 32 + lq * 8];
#pragma unroll
            for (int nt = 0; nt < 8; nt++) {
                half8 b = *(const half8*)&swz[16384 + (kc * 8 + nt) * 512 + lane * 8];
                acc[nt] = __builtin_amdgcn_mfma_f32_16x16x32_f16(a, b, acc[nt], 0, 0, 0);
            }
        }
#pragma unroll
        for (int nt = 0; nt < 8; nt++) {
            float bo = b_out[nt * 16 + lm];
#pragma unroll
            for (int r = 0; r < 4; r++) {
                int row = m0 + wrow + lq * 4 + r;
                if (row < N_NODES)
                    out[(size_t)row * 128 + nt * 16 + lm] = acc[nt][r] + bo;
            }
        }
    }
}

extern "C" void kernel_launch(void* const* d_in, const int* in_sizes, int n_in,
                              void* d_out, int out_size, void* d_ws, size_t ws_size,
                              hipStream_t stream) {
    const float* x       = (const float*)d_in[0];
    const void*  e_raw   = d_in[1];
    const float* W_gat   = (const float*)d_in[2];
    const float* b_gat   = (const float*)d_in[3];
    const float* att_src = (const float*)d_in[4];
    const float* att_dst = (const float*)d_in[5];
    const float* W_enc   = (const float*)d_in[6];
    const float* b_enc   = (const float*)d_in[7];
    const float* W_dec   = (const float*)d_in[8];
    const float* b_dec   = (const float*)d_in[9];
    const float* W_out   = (const float*)d_in[10];
    const float* b_out   = (const float*)d_in[11];
    float* out = (float*)d_out;

    float* ws      = (float*)d_ws;
    float*   hreg  = ws;                       // 6,400,000 f
    unsigned* h_bf = (unsigned*)hreg;          // 3,200,000 u (50000 x 64)
    float* a_src   = hreg + 6400000;           // 200,000 f
    float* a_dst   = a_src + 200000;           // 200,000 f
    float* agg     = a_dst + 200000;           // 6,400,000 f
    uint2* ebuck   = (uint2*)agg;              // 196*CAP*8B = 9.6 MB, aliases agg
    int*   edges   = (int*)(agg + 6400000);    // 1,600,000 i
    int*   csr_src = edges + 1600000;          // 196*CAP = 1,204,224 i
    int2*  nodeoff = (int2*)(csr_src + NBUCK * CAP);  // 50,000 int2
    int*   flag    = (int*)(nodeoff + 50000);  // 1 i
    int*   bcursor = flag + 1;                 // 256 i
    _Float16* swz  = (_Float16*)(((uintptr_t)(bcursor + 256) + 15) & ~(uintptr_t)15); // 32768 f16

    const int GBLK = (N_NODES + BM - 1) / BM;  // 782

    k_detect<<<1, 256, 0, stream>>>((const unsigned*)e_raw, flag);
    k_pre<<<REPACK_BLOCKS + 128 + 1, 256, 0, stream>>>(e_raw, flag, edges,
                                                       W_enc, W_dec, W_out, swz, bcursor);

    k_gat_lin<<<GBLK, 256, 0, stream>>>(x, W_gat, att_src, att_dst, h_bf, a_src, a_dst);

    k_bucket<<<NB_BUCKET_BLOCKS, 256, 0, stream>>>(edges, bcursor, ebuck);
    k_bfill<<<NBUCK, 256, 0, stream>>>(ebuck, bcursor, nodeoff, csr_src);

    k_gather<<<(N_NODES + 3) / 4, 256, 0, stream>>>(nodeoff, csr_src, a_src, a_dst, h_bf, agg);

    k_mlp<<<GBLK, 256, 0, stream>>>(agg, b_gat, swz, b_enc, b_dec, b_out, out);
}

// Round 11
// 212.928 us; speedup vs baseline: 5.7420x; 1.0767x over previous
//
#include <hip/hip_runtime.h>
#include <hip/hip_bf16.h>

#define N_NODES 50000
#define N_EDGES 800000
#define BM 64
#define NBUCK 196            // buckets of 256 nodes: d >> 8
#define CAP 6144             // fixed capacity per bucket (mean 4081, >30 sigma)
#define CHUNK 8192           // edges per block in bucket pass
#define NB_BUCKET_BLOCKS ((N_EDGES + CHUNK - 1) / CHUNK)   // 98
#define REPACK_BLOCKS (2 * N_EDGES / 256)                  // 6250
#define SWZ_BLOCKS 192                                     // 49152 halves
#define SWZ_G 32768                                        // W_gat offset in swz

typedef _Float16 half4v __attribute__((ext_vector_type(4)));
typedef _Float16 half8  __attribute__((ext_vector_type(8)));
typedef float    float4v __attribute__((ext_vector_type(4)));

__device__ __forceinline__ float elu_f(float v) {
    return (v > 0.f) ? v : (__expf(v) - 1.f);
}

// pack two fp32 -> packed bf16x2 (RNE)
__device__ __forceinline__ unsigned f2bf2(float a, float b) {
    unsigned ua = __float_as_uint(a), ub = __float_as_uint(b);
    ua = (ua + 0x7FFFu + ((ua >> 16) & 1u)) >> 16;
    ub = (ub + 0x7FFFu + ((ub >> 16) & 1u)) >> 16;
    return ua | (ub << 16);
}
__device__ __forceinline__ float2 bf2f2(unsigned u) {
    float2 f;
    f.x = __uint_as_float(u << 16);
    f.y = __uint_as_float(u & 0xFFFF0000u);
    return f;
}

// ---------------- edge-index dtype detection ----------------
__global__ void k_detect(const unsigned* __restrict__ e_raw, int* __restrict__ flag) {
    __shared__ int nz;
    if (threadIdx.x == 0) nz = 0;
    __syncthreads();
    int cnt = 0;
    for (int i = threadIdx.x; i < 2048; i += 256)
        if (e_raw[2 * i + 1] != 0u) cnt = 1;
    if (cnt) atomicOr(&nz, 1);
    __syncthreads();
    if (threadIdx.x == 0) *flag = (nz == 0) ? 1 : 0;   // 1 == int64 layout
}

// ---------------- fused pre-pass: repack + weight swizzle + bcursor zero --
// swz layout: [We 0..8192) N=64 | [Wd 8192..16384) N=128 | [Wo 16384..32768)
// N=128 | [Wg 32768..49152) N=128.  B-frag: frag=kc*nnt+nt, within frag
// lane holds B[k=kc*32+(lane>>4)*8+j][n=nt*16+(lane&15)], j=0..7.
__global__ __launch_bounds__(256) void k_pre(const void* __restrict__ e_raw,
        const int* __restrict__ flag, int* __restrict__ edges,
        const float* __restrict__ We, const float* __restrict__ Wd,
        const float* __restrict__ Wo, const float* __restrict__ Wg,
        _Float16* __restrict__ swz, int* __restrict__ bcursor) {
    const int b = blockIdx.x;
    const int tid = threadIdx.x;
    if (b < REPACK_BLOCKS) {
        int i = b * 256 + tid;
        if (*flag) edges[i] = (int)((const long long*)e_raw)[i];
        else       edges[i] = ((const int*)e_raw)[i];
    } else if (b < REPACK_BLOCKS + SWZ_BLOCKS) {
        int t = (b - REPACK_BLOCKS) * 256 + tid;
        const float* W; int base, N;
        if (t < 8192)       { W = We; base = 0;     N = 64;  }
        else if (t < 16384) { W = Wd; base = 8192;  N = 128; }
        else if (t < 32768) { W = Wo; base = 16384; N = 128; }
        else                { W = Wg; base = SWZ_G; N = 128; }
        int loc = t - base;
        int nnt = N >> 4;
        int frag = loc >> 9, r = loc & 511, lane = r >> 3, j = r & 7;
        int kc = frag / nnt, nt = frag - kc * nnt;
        int k = kc * 32 + ((lane >> 4) << 3) + j;
        int n = nt * 16 + (lane & 15);
        swz[t] = (_Float16)W[k * N + n];
    } else {
        bcursor[tid] = 0;
    }
}

// ---------------- K1: h(bf16) = x @ W_gat via MFMA; att head dots --------
// 64 rows/block, 4 waves, wave slab = 16 rows. K=128, N=128.
// MFMA results staged f32 in padded LDS, then the verified epilogue
// (bf16 pack + width-8 shuffle dots) reads rows back.
__global__ __launch_bounds__(256) void k_gat_lin(const float* __restrict__ x,
        const _Float16* __restrict__ swz, const float* __restrict__ att_s,
        const float* __restrict__ att_d, unsigned* __restrict__ h_bf,
        float* __restrict__ a_src, float* __restrict__ a_dst) {
    __shared__ _Float16 sx[64 * 128];   // 16 KB  x-tile f16
    __shared__ float sh[64 * 132];      // 33.8 KB h-tile f32 (pad 132: 2-way free)
    const int tid = threadIdx.x;
    const int m0 = blockIdx.x * 64;

    // stage x -> f16 LDS
#pragma unroll
    for (int i = 0; i < 8; i++) {
        int idx = tid + i * 256;        // 2048 float4 slots (64 x 32)
        int r = idx >> 5, c4 = idx & 31;
        int row = m0 + r; if (row >= N_NODES) row = N_NODES - 1;
        float4 v = ((const float4*)(x + (size_t)row * 128))[c4];
        half4v h;
        h[0] = (_Float16)v.x; h[1] = (_Float16)v.y;
        h[2] = (_Float16)v.z; h[3] = (_Float16)v.w;
        *(half4v*)&sx[r * 128 + c4 * 4] = h;
    }
    __syncthreads();

    const int wave = tid >> 6, lane = tid & 63;
    const int lm = lane & 15, lq = lane >> 4;
    const int wrow = wave * 16;

    {
        float4v acc[8];
#pragma unroll
        for (int nt = 0; nt < 8; nt++) acc[nt] = (float4v){0.f, 0.f, 0.f, 0.f};
#pragma unroll
        for (int kc = 0; kc < 4; kc++) {
            half8 a = *(const half8*)&sx[(wrow + lm) * 128 + kc * 32 + lq * 8];
#pragma unroll
            for (int nt = 0; nt < 8; nt++) {
                half8 b = *(const half8*)&swz[SWZ_G + (kc * 8 + nt) * 512 + lane * 8];
                acc[nt] = __builtin_amdgcn_mfma_f32_16x16x32_f16(a, b, acc[nt], 0, 0, 0);
            }
        }
        // C/D layout: col = nt*16 + lm, row = lq*4 + r
#pragma unroll
        for (int nt = 0; nt < 8; nt++)
#pragma unroll
            for (int r = 0; r < 4; r++)
                sh[(wrow + lq * 4 + r) * 132 + nt * 16 + lm] = acc[nt][r];
    }
    __syncthreads();

    // epilogue: pack bf16 h + attention dots (8 rows x 4 cols per thread)
    const int c0 = (tid & 31) * 4;
    const int r0 = (tid >> 5) * 8;
    float4 as4 = *(const float4*)&att_s[c0];
    float4 ad4 = *(const float4*)&att_d[c0];
    const int head = c0 >> 5;

#pragma unroll
    for (int r = 0; r < 8; r++) {
        int row = m0 + r0 + r;
        bool ok = row < N_NODES;
        float4 hv = *(const float4*)&sh[(r0 + r) * 132 + c0];
        if (ok) {
            uint2 p;
            p.x = f2bf2(hv.x, hv.y);
            p.y = f2bf2(hv.z, hv.w);
            *(uint2*)&h_bf[(size_t)row * 64 + (c0 >> 1)] = p;
        }
        float vs = hv.x * as4.x + hv.y * as4.y + hv.z * as4.z + hv.w * as4.w;
        float vd = hv.x * ad4.x + hv.y * ad4.y + hv.z * ad4.z + hv.w * ad4.w;
#pragma unroll
        for (int o = 4; o >= 1; o >>= 1) {
            vs += __shfl_down(vs, o, 8);
            vd += __shfl_down(vd, o, 8);
        }
        if (ok && (tid & 7) == 0) {
            a_src[row * 4 + head] = vs;
            a_dst[row * 4 + head] = vd;
        }
    }
}

// ---------------- CSR build v3: single-pass fixed-cap bucket sort --------
__global__ __launch_bounds__(256) void k_bucket(const int* __restrict__ edges,
        int* __restrict__ bcursor, uint2* __restrict__ ebuck) {
    __shared__ int lh[256];
    __shared__ int gbase[256];
    __shared__ int lcur[256];
    const int tid = threadIdx.x;
    const int base = blockIdx.x * CHUNK;

    lh[tid] = 0;
    __syncthreads();
#pragma unroll 4
    for (int j = 0; j < CHUNK / 256; j++) {
        int e = base + j * 256 + tid;
        if (e < N_EDGES) {
            int d = edges[N_EDGES + e];
            atomicAdd(&lh[d >> 8], 1);
        }
    }
    __syncthreads();
    if (lh[tid]) gbase[tid] = atomicAdd(&bcursor[tid], lh[tid]);
    lcur[tid] = 0;
    __syncthreads();
#pragma unroll 4
    for (int j = 0; j < CHUNK / 256; j++) {
        int e = base + j * 256 + tid;
        if (e < N_EDGES) {
            int sN = edges[e];
            int d  = edges[N_EDGES + e];
            int b  = d >> 8;
            int idx = gbase[b] + atomicAdd(&lcur[b], 1);
            if (idx < CAP) {    // defensive; statistically impossible to trip
                uint2 pr; pr.x = (unsigned)sN; pr.y = (unsigned)d;
                ebuck[b * CAP + idx] = pr;
            }
        }
    }
}

// per-bucket fine sort -> nodeoff(start,deg) + csr_src (block-owned region)
__global__ __launch_bounds__(256) void k_bfill(const uint2* __restrict__ ebuck,
        const int* __restrict__ bcursor, int2* __restrict__ nodeoff,
        int* __restrict__ csr_src) {
    __shared__ int lh[256];
    __shared__ int lexc[256];
    __shared__ int lcur[256];
    const int tid = threadIdx.x;
    const int b = blockIdx.x;
    const int lo = b * CAP;
    int cnt = bcursor[b]; if (cnt > CAP) cnt = CAP;
    const int hi = lo + cnt;
    const int n0 = b << 8;

    lh[tid] = 0;
    lcur[tid] = 0;
    __syncthreads();
    for (int i = lo + tid; i < hi; i += 256)
        atomicAdd(&lh[ebuck[i].y & 255], 1);
    __syncthreads();
    {
        int v = lh[tid];
        lexc[tid] = v;
        __syncthreads();
        for (int o = 1; o < 256; o <<= 1) {
            int u = (tid >= o) ? lexc[tid - o] : 0;
            __syncthreads();
            lexc[tid] += u;
            __syncthreads();
        }
        int s = lexc[tid] - v;   // exclusive
        __syncthreads();
        lexc[tid] = s;
        int node = n0 + tid;
        if (node < N_NODES) {
            int2 no; no.x = lo + s; no.y = v;
            nodeoff[node] = no;
        }
    }
    __syncthreads();
    for (int i = lo + tid; i < hi; i += 256) {
        uint2 pr = ebuck[i];
        int li = (int)(pr.y & 255);
        int p = atomicAdd(&lcur[li], 1);
        csr_src[lo + lexc[li] + p] = (int)pr.x;
    }
}

// ---------------- K3: CSR gather — 2 edges/wave, 4 ch/lane ---------------
__global__ __launch_bounds__(256) void k_gather(const int2* __restrict__ nodeoff,
        const int* __restrict__ csr_src, const float* __restrict__ a_src,
        const float* __restrict__ a_dst, const unsigned* __restrict__ h_bf,
        float* __restrict__ agg) {
    int d = blockIdx.x * 4 + (threadIdx.x >> 6);
    if (d >= N_NODES) return;
    const int lane = threadIdx.x & 63;
    const int half = lane >> 5;
    const int l32 = lane & 31;
    const int hd = l32 >> 3;             // head of channels 4*l32..+3
    int2 nd = nodeoff[d];
    const int lo = nd.x, hi = nd.x + nd.y;

    const float adh = a_dst[d * 4 + hd];

    float den = 0.f;
    float ax = 0.f, ay = 0.f, az = 0.f, aw = 0.f;

    if (half == 0) {   // self-loop on half 0
        float t = a_src[d * 4 + hd] + adh;
        t = t > 0.f ? t : 0.2f * t;
        float es = __expf(t);
        den = es;
        uint2 hu = ((const uint2*)(h_bf + (size_t)d * 64))[l32];
        float2 c01 = bf2f2(hu.x), c23 = bf2f2(hu.y);
        ax = c01.x * es; ay = c01.y * es;
        az = c23.x * es; aw = c23.y * es;
    }

    int base = lo;
    for (; base + 8 <= hi; base += 8) {
        int i0 = base + half;
        int s0 = csr_src[i0 + 0];
        int s1 = csr_src[i0 + 2];
        int s2 = csr_src[i0 + 4];
        int s3 = csr_src[i0 + 6];
        uint2 u0 = ((const uint2*)(h_bf + (size_t)s0 * 64))[l32];
        uint2 u1 = ((const uint2*)(h_bf + (size_t)s1 * 64))[l32];
        uint2 u2 = ((const uint2*)(h_bf + (size_t)s2 * 64))[l32];
        uint2 u3 = ((const uint2*)(h_bf + (size_t)s3 * 64))[l32];
        float a0 = a_src[s0 * 4 + hd];
        float a1 = a_src[s1 * 4 + hd];
        float a2 = a_src[s2 * 4 + hd];
        float a3 = a_src[s3 * 4 + hd];

        float t0 = a0 + adh; t0 = t0 > 0.f ? t0 : 0.2f * t0;
        float t1 = a1 + adh; t1 = t1 > 0.f ? t1 : 0.2f * t1;
        float t2 = a2 + adh; t2 = t2 > 0.f ? t2 : 0.2f * t2;
        float t3 = a3 + adh; t3 = t3 > 0.f ? t3 : 0.2f * t3;
        float e0 = __expf(t0);
        float e1 = __expf(t1);
        float e2 = __expf(t2);
        float e3 = __expf(t3);
        den += (e0 + e1) + (e2 + e3);

        float2 p, q;
        p = bf2f2(u0.x); q = bf2f2(u0.y);
        ax = fmaf(p.x, e0, ax); ay = fmaf(p.y, e0, ay);
        az = fmaf(q.x, e0, az); aw = fmaf(q.y, e0, aw);
        p = bf2f2(u1.x); q = bf2f2(u1.y);
        ax = fmaf(p.x, e1, ax); ay = fmaf(p.y, e1, ay);
        az = fmaf(q.x, e1, az); aw = fmaf(q.y, e1, aw);
        p = bf2f2(u2.x); q = bf2f2(u2.y);
        ax = fmaf(p.x, e2, ax); ay = fmaf(p.y, e2, ay);
        az = fmaf(q.x, e2, az); aw = fmaf(q.y, e2, aw);
        p = bf2f2(u3.x); q = bf2f2(u3.y);
        ax = fmaf(p.x, e3, ax); ay = fmaf(p.y, e3, ay);
        az = fmaf(q.x, e3, az); aw = fmaf(q.y, e3, aw);
    }
    for (int i = base + half; i < hi; i += 2) {
        int s = csr_src[i];
        float tt = a_src[s * 4 + hd] + adh;
        tt = tt > 0.f ? tt : 0.2f * tt;
        float e = __expf(tt);
        den += e;
        uint2 hu = ((const uint2*)(h_bf + (size_t)s * 64))[l32];
        float2 p = bf2f2(hu.x), q = bf2f2(hu.y);
        ax = fmaf(p.x, e, ax); ay = fmaf(p.y, e, ay);
        az = fmaf(q.x, e, az); aw = fmaf(q.y, e, aw);
    }

    // merge halves
    den += __shfl_xor(den, 32);
    ax += __shfl_xor(ax, 32);
    ay += __shfl_xor(ay, 32);
    az += __shfl_xor(az, 32);
    aw += __shfl_xor(aw, 32);

    if (half == 0) {
        float inv = 1.f / (den + 1e-16f);
        float4 o; o.x = ax * inv; o.y = ay * inv; o.z = az * inv; o.w = aw * inv;
        ((float4*)(agg + (size_t)d * 128))[l32] = o;
    }
}

// ---------------- K4: fused MLP via MFMA f16 -----------------------------
__global__ __launch_bounds__(256) void k_mlp(const float* __restrict__ agg,
        const float* __restrict__ b_gat, const _Float16* __restrict__ swz,
        const float* __restrict__ b_enc, const float* __restrict__ b_dec,
        const float* __restrict__ b_out, float* __restrict__ out) {
    __shared__ _Float16 sx[64 * 128];    // 16 KB
    __shared__ _Float16 se[4 * 16 * 64]; // 8 KB
    const int tid = threadIdx.x;
    const int m0 = blockIdx.x * 64;

#pragma unroll
    for (int i = 0; i < 8; i++) {
        int idx = tid + i * 256;
        int r = idx >> 5, c4 = idx & 31;
        int row = m0 + r; if (row >= N_NODES) row = N_NODES - 1;
        float4 v = ((const float4*)(agg + (size_t)row * 128))[c4];
        float4 bg = ((const float4*)b_gat)[c4];
        half4v h;
        h[0] = (_Float16)elu_f(v.x + bg.x);
        h[1] = (_Float16)elu_f(v.y + bg.y);
        h[2] = (_Float16)elu_f(v.z + bg.z);
        h[3] = (_Float16)elu_f(v.w + bg.w);
        *(half4v*)&sx[r * 128 + c4 * 4] = h;
    }
    __syncthreads();

    const int wave = tid >> 6, lane = tid & 63;
    const int lm = lane & 15, lq = lane >> 4;
    const int wrow = wave * 16;
    _Float16* eslab = &se[wave * 16 * 64];

    // L1: E = X1 @ W_enc + b_enc
    {
        float4v acc[4];
#pragma unroll
        for (int nt = 0; nt < 4; nt++) acc[nt] = (float4v){0.f, 0.f, 0.f, 0.f};
#pragma unroll
        for (int kc = 0; kc < 4; kc++) {
            half8 a = *(const half8*)&sx[(wrow + lm) * 128 + kc * 32 + lq * 8];
#pragma unroll
            for (int nt = 0; nt < 4; nt++) {
                half8 b = *(const half8*)&swz[(kc * 4 + nt) * 512 + lane * 8];
                acc[nt] = __builtin_amdgcn_mfma_f32_16x16x32_f16(a, b, acc[nt], 0, 0, 0);
            }
        }
#pragma unroll
        for (int nt = 0; nt < 4; nt++) {
            float be = b_enc[nt * 16 + lm];
#pragma unroll
            for (int r = 0; r < 4; r++)
                eslab[(lq * 4 + r) * 64 + nt * 16 + lm] = (_Float16)(acc[nt][r] + be);
        }
    }

    // L2: X2 = elu(E @ W_dec + b_dec) -> sx slab
    {
        float4v acc[8];
#pragma unroll
        for (int nt = 0; nt < 8; nt++) acc[nt] = (float4v){0.f, 0.f, 0.f, 0.f};
#pragma unroll
        for (int kc = 0; kc < 2; kc++) {
            half8 a = *(const half8*)&eslab[lm * 64 + kc * 32 + lq * 8];
#pragma unroll
            for (int nt = 0; nt < 8; nt++) {
                half8 b = *(const half8*)&swz[8192 + (kc * 8 + nt) * 512 + lane * 8];
                acc[nt] = __builtin_amdgcn_mfma_f32_16x16x32_f16(a, b, acc[nt], 0, 0, 0);
            }
        }
#pragma unroll
        for (int nt = 0; nt < 8; nt++) {
            float bd = b_dec[nt * 16 + lm];
#pragma unroll
            for (int r = 0; r < 4; r++)
                sx[(wrow + lq * 4 + r) * 128 + nt * 16 + lm] =
                    (_Float16)elu_f(acc[nt][r] + bd);
        }
    }

    // L3: OUT = X2 @ W_out + b_out
    {
        float4v acc[8];
#pragma unroll
        for (int nt = 0; nt < 8; nt++) acc[nt] = (float4v){0.f, 0.f, 0.f, 0.f};
#pragma unroll
        for (int kc = 0; kc < 4; kc++) {
            half8 a = *(const half8*)&sx[(wrow + lm) * 128 + kc * 32 + lq * 8];
#pragma unroll
            for (int nt = 0; nt < 8; nt++) {
                half8 b = *(const half8*)&swz[16384 + (kc * 8 + nt) * 512 + lane * 8];
                acc[nt] = __builtin_amdgcn_mfma_f32_16x16x32_f16(a, b, acc[nt], 0, 0, 0);
            }
        }
#pragma unroll
        for (int nt = 0; nt < 8; nt++) {
            float bo = b_out[nt * 16 + lm];
#pragma unroll
            for (int r = 0; r < 4; r++) {
                int row = m0 + wrow + lq * 4 + r;
                if (row < N_NODES)
                    out[(size_t)row * 128 + nt * 16 + lm] = acc[nt][r] + bo;
            }
        }
    }
}

extern "C" void kernel_launch(void* const* d_in, const int* in_sizes, int n_in,
                              void* d_out, int out_size, void* d_ws, size_t ws_size,
                              hipStream_t stream) {
    const float* x       = (const float*)d_in[0];
    const void*  e_raw   = d_in[1];
    const float* W_gat   = (const float*)d_in[2];
    const float* b_gat   = (const float*)d_in[3];
    const float* att_src = (const float*)d_in[4];
    const float* att_dst = (const float*)d_in[5];
    const float* W_enc   = (const float*)d_in[6];
    const float* b_enc   = (const float*)d_in[7];
    const float* W_dec   = (const float*)d_in[8];
    const float* b_dec   = (const float*)d_in[9];
    const float* W_out   = (const float*)d_in[10];
    const float* b_out   = (const float*)d_in[11];
    float* out = (float*)d_out;

    float* ws      = (float*)d_ws;
    float*   hreg  = ws;                       // 6,400,000 f
    unsigned* h_bf = (unsigned*)hreg;          // 3,200,000 u (50000 x 64)
    float* a_src   = hreg + 6400000;           // 200,000 f
    float* a_dst   = a_src + 200000;           // 200,000 f
    float* agg     = a_dst + 200000;           // 6,400,000 f
    uint2* ebuck   = (uint2*)agg;              // 196*CAP*8B = 9.6 MB, aliases agg
    int*   edges   = (int*)(agg + 6400000);    // 1,600,000 i
    int*   csr_src = edges + 1600000;          // 196*CAP = 1,204,224 i
    int2*  nodeoff = (int2*)(csr_src + NBUCK * CAP);  // 50,000 int2
    int*   flag    = (int*)(nodeoff + 50000);  // 1 i
    int*   bcursor = flag + 1;                 // 256 i
    _Float16* swz  = (_Float16*)(((uintptr_t)(bcursor + 256) + 15) & ~(uintptr_t)15); // 49152 f16

    const int GBLK = (N_NODES + BM - 1) / BM;  // 782

    k_detect<<<1, 256, 0, stream>>>((const unsigned*)e_raw, flag);
    k_pre<<<REPACK_BLOCKS + SWZ_BLOCKS + 1, 256, 0, stream>>>(
        e_raw, flag, edges, W_enc, W_dec, W_out, W_gat, swz, bcursor);

    k_gat_lin<<<GBLK, 256, 0, stream>>>(x, swz, att_src, att_dst, h_bf, a_src, a_dst);

    k_bucket<<<NB_BUCKET_BLOCKS, 256, 0, stream>>>(edges, bcursor, ebuck);
    k_bfill<<<NBUCK, 256, 0, stream>>>(ebuck, bcursor, nodeoff, csr_src);

    k_gather<<<(N_NODES + 3) / 4, 256, 0, stream>>>(nodeoff, csr_src, a_src, a_dst, h_bf, agg);

    k_mlp<<<GBLK, 256, 0, stream>>>(agg, b_gat, swz, b_enc, b_dec, b_out, out);
}